// Round 1
// baseline (1088.019 us; speedup 1.0000x reference)
//
#include <hip/hip_runtime.h>
#include <cstdint>
#include <cstddef>

typedef __attribute__((ext_vector_type(4))) float f32x4;
typedef __attribute__((ext_vector_type(8))) short s16x8;

__device__ inline unsigned short f2b(float f) {
  union { float f; unsigned u; } c; c.f = f;
  return (unsigned short)((c.u + 0x7FFFu + ((c.u >> 16) & 1u)) >> 16);
}
__device__ inline float b2f(unsigned short u) {
  union { unsigned u; float f; } c; c.u = ((unsigned)u) << 16;
  return c.f;
}

__device__ inline void gload_lds16(const void* g, void* l) {
  __builtin_amdgcn_global_load_lds(
      (const __attribute__((address_space(1))) unsigned int*)g,
      (__attribute__((address_space(3))) unsigned int*)l, 16, 0, 0);
}

// ---------------- fp32 -> bf16 convert (float4 per thread) ----------------
__global__ __launch_bounds__(256) void cvt_bf16_k(const float* __restrict__ in,
                                                  unsigned short* __restrict__ out,
                                                  int n4) {
  int i = blockIdx.x * 256 + threadIdx.x;
  if (i >= n4) return;
  float4 v = ((const float4*)in)[i];
  ushort4 o;
  o.x = f2b(v.x); o.y = f2b(v.y); o.z = f2b(v.z); o.w = f2b(v.w);
  ((ushort4*)out)[i] = o;
}

// ------- build combined weight: rows 0..1535 = dt_proj_w @ x_proj_w[:48]
// -------                        rows 1536..1663 = x_proj_w[48:80] then zeros
__global__ __launch_bounds__(256) void build_wbig(const float* __restrict__ xpw,
                                                  const float* __restrict__ dtw,
                                                  unsigned short* __restrict__ wbig) {
  int k = blockIdx.x * 256 + threadIdx.x;   // 0..1535
  int rowid = blockIdx.y;                   // 0..1663
  float v;
  if (rowid < 1536) {
    float s = 0.f;
    #pragma unroll 8
    for (int r = 0; r < 48; ++r)
      s = __builtin_fmaf(dtw[rowid * 48 + r], xpw[r * 1536 + k], s);
    v = s;
  } else {
    int rr = rowid - 1536;
    v = (rr < 32) ? xpw[(48 + rr) * 1536 + k] : 0.f;
  }
  wbig[(size_t)rowid * 1536 + k] = f2b(v);
}

// ---------------- LayerNorm over 768, one wave per row, bf16 out ----------
__global__ __launch_bounds__(256) void ln_kernel(const float* __restrict__ x,
                                                 const float* __restrict__ gam,
                                                 const float* __restrict__ bet,
                                                 unsigned short* __restrict__ out) {
  int w = threadIdx.x >> 6, lane = threadIdx.x & 63;
  size_t row = (size_t)blockIdx.x * 4 + w;
  const float4* xr = (const float4*)(x + row * 768);
  float4 v0 = xr[lane], v1 = xr[lane + 64], v2 = xr[lane + 128];
  float s = v0.x + v0.y + v0.z + v0.w + v1.x + v1.y + v1.z + v1.w +
            v2.x + v2.y + v2.z + v2.w;
  #pragma unroll
  for (int o = 32; o; o >>= 1) s += __shfl_xor(s, o);
  float mu = s * (1.f / 768.f);
  float q = 0.f;
  {
    float d;
    d = v0.x - mu; q += d * d; d = v0.y - mu; q += d * d;
    d = v0.z - mu; q += d * d; d = v0.w - mu; q += d * d;
    d = v1.x - mu; q += d * d; d = v1.y - mu; q += d * d;
    d = v1.z - mu; q += d * d; d = v1.w - mu; q += d * d;
    d = v2.x - mu; q += d * d; d = v2.y - mu; q += d * d;
    d = v2.z - mu; q += d * d; d = v2.w - mu; q += d * d;
  }
  #pragma unroll
  for (int o = 32; o; o >>= 1) q += __shfl_xor(q, o);
  float rs = rsqrtf(q * (1.f / 768.f) + 1e-5f);
  const float4* gr = (const float4*)gam;
  const float4* br = (const float4*)bet;
  ushort4* orow = (ushort4*)(out + row * 768);
  float4 vv[3] = {v0, v1, v2};
  #pragma unroll
  for (int i = 0; i < 3; ++i) {
    int c4 = lane + i * 64;
    float4 g4 = gr[c4], b4 = br[c4];
    ushort4 o;
    o.x = f2b((vv[i].x - mu) * rs * g4.x + b4.x);
    o.y = f2b((vv[i].y - mu) * rs * g4.y + b4.y);
    o.z = f2b((vv[i].z - mu) * rs * g4.z + b4.z);
    o.w = f2b((vv[i].w - mu) * rs * g4.w + b4.w);
    orow[c4] = o;
  }
}

// ---------------- causal depthwise conv(4) + bias + SiLU -> bf16 ----------
__global__ __launch_bounds__(256) void conv_silu(const float* __restrict__ xres,
                                                 const float* __restrict__ cw,
                                                 const float* __restrict__ cb,
                                                 unsigned short* __restrict__ xs_act) {
  int idx = blockIdx.x * 256 + threadIdx.x;  // 4096*384
  int t = idx / 384;
  int c4 = idx - t * 384;
  int pos = t & 1023;
  const float* base = xres + (size_t)t * 3072 + c4 * 4;
  float4 z = {0.f, 0.f, 0.f, 0.f};
  float4 x3 = *(const float4*)base;
  float4 x2 = (pos >= 1) ? *(const float4*)(base - 3072) : z;
  float4 x1 = (pos >= 2) ? *(const float4*)(base - 6144) : z;
  float4 x0 = (pos >= 3) ? *(const float4*)(base - 9216) : z;
  float a0[4] = {x0.x, x0.y, x0.z, x0.w};
  float a1[4] = {x1.x, x1.y, x1.z, x1.w};
  float a2[4] = {x2.x, x2.y, x2.z, x2.w};
  float a3[4] = {x3.x, x3.y, x3.z, x3.w};
  ushort4 o;
  unsigned short* op = &o.x;
  #pragma unroll
  for (int i = 0; i < 4; ++i) {
    int dd = c4 * 4 + i;
    float4 wv = *(const float4*)(cw + dd * 4);
    float v = wv.x * a0[i] + wv.y * a1[i] + wv.z * a2[i] + wv.w * a3[i] + cb[dd];
    float sv = v / (1.f + __expf(-v));
    op[i] = f2b(sv);
  }
  *(ushort4*)(xs_act + (size_t)t * 1536 + c4 * 4) = o;
}

// ---------------- selective scan: 16 lanes per (b,d), DPP reduce ----------
__global__ __launch_bounds__(256) void scan_kernel(
    const float* __restrict__ dbc,            // (4096,1664): delta | B | C
    const unsigned short* __restrict__ u_bf,  // (4096,1536) bf16
    const float* __restrict__ xres,           // (4096,3072), res at +1536
    const float* __restrict__ A_log,          // (1536,16)
    const float* __restrict__ D_param,        // (1536)
    const float* __restrict__ dt_bias,        // (1536)
    unsigned short* __restrict__ y_out) {     // (4096,1536) bf16
  int tid = threadIdx.x;
  int grp = tid >> 4;
  int n = tid & 15;
  int b = blockIdx.x / 96;
  int d = (blockIdx.x - b * 96) * 16 + grp;
  float A = -__expf(A_log[d * 16 + n]);
  float bias = dt_bias[d];
  float Dp = D_param[d];
  const float* drow = dbc + (size_t)b * 1024 * 1664 + d;
  const float* bcrow = dbc + (size_t)b * 1024 * 1664 + 1536 + n;
  const unsigned short* urow = u_bf + (size_t)b * 1024 * 1536 + d;
  const float* rrow = xres + (size_t)b * 1024 * 3072 + 1536 + d;
  unsigned short* yrow = y_out + (size_t)b * 1024 * 1536 + d;
  float h = 0.f;
  #pragma unroll 4
  for (int t = 0; t < 1024; ++t) {
    float x = drow[(size_t)t * 1664] + bias;
    float dsp = (x > 20.f) ? x : __logf(1.f + __expf(x));
    float ut = b2f(urow[(size_t)t * 1536]);
    float Bv = bcrow[(size_t)t * 1664];
    float Cv = bcrow[(size_t)t * 1664 + 16];
    float dA = __expf(dsp * A);
    h = __builtin_fmaf(dA, h, dsp * ut * Bv);
    float p = h * Cv;
    // sum over the 16-lane group via DPP row rotations (row = 16 lanes)
    p += __int_as_float(__builtin_amdgcn_update_dpp(0, __float_as_int(p), 0x128, 0xF, 0xF, true));
    p += __int_as_float(__builtin_amdgcn_update_dpp(0, __float_as_int(p), 0x124, 0xF, 0xF, true));
    p += __int_as_float(__builtin_amdgcn_update_dpp(0, __float_as_int(p), 0x122, 0xF, 0xF, true));
    p += __int_as_float(__builtin_amdgcn_update_dpp(0, __float_as_int(p), 0x121, 0xF, 0xF, true));
    if (n == 0) {
      float r = rrow[(size_t)t * 3072];
      float sr = r / (1.f + __expf(-r));
      yrow[(size_t)t * 1536] = f2b(__builtin_fmaf(ut, Dp, p) * sr);
    }
  }
}

// ---------------- bf16 MFMA GEMM: C(MxN) = A(MxK) @ B(NxK)^T -------------
// MODE 0: C fp32 = acc
// MODE 1: C fp32 = res + acc
// MODE 2: C bf16 = gelu_exact(acc + bias[col])
// MODE 3: C fp32 = res + bias[col] + acc
template <int MODE>
__global__ __launch_bounds__(256, 2) void gemm_bt(
    const unsigned short* __restrict__ A, const unsigned short* __restrict__ B,
    int M, int N, int K, float* __restrict__ Cf, unsigned short* __restrict__ Cb,
    const float* __restrict__ res, const float* __restrict__ bias) {
  __shared__ __align__(16) unsigned short As[128 * 32];
  __shared__ __align__(16) unsigned short Bs[128 * 32];
  int tid = threadIdx.x;
  int lane = tid & 63;
  int w = tid >> 6;
  int wm = w >> 1, wn = w & 1;
  int row0 = blockIdx.y * 128;
  int col0 = blockIdx.x * 128;
  const int lr = lane & 15;
  const int kb = lane >> 4;

  f32x4 acc[4][4];
  #pragma unroll
  for (int i = 0; i < 4; ++i)
    #pragma unroll
    for (int j = 0; j < 4; ++j) acc[i][j] = (f32x4)0.f;

  for (int k0 = 0; k0 < K; k0 += 32) {
    #pragma unroll
    for (int j = 0; j < 2; ++j) {
      int e = j * 256 + tid;
      int r = e >> 2, cc = e & 3;
      gload_lds16(A + (size_t)(row0 + r) * K + k0 + cc * 8, &As[e * 8]);
      gload_lds16(B + (size_t)(col0 + r) * K + k0 + cc * 8, &Bs[e * 8]);
    }
    __syncthreads();
    s16x8 af[4], bf[4];
    #pragma unroll
    for (int m = 0; m < 4; ++m)
      af[m] = *(const s16x8*)&As[(wm * 64 + m * 16 + lr) * 32 + kb * 8];
    #pragma unroll
    for (int nn = 0; nn < 4; ++nn)
      bf[nn] = *(const s16x8*)&Bs[(wn * 64 + nn * 16 + lr) * 32 + kb * 8];
    #pragma unroll
    for (int m = 0; m < 4; ++m)
      #pragma unroll
      for (int nn = 0; nn < 4; ++nn)
        acc[m][nn] = __builtin_amdgcn_mfma_f32_16x16x32_bf16(af[m], bf[nn], acc[m][nn], 0, 0, 0);
    __syncthreads();
  }

  #pragma unroll
  for (int m = 0; m < 4; ++m) {
    int rbase = row0 + wm * 64 + m * 16 + kb * 4;
    #pragma unroll
    for (int nn = 0; nn < 4; ++nn) {
      int col = col0 + wn * 64 + nn * 16 + lr;
      #pragma unroll
      for (int r = 0; r < 4; ++r) {
        int row = rbase + r;
        size_t idx = (size_t)row * N + col;
        float v = acc[m][nn][r];
        if (MODE == 0) {
          Cf[idx] = v;
        } else if (MODE == 1) {
          Cf[idx] = res[idx] + v;
        } else if (MODE == 2) {
          float tt = v + bias[col];
          float gl = 0.5f * tt * (1.f + erff(tt * 0.7071067811865475f));
          Cb[idx] = f2b(gl);
        } else {
          Cf[idx] = res[idx] + bias[col] + v;
        }
      }
    }
  }
}

extern "C" void kernel_launch(void* const* d_in, const int* in_sizes, int n_in,
                              void* d_out, int out_size, void* d_ws, size_t ws_size,
                              hipStream_t stream) {
  (void)in_sizes; (void)n_in; (void)out_size; (void)ws_size;
  const float* src   = (const float*)d_in[0];
  const float* n1g   = (const float*)d_in[1];
  const float* n1b   = (const float*)d_in[2];
  const float* inW   = (const float*)d_in[3];
  const float* convW = (const float*)d_in[4];
  const float* convB = (const float*)d_in[5];
  const float* xpW   = (const float*)d_in[6];
  const float* dtW   = (const float*)d_in[7];
  const float* dtB   = (const float*)d_in[8];
  const float* Alog  = (const float*)d_in[9];
  const float* Dpar  = (const float*)d_in[10];
  const float* outW  = (const float*)d_in[11];
  const float* n2g   = (const float*)d_in[12];
  const float* n2b   = (const float*)d_in[13];
  const float* w1    = (const float*)d_in[14];
  const float* b1    = (const float*)d_in[15];
  const float* w2    = (const float*)d_in[16];
  const float* b2    = (const float*)d_in[17];

  char* ws = (char*)d_ws;
  unsigned short* wbA  = (unsigned short*)(ws + 0);           // in_proj bf16  (3072x768)
  unsigned short* wbO  = (unsigned short*)(ws + 4718592);     // out_proj bf16 (768x1536)
  unsigned short* wb1  = (unsigned short*)(ws + 7077888);     // w1 bf16       (3072x768)
  unsigned short* wb2  = (unsigned short*)(ws + 11796480);    // w2 bf16       (768x3072)
  unsigned short* wbig = (unsigned short*)(ws + 16515072);    // (1664x1536) bf16
  unsigned short* hbf  = (unsigned short*)(ws + 21626880);    // (4096x768) bf16; reused as h2
  float*          xres = (float*)(ws + 27918336);             // (4096x3072) fp32
  unsigned short* xsact= (unsigned short*)(ws + 78249984);    // (4096x1536) bf16
  float*          xbuf = (float*)(ws + 78249984);             // (4096x768) fp32 (reuse, after scan)
  float*          dbc  = (float*)(ws + 90832896);             // (4096x1664) fp32
  unsigned short* ff1  = (unsigned short*)(ws + 90832896);    // (4096x3072) bf16 (reuse, after scan)
  unsigned short* ybuf = (unsigned short*)(ws + 118095872);   // (4096x1536) bf16
  float* outp = (float*)d_out;

  // weight prep
  cvt_bf16_k<<<2304, 256, 0, stream>>>(inW, wbA, 589824);
  cvt_bf16_k<<<1152, 256, 0, stream>>>(outW, wbO, 294912);
  cvt_bf16_k<<<2304, 256, 0, stream>>>(w1, wb1, 589824);
  cvt_bf16_k<<<2304, 256, 0, stream>>>(w2, wb2, 589824);
  build_wbig<<<dim3(6, 1664), 256, 0, stream>>>(xpW, dtW, wbig);

  // mamba block
  ln_kernel<<<1024, 256, 0, stream>>>(src, n1g, n1b, hbf);
  gemm_bt<0><<<dim3(24, 32), 256, 0, stream>>>(hbf, wbA, 4096, 3072, 768, xres, nullptr, nullptr, nullptr);
  conv_silu<<<6144, 256, 0, stream>>>(xres, convW, convB, xsact);
  gemm_bt<0><<<dim3(13, 32), 256, 0, stream>>>(xsact, wbig, 4096, 1664, 1536, dbc, nullptr, nullptr, nullptr);
  scan_kernel<<<384, 256, 0, stream>>>(dbc, xsact, xres, Alog, Dpar, dtB, ybuf);
  gemm_bt<1><<<dim3(6, 32), 256, 0, stream>>>(ybuf, wbO, 4096, 768, 1536, xbuf, nullptr, src, nullptr);

  // FFN block
  ln_kernel<<<1024, 256, 0, stream>>>(xbuf, n2g, n2b, hbf);
  gemm_bt<2><<<dim3(24, 32), 256, 0, stream>>>(hbf, wb1, 4096, 3072, 768, nullptr, ff1, nullptr, b1);
  gemm_bt<3><<<dim3(6, 32), 256, 0, stream>>>(ff1, wb2, 4096, 768, 3072, outp, nullptr, xbuf, b2);
}

// Round 2
// 543.772 us; speedup vs baseline: 2.0009x; 2.0009x over previous
//
#include <hip/hip_runtime.h>
#include <cstdint>
#include <cstddef>

typedef __attribute__((ext_vector_type(4))) float f32x4;
typedef __attribute__((ext_vector_type(8))) short s16x8;

__device__ inline unsigned short f2b(float f) {
  union { float f; unsigned u; } c; c.f = f;
  return (unsigned short)((c.u + 0x7FFFu + ((c.u >> 16) & 1u)) >> 16);
}
__device__ inline float b2f(unsigned short u) {
  union { unsigned u; float f; } c; c.u = ((unsigned)u) << 16;
  return c.f;
}

__device__ inline void gload_lds16(const void* g, void* l) {
  __builtin_amdgcn_global_load_lds(
      (const __attribute__((address_space(1))) unsigned int*)g,
      (__attribute__((address_space(3))) unsigned int*)l, 16, 0, 0);
}

// map linear index j in [0, 1.57M) into the dead first-half columns of xres
// (rows 0..1023, cols 0..1535 are free after conv_silu consumed them)
__device__ inline size_t hole(int j) {
  int r = j / 1536;
  int c = j - r * 1536;
  return (size_t)r * 3072 + c;
}

// ---------------- fp32 -> bf16 convert (float4 per thread) ----------------
__global__ __launch_bounds__(256) void cvt_bf16_k(const float* __restrict__ in,
                                                  unsigned short* __restrict__ out,
                                                  int n4) {
  int i = blockIdx.x * 256 + threadIdx.x;
  if (i >= n4) return;
  float4 v = ((const float4*)in)[i];
  ushort4 o;
  o.x = f2b(v.x); o.y = f2b(v.y); o.z = f2b(v.z); o.w = f2b(v.w);
  ((ushort4*)out)[i] = o;
}

// ------- build combined weight: rows 0..1535 = dt_proj_w @ x_proj_w[:48]
// -------                        rows 1536..1663 = x_proj_w[48:80] then zeros
__global__ __launch_bounds__(256) void build_wbig(const float* __restrict__ xpw,
                                                  const float* __restrict__ dtw,
                                                  unsigned short* __restrict__ wbig) {
  int k = blockIdx.x * 256 + threadIdx.x;   // 0..1535
  int rowid = blockIdx.y;                   // 0..1663
  float v;
  if (rowid < 1536) {
    float s = 0.f;
    #pragma unroll 8
    for (int r = 0; r < 48; ++r)
      s = __builtin_fmaf(dtw[rowid * 48 + r], xpw[r * 1536 + k], s);
    v = s;
  } else {
    int rr = rowid - 1536;
    v = (rr < 32) ? xpw[(48 + rr) * 1536 + k] : 0.f;
  }
  wbig[(size_t)rowid * 1536 + k] = f2b(v);
}

// ---------------- LayerNorm over 768, one wave per row, bf16 out ----------
__global__ __launch_bounds__(256) void ln_kernel(const float* __restrict__ x,
                                                 const float* __restrict__ gam,
                                                 const float* __restrict__ bet,
                                                 unsigned short* __restrict__ out) {
  int w = threadIdx.x >> 6, lane = threadIdx.x & 63;
  size_t row = (size_t)blockIdx.x * 4 + w;
  const float4* xr = (const float4*)(x + row * 768);
  float4 v0 = xr[lane], v1 = xr[lane + 64], v2 = xr[lane + 128];
  float s = v0.x + v0.y + v0.z + v0.w + v1.x + v1.y + v1.z + v1.w +
            v2.x + v2.y + v2.z + v2.w;
  #pragma unroll
  for (int o = 32; o; o >>= 1) s += __shfl_xor(s, o);
  float mu = s * (1.f / 768.f);
  float q = 0.f;
  {
    float d;
    d = v0.x - mu; q += d * d; d = v0.y - mu; q += d * d;
    d = v0.z - mu; q += d * d; d = v0.w - mu; q += d * d;
    d = v1.x - mu; q += d * d; d = v1.y - mu; q += d * d;
    d = v1.z - mu; q += d * d; d = v1.w - mu; q += d * d;
    d = v2.x - mu; q += d * d; d = v2.y - mu; q += d * d;
    d = v2.z - mu; q += d * d; d = v2.w - mu; q += d * d;
  }
  #pragma unroll
  for (int o = 32; o; o >>= 1) q += __shfl_xor(q, o);
  float rs = rsqrtf(q * (1.f / 768.f) + 1e-5f);
  const float4* gr = (const float4*)gam;
  const float4* br = (const float4*)bet;
  ushort4* orow = (ushort4*)(out + row * 768);
  float4 vv[3] = {v0, v1, v2};
  #pragma unroll
  for (int i = 0; i < 3; ++i) {
    int c4 = lane + i * 64;
    float4 g4 = gr[c4], b4 = br[c4];
    ushort4 o;
    o.x = f2b((vv[i].x - mu) * rs * g4.x + b4.x);
    o.y = f2b((vv[i].y - mu) * rs * g4.y + b4.y);
    o.z = f2b((vv[i].z - mu) * rs * g4.z + b4.z);
    o.w = f2b((vv[i].w - mu) * rs * g4.w + b4.w);
    orow[c4] = o;
  }
}

// ---------------- causal depthwise conv(4) + bias + SiLU -> bf16 ----------
__global__ __launch_bounds__(256) void conv_silu(const float* __restrict__ xres,
                                                 const float* __restrict__ cw,
                                                 const float* __restrict__ cb,
                                                 unsigned short* __restrict__ xs_act) {
  int idx = blockIdx.x * 256 + threadIdx.x;  // 4096*384
  int t = idx / 384;
  int c4 = idx - t * 384;
  int pos = t & 1023;
  const float* base = xres + (size_t)t * 3072 + c4 * 4;
  float4 z = {0.f, 0.f, 0.f, 0.f};
  float4 x3 = *(const float4*)base;
  float4 x2 = (pos >= 1) ? *(const float4*)(base - 3072) : z;
  float4 x1 = (pos >= 2) ? *(const float4*)(base - 6144) : z;
  float4 x0 = (pos >= 3) ? *(const float4*)(base - 9216) : z;
  float a0[4] = {x0.x, x0.y, x0.z, x0.w};
  float a1[4] = {x1.x, x1.y, x1.z, x1.w};
  float a2[4] = {x2.x, x2.y, x2.z, x2.w};
  float a3[4] = {x3.x, x3.y, x3.z, x3.w};
  ushort4 o;
  unsigned short* op = &o.x;
  #pragma unroll
  for (int i = 0; i < 4; ++i) {
    int dd = c4 * 4 + i;
    float4 wv = *(const float4*)(cw + dd * 4);
    float v = wv.x * a0[i] + wv.y * a1[i] + wv.z * a2[i] + wv.w * a3[i] + cb[dd];
    float sv = v / (1.f + __expf(-v));
    op[i] = f2b(sv);
  }
  *(ushort4*)(xs_act + (size_t)t * 1536 + c4 * 4) = o;
}

// ================== chunked selective scan (16 chunks x 64 steps) =========
// block = 256 thr: 16 groups (16 consecutive d) x 16 lanes (n)
// grid  = b(4) * dtile(96) * chunk(16) = 6144 blocks
// P1: from h=0 compute chunk decay product P and local end-state h_end.
__global__ __launch_bounds__(256) void scan_p1(
    const float* __restrict__ dbc, const unsigned short* __restrict__ u_bf,
    const float* __restrict__ A_log, const float* __restrict__ dt_bias,
    float* __restrict__ P_buf, float* __restrict__ xres_holes) {
  int tid = threadIdx.x;
  int grp = tid >> 4, n = tid & 15;
  int blk = blockIdx.x;
  int c = blk & 15;
  int bt = blk >> 4;
  int b = bt / 96;
  int dtile = bt - b * 96;
  int d = dtile * 16 + grp;
  float A = -__expf(A_log[d * 16 + n]);
  float bias = dt_bias[d];
  const float* base = dbc + (size_t)b * 1024 * 1664;
  const unsigned short* ub = u_bf + (size_t)b * 1024 * 1536;
  int t0 = c * 64;
  float h = 0.f, P = 1.f;
  #pragma unroll 4
  for (int s = 0; s < 64; ++s) {
    size_t t = t0 + s;
    float x = base[t * 1664 + d] + bias;
    float dsp = (x > 20.f) ? x : __logf(1.f + __expf(x));
    float ut = b2f(ub[t * 1536 + d]);
    float Bv = base[t * 1664 + 1536 + n];
    float dA = __expf(dsp * A);
    h = __builtin_fmaf(dA, h, dsp * ut * Bv);
    P *= dA;
  }
  int idx = (b * 1536 + d) * 16 + n;
  int j = c * 98304 + idx;
  P_buf[j] = P;
  xres_holes[hole(j)] = h;
}

// P2: per (b,d,n) combine the 16 chunks; store each chunk's true initial
// state H_{c-1} in-place over P_buf[c].
__global__ __launch_bounds__(256) void scan_p2(float* __restrict__ P_buf,
                                               const float* __restrict__ xres_holes) {
  int i = blockIdx.x * 256 + threadIdx.x;  // [0, 98304)
  float H = 0.f;
  #pragma unroll
  for (int c = 0; c < 16; ++c) {
    int j = c * 98304 + i;
    float P = P_buf[j];
    float he = xres_holes[hole(j)];
    P_buf[j] = H;
    H = __builtin_fmaf(P, H, he);
  }
}

// P3: replay each chunk from its true H_init; reduce h*C over n via DPP,
// fuse +u*D and *silu(res), write bf16 y.
__global__ __launch_bounds__(256) void scan_p3(
    const float* __restrict__ dbc, const unsigned short* __restrict__ u_bf,
    const float* __restrict__ xres, const float* __restrict__ A_log,
    const float* __restrict__ D_param, const float* __restrict__ dt_bias,
    const float* __restrict__ P_buf, unsigned short* __restrict__ y_out) {
  int tid = threadIdx.x;
  int grp = tid >> 4, n = tid & 15;
  int blk = blockIdx.x;
  int c = blk & 15;
  int bt = blk >> 4;
  int b = bt / 96;
  int dtile = bt - b * 96;
  int d = dtile * 16 + grp;
  float A = -__expf(A_log[d * 16 + n]);
  float bias = dt_bias[d];
  float Dp = D_param[d];
  const float* base = dbc + (size_t)b * 1024 * 1664;
  const unsigned short* ub = u_bf + (size_t)b * 1024 * 1536;
  const float* rbase = xres + (size_t)b * 1024 * 3072 + 1536 + d;
  unsigned short* yrow = y_out + (size_t)b * 1024 * 1536 + d;
  int t0 = c * 64;
  int idx = (b * 1536 + d) * 16 + n;
  float h = P_buf[c * 98304 + idx];
  #pragma unroll 4
  for (int s = 0; s < 64; ++s) {
    size_t t = t0 + s;
    float x = base[t * 1664 + d] + bias;
    float dsp = (x > 20.f) ? x : __logf(1.f + __expf(x));
    float ut = b2f(ub[t * 1536 + d]);
    float Bv = base[t * 1664 + 1536 + n];
    float Cv = base[t * 1664 + 1552 + n];
    float dA = __expf(dsp * A);
    h = __builtin_fmaf(dA, h, dsp * ut * Bv);
    float p = h * Cv;
    p += __int_as_float(__builtin_amdgcn_update_dpp(0, __float_as_int(p), 0x128, 0xF, 0xF, true));
    p += __int_as_float(__builtin_amdgcn_update_dpp(0, __float_as_int(p), 0x124, 0xF, 0xF, true));
    p += __int_as_float(__builtin_amdgcn_update_dpp(0, __float_as_int(p), 0x122, 0xF, 0xF, true));
    p += __int_as_float(__builtin_amdgcn_update_dpp(0, __float_as_int(p), 0x121, 0xF, 0xF, true));
    if (n == 0) {
      float r = rbase[t * 3072];
      float sr = r / (1.f + __expf(-r));
      yrow[t * 1536] = f2b(__builtin_fmaf(ut, Dp, p) * sr);
    }
  }
}

// ---------------- bf16 MFMA GEMM: C(MxN) = A(MxK) @ B(NxK)^T -------------
// MODE 0: C fp32 = acc
// MODE 1: C fp32 = res + acc
// MODE 2: C bf16 = gelu_exact(acc + bias[col])
// MODE 3: C fp32 = res + bias[col] + acc
template <int MODE>
__global__ __launch_bounds__(256, 2) void gemm_bt(
    const unsigned short* __restrict__ A, const unsigned short* __restrict__ B,
    int M, int N, int K, float* __restrict__ Cf, unsigned short* __restrict__ Cb,
    const float* __restrict__ res, const float* __restrict__ bias) {
  __shared__ __align__(16) unsigned short As[128 * 32];
  __shared__ __align__(16) unsigned short Bs[128 * 32];
  int tid = threadIdx.x;
  int lane = tid & 63;
  int w = tid >> 6;
  int wm = w >> 1, wn = w & 1;
  int row0 = blockIdx.y * 128;
  int col0 = blockIdx.x * 128;
  const int lr = lane & 15;
  const int kb = lane >> 4;

  f32x4 acc[4][4];
  #pragma unroll
  for (int i = 0; i < 4; ++i)
    #pragma unroll
    for (int j = 0; j < 4; ++j) acc[i][j] = (f32x4)0.f;

  for (int k0 = 0; k0 < K; k0 += 32) {
    #pragma unroll
    for (int j = 0; j < 2; ++j) {
      int e = j * 256 + tid;
      int r = e >> 2, cc = e & 3;
      gload_lds16(A + (size_t)(row0 + r) * K + k0 + cc * 8, &As[e * 8]);
      gload_lds16(B + (size_t)(col0 + r) * K + k0 + cc * 8, &Bs[e * 8]);
    }
    __syncthreads();
    s16x8 af[4], bf[4];
    #pragma unroll
    for (int m = 0; m < 4; ++m)
      af[m] = *(const s16x8*)&As[(wm * 64 + m * 16 + lr) * 32 + kb * 8];
    #pragma unroll
    for (int nn = 0; nn < 4; ++nn)
      bf[nn] = *(const s16x8*)&Bs[(wn * 64 + nn * 16 + lr) * 32 + kb * 8];
    #pragma unroll
    for (int m = 0; m < 4; ++m)
      #pragma unroll
      for (int nn = 0; nn < 4; ++nn)
        acc[m][nn] = __builtin_amdgcn_mfma_f32_16x16x32_bf16(af[m], bf[nn], acc[m][nn], 0, 0, 0);
    __syncthreads();
  }

  #pragma unroll
  for (int m = 0; m < 4; ++m) {
    int rbase = row0 + wm * 64 + m * 16 + kb * 4;
    #pragma unroll
    for (int nn = 0; nn < 4; ++nn) {
      int col = col0 + wn * 64 + nn * 16 + lr;
      #pragma unroll
      for (int r = 0; r < 4; ++r) {
        int row = rbase + r;
        size_t idx = (size_t)row * N + col;
        float v = acc[m][nn][r];
        if (MODE == 0) {
          Cf[idx] = v;
        } else if (MODE == 1) {
          Cf[idx] = res[idx] + v;
        } else if (MODE == 2) {
          float tt = v + bias[col];
          float gl = 0.5f * tt * (1.f + erff(tt * 0.7071067811865475f));
          Cb[idx] = f2b(gl);
        } else {
          Cf[idx] = res[idx] + bias[col] + v;
        }
      }
    }
  }
}

extern "C" void kernel_launch(void* const* d_in, const int* in_sizes, int n_in,
                              void* d_out, int out_size, void* d_ws, size_t ws_size,
                              hipStream_t stream) {
  (void)in_sizes; (void)n_in; (void)out_size; (void)ws_size;
  const float* src   = (const float*)d_in[0];
  const float* n1g   = (const float*)d_in[1];
  const float* n1b   = (const float*)d_in[2];
  const float* inW   = (const float*)d_in[3];
  const float* convW = (const float*)d_in[4];
  const float* convB = (const float*)d_in[5];
  const float* xpW   = (const float*)d_in[6];
  const float* dtW   = (const float*)d_in[7];
  const float* dtB   = (const float*)d_in[8];
  const float* Alog  = (const float*)d_in[9];
  const float* Dpar  = (const float*)d_in[10];
  const float* outW  = (const float*)d_in[11];
  const float* n2g   = (const float*)d_in[12];
  const float* n2b   = (const float*)d_in[13];
  const float* w1    = (const float*)d_in[14];
  const float* b1    = (const float*)d_in[15];
  const float* w2    = (const float*)d_in[16];
  const float* b2    = (const float*)d_in[17];

  char* ws = (char*)d_ws;
  unsigned short* wbA  = (unsigned short*)(ws + 0);           // in_proj bf16  (3072x768)
  unsigned short* wbO  = (unsigned short*)(ws + 4718592);     // out_proj bf16 (768x1536)
  unsigned short* wb1  = (unsigned short*)(ws + 7077888);     // w1 bf16       (3072x768)
  unsigned short* wb2  = (unsigned short*)(ws + 11796480);    // w2 bf16       (768x3072)
  unsigned short* wbig = (unsigned short*)(ws + 16515072);    // (1664x1536) bf16
  unsigned short* hbf  = (unsigned short*)(ws + 21626880);    // (4096x768) bf16; reused as h2
  float*          Pbuf = (float*)(ws + 21626880);             // scan scratch: reuses hbf (dead between GEMM1 and LN2)
  float*          xres = (float*)(ws + 27918336);             // (4096x3072) fp32; first-half cols reused as scan h_end holes
  unsigned short* xsact= (unsigned short*)(ws + 78249984);    // (4096x1536) bf16
  float*          xbuf = (float*)(ws + 78249984);             // (4096x768) fp32 (reuse, after scan)
  float*          dbc  = (float*)(ws + 90832896);             // (4096x1664) fp32
  unsigned short* ff1  = (unsigned short*)(ws + 90832896);    // (4096x3072) bf16 (reuse, after scan)
  unsigned short* ybuf = (unsigned short*)(ws + 118095872);   // (4096x1536) bf16
  float* outp = (float*)d_out;

  // weight prep
  cvt_bf16_k<<<2304, 256, 0, stream>>>(inW, wbA, 589824);
  cvt_bf16_k<<<1152, 256, 0, stream>>>(outW, wbO, 294912);
  cvt_bf16_k<<<2304, 256, 0, stream>>>(w1, wb1, 589824);
  cvt_bf16_k<<<2304, 256, 0, stream>>>(w2, wb2, 589824);
  build_wbig<<<dim3(6, 1664), 256, 0, stream>>>(xpW, dtW, wbig);

  // mamba block
  ln_kernel<<<1024, 256, 0, stream>>>(src, n1g, n1b, hbf);
  gemm_bt<0><<<dim3(24, 32), 256, 0, stream>>>(hbf, wbA, 4096, 3072, 768, xres, nullptr, nullptr, nullptr);
  conv_silu<<<6144, 256, 0, stream>>>(xres, convW, convB, xsact);
  gemm_bt<0><<<dim3(13, 32), 256, 0, stream>>>(xsact, wbig, 4096, 1664, 1536, dbc, nullptr, nullptr, nullptr);
  scan_p1<<<6144, 256, 0, stream>>>(dbc, xsact, Alog, dtB, Pbuf, xres);
  scan_p2<<<384, 256, 0, stream>>>(Pbuf, xres);
  scan_p3<<<6144, 256, 0, stream>>>(dbc, xsact, xres, Alog, Dpar, dtB, Pbuf, ybuf);
  gemm_bt<1><<<dim3(6, 32), 256, 0, stream>>>(ybuf, wbO, 4096, 768, 1536, xbuf, nullptr, src, nullptr);

  // FFN block
  ln_kernel<<<1024, 256, 0, stream>>>(xbuf, n2g, n2b, hbf);
  gemm_bt<2><<<dim3(24, 32), 256, 0, stream>>>(hbf, wb1, 4096, 3072, 768, nullptr, ff1, nullptr, b1);
  gemm_bt<3><<<dim3(6, 32), 256, 0, stream>>>(ff1, wb2, 4096, 768, 3072, outp, nullptr, xbuf, b2);
}

// Round 3
// 367.460 us; speedup vs baseline: 2.9609x; 1.4798x over previous
//
#include <hip/hip_runtime.h>
#include <cstdint>
#include <cstddef>

typedef __attribute__((ext_vector_type(4))) float f32x4;
typedef __attribute__((ext_vector_type(8))) short s16x8;

#if __has_builtin(__builtin_amdgcn_exp2f)
#define EXP2F(x) __builtin_amdgcn_exp2f(x)
#else
#define EXP2F(x) __expf((x) * 0.6931471805599453f)
#endif
#if __has_builtin(__builtin_amdgcn_rcpf)
#define RCPF(x) __builtin_amdgcn_rcpf(x)
#else
#define RCPF(x) (1.0f / (x))
#endif

__device__ inline unsigned short f2b(float f) {
  union { float f; unsigned u; } c; c.f = f;
  return (unsigned short)((c.u + 0x7FFFu + ((c.u >> 16) & 1u)) >> 16);
}
__device__ inline float b2f(unsigned short u) {
  union { unsigned u; float f; } c; c.u = ((unsigned)u) << 16;
  return c.f;
}

__device__ inline void gload_lds16(const void* g, void* l) {
  __builtin_amdgcn_global_load_lds(
      (const __attribute__((address_space(1))) unsigned int*)g,
      (__attribute__((address_space(3))) unsigned int*)l, 16, 0, 0);
}

// map linear index j in [0, 1.57M) into the dead first-half columns of xres
// (rows 0..1023, cols 0..1535 are free after conv_silu consumed them)
__device__ inline size_t hole(int j) {
  int r = j / 1536;
  int c = j - r * 1536;
  return (size_t)r * 3072 + c;
}

// ---------------- fp32 -> bf16 convert (float4 per thread) ----------------
__global__ __launch_bounds__(256) void cvt_bf16_k(const float* __restrict__ in,
                                                  unsigned short* __restrict__ out,
                                                  int n4) {
  int i = blockIdx.x * 256 + threadIdx.x;
  if (i >= n4) return;
  float4 v = ((const float4*)in)[i];
  ushort4 o;
  o.x = f2b(v.x); o.y = f2b(v.y); o.z = f2b(v.z); o.w = f2b(v.w);
  ((ushort4*)out)[i] = o;
}

// ------- build combined weight: rows 0..1535 = dt_proj_w @ x_proj_w[:48]
// -------                        rows 1536..1663 = x_proj_w[48:80] then zeros
__global__ __launch_bounds__(256) void build_wbig(const float* __restrict__ xpw,
                                                  const float* __restrict__ dtw,
                                                  unsigned short* __restrict__ wbig) {
  int k = blockIdx.x * 256 + threadIdx.x;   // 0..1535
  int rowid = blockIdx.y;                   // 0..1663
  float v;
  if (rowid < 1536) {
    float s = 0.f;
    #pragma unroll 8
    for (int r = 0; r < 48; ++r)
      s = __builtin_fmaf(dtw[rowid * 48 + r], xpw[r * 1536 + k], s);
    v = s;
  } else {
    int rr = rowid - 1536;
    v = (rr < 32) ? xpw[(48 + rr) * 1536 + k] : 0.f;
  }
  wbig[(size_t)rowid * 1536 + k] = f2b(v);
}

// ---------------- LayerNorm over 768, one wave per row, bf16 out ----------
__global__ __launch_bounds__(256) void ln_kernel(const float* __restrict__ x,
                                                 const float* __restrict__ gam,
                                                 const float* __restrict__ bet,
                                                 unsigned short* __restrict__ out) {
  int w = threadIdx.x >> 6, lane = threadIdx.x & 63;
  size_t row = (size_t)blockIdx.x * 4 + w;
  const float4* xr = (const float4*)(x + row * 768);
  float4 v0 = xr[lane], v1 = xr[lane + 64], v2 = xr[lane + 128];
  float s = v0.x + v0.y + v0.z + v0.w + v1.x + v1.y + v1.z + v1.w +
            v2.x + v2.y + v2.z + v2.w;
  #pragma unroll
  for (int o = 32; o; o >>= 1) s += __shfl_xor(s, o);
  float mu = s * (1.f / 768.f);
  float q = 0.f;
  {
    float d;
    d = v0.x - mu; q += d * d; d = v0.y - mu; q += d * d;
    d = v0.z - mu; q += d * d; d = v0.w - mu; q += d * d;
    d = v1.x - mu; q += d * d; d = v1.y - mu; q += d * d;
    d = v1.z - mu; q += d * d; d = v1.w - mu; q += d * d;
    d = v2.x - mu; q += d * d; d = v2.y - mu; q += d * d;
    d = v2.z - mu; q += d * d; d = v2.w - mu; q += d * d;
  }
  #pragma unroll
  for (int o = 32; o; o >>= 1) q += __shfl_xor(q, o);
  float rs = rsqrtf(q * (1.f / 768.f) + 1e-5f);
  const float4* gr = (const float4*)gam;
  const float4* br = (const float4*)bet;
  ushort4* orow = (ushort4*)(out + row * 768);
  float4 vv[3] = {v0, v1, v2};
  #pragma unroll
  for (int i = 0; i < 3; ++i) {
    int c4 = lane + i * 64;
    float4 g4 = gr[c4], b4 = br[c4];
    ushort4 o;
    o.x = f2b((vv[i].x - mu) * rs * g4.x + b4.x);
    o.y = f2b((vv[i].y - mu) * rs * g4.y + b4.y);
    o.z = f2b((vv[i].z - mu) * rs * g4.z + b4.z);
    o.w = f2b((vv[i].w - mu) * rs * g4.w + b4.w);
    orow[c4] = o;
  }
}

// ---------------- causal depthwise conv(4) + bias + SiLU -> bf16 ----------
__global__ __launch_bounds__(256) void conv_silu(const float* __restrict__ xres,
                                                 const float* __restrict__ cw,
                                                 const float* __restrict__ cb,
                                                 unsigned short* __restrict__ xs_act) {
  int idx = blockIdx.x * 256 + threadIdx.x;  // 4096*384
  int t = idx / 384;
  int c4 = idx - t * 384;
  int pos = t & 1023;
  const float* base = xres + (size_t)t * 3072 + c4 * 4;
  float4 z = {0.f, 0.f, 0.f, 0.f};
  float4 x3 = *(const float4*)base;
  float4 x2 = (pos >= 1) ? *(const float4*)(base - 3072) : z;
  float4 x1 = (pos >= 2) ? *(const float4*)(base - 6144) : z;
  float4 x0 = (pos >= 3) ? *(const float4*)(base - 9216) : z;
  float a0[4] = {x0.x, x0.y, x0.z, x0.w};
  float a1[4] = {x1.x, x1.y, x1.z, x1.w};
  float a2[4] = {x2.x, x2.y, x2.z, x2.w};
  float a3[4] = {x3.x, x3.y, x3.z, x3.w};
  ushort4 o;
  unsigned short* op = &o.x;
  #pragma unroll
  for (int i = 0; i < 4; ++i) {
    int dd = c4 * 4 + i;
    float4 wv = *(const float4*)(cw + dd * 4);
    float v = wv.x * a0[i] + wv.y * a1[i] + wv.z * a2[i] + wv.w * a3[i] + cb[dd];
    float sv = v * RCPF(1.f + __expf(-v));
    op[i] = f2b(sv);
  }
  *(ushort4*)(xs_act + (size_t)t * 1536 + c4 * 4) = o;
}

// ================== chunked selective scan (16 chunks x 64 steps) =========
// New layout: one lane per (b, d, half-of-n). 8 n-states live in registers.
// block = 256 thr covers 128 d; grid = b(4) * dtile(12) * chunk(16) = 768.
// P1: from h=0 compute per-chunk decay products P[8] and local end h_end[8].
__global__ __launch_bounds__(256) void scan_p1(
    const float* __restrict__ dbc, const unsigned short* __restrict__ u_bf,
    const float* __restrict__ A_log, const float* __restrict__ dt_bias,
    float* __restrict__ P_buf, float* __restrict__ h_holes) {
  int tid = threadIdx.x;
  int dl = tid >> 1;
  int nh = (tid & 1) * 8;
  int blk = blockIdx.x;
  int c = blk & 15;
  int bt = blk >> 4;
  int b = bt / 12;
  int dtile = bt - b * 12;
  int d = dtile * 128 + dl;
  float bias = dt_bias[d];
  float Al2[8];
  {
    float4 a0 = *(const float4*)(A_log + d * 16 + nh);
    float4 a1 = *(const float4*)(A_log + d * 16 + nh + 4);
    const float L2E = 1.4426950408889634f;
    Al2[0] = -__expf(a0.x) * L2E; Al2[1] = -__expf(a0.y) * L2E;
    Al2[2] = -__expf(a0.z) * L2E; Al2[3] = -__expf(a0.w) * L2E;
    Al2[4] = -__expf(a1.x) * L2E; Al2[5] = -__expf(a1.y) * L2E;
    Al2[6] = -__expf(a1.z) * L2E; Al2[7] = -__expf(a1.w) * L2E;
  }
  const float* base_d = dbc + (size_t)b * 1024 * 1664 + d;
  const float* base_bc = dbc + (size_t)b * 1024 * 1664 + 1536 + nh;
  const unsigned short* ub = u_bf + (size_t)b * 1024 * 1536 + d;
  float h[8], P[8];
  #pragma unroll
  for (int k = 0; k < 8; ++k) { h[k] = 0.f; P[k] = 1.f; }
  int t0 = c * 64;
  #pragma unroll 2
  for (int s = 0; s < 64; ++s) {
    size_t t = t0 + s;
    float x = base_d[t * 1664] + bias;
    float dsp = (x > 20.f) ? x : __logf(1.f + __expf(x));
    float du = dsp * b2f(ub[t * 1536]);
    float4 B0 = *(const float4*)(base_bc + t * 1664);
    float4 B1 = *(const float4*)(base_bc + t * 1664 + 4);
    float Bv[8] = {B0.x, B0.y, B0.z, B0.w, B1.x, B1.y, B1.z, B1.w};
    #pragma unroll
    for (int k = 0; k < 8; ++k) {
      float dA = EXP2F(dsp * Al2[k]);
      h[k] = __builtin_fmaf(dA, h[k], du * Bv[k]);
      P[k] *= dA;
    }
  }
  int j = c * 98304 + (b * 1536 + d) * 16 + nh;
  *(float4*)(P_buf + j) = make_float4(P[0], P[1], P[2], P[3]);
  *(float4*)(P_buf + j + 4) = make_float4(P[4], P[5], P[6], P[7]);
  float* hp = h_holes + hole(j);
  *(float4*)hp = make_float4(h[0], h[1], h[2], h[3]);
  *(float4*)(hp + 4) = make_float4(h[4], h[5], h[6], h[7]);
}

// P2: per (b,d,n) combine the 16 chunks; store each chunk's true initial
// state H_{c-1} in-place over P_buf[c].
__global__ __launch_bounds__(256) void scan_p2(float* __restrict__ P_buf,
                                               const float* __restrict__ h_holes) {
  int i = blockIdx.x * 256 + threadIdx.x;  // [0, 98304)
  float H = 0.f;
  #pragma unroll
  for (int c = 0; c < 16; ++c) {
    int j = c * 98304 + i;
    float P = P_buf[j];
    float he = h_holes[hole(j)];
    P_buf[j] = H;
    H = __builtin_fmaf(P, H, he);
  }
}

// P3: replay each chunk from its true H_init; reduce over n in-register +
// one DPP-xor1 across the lane pair; fuse +u*D and *silu(res); bf16 y out.
__global__ __launch_bounds__(256) void scan_p3(
    const float* __restrict__ dbc, const unsigned short* __restrict__ u_bf,
    const float* __restrict__ xres, const float* __restrict__ A_log,
    const float* __restrict__ D_param, const float* __restrict__ dt_bias,
    const float* __restrict__ P_buf, unsigned short* __restrict__ y_out) {
  int tid = threadIdx.x;
  int dl = tid >> 1;
  int nh = (tid & 1) * 8;
  int blk = blockIdx.x;
  int c = blk & 15;
  int bt = blk >> 4;
  int b = bt / 12;
  int dtile = bt - b * 12;
  int d = dtile * 128 + dl;
  float bias = dt_bias[d];
  float Dp = D_param[d];
  float Al2[8];
  {
    float4 a0 = *(const float4*)(A_log + d * 16 + nh);
    float4 a1 = *(const float4*)(A_log + d * 16 + nh + 4);
    const float L2E = 1.4426950408889634f;
    Al2[0] = -__expf(a0.x) * L2E; Al2[1] = -__expf(a0.y) * L2E;
    Al2[2] = -__expf(a0.z) * L2E; Al2[3] = -__expf(a0.w) * L2E;
    Al2[4] = -__expf(a1.x) * L2E; Al2[5] = -__expf(a1.y) * L2E;
    Al2[6] = -__expf(a1.z) * L2E; Al2[7] = -__expf(a1.w) * L2E;
  }
  const float* base_d = dbc + (size_t)b * 1024 * 1664 + d;
  const float* base_bc = dbc + (size_t)b * 1024 * 1664 + 1536 + nh;
  const unsigned short* ub = u_bf + (size_t)b * 1024 * 1536 + d;
  const float* rbase = xres + (size_t)b * 1024 * 3072 + 1536 + d;
  unsigned short* yrow = y_out + (size_t)b * 1024 * 1536 + d;
  int j = c * 98304 + (b * 1536 + d) * 16 + nh;
  float h[8];
  {
    float4 h0 = *(const float4*)(P_buf + j);
    float4 h1 = *(const float4*)(P_buf + j + 4);
    h[0] = h0.x; h[1] = h0.y; h[2] = h0.z; h[3] = h0.w;
    h[4] = h1.x; h[5] = h1.y; h[6] = h1.z; h[7] = h1.w;
  }
  int t0 = c * 64;
  #pragma unroll 2
  for (int s = 0; s < 64; ++s) {
    size_t t = t0 + s;
    float x = base_d[t * 1664] + bias;
    float dsp = (x > 20.f) ? x : __logf(1.f + __expf(x));
    float ut = b2f(ub[t * 1536]);
    float du = dsp * ut;
    float4 B0 = *(const float4*)(base_bc + t * 1664);
    float4 B1 = *(const float4*)(base_bc + t * 1664 + 4);
    float4 C0 = *(const float4*)(base_bc + t * 1664 + 16);
    float4 C1 = *(const float4*)(base_bc + t * 1664 + 20);
    float Bv[8] = {B0.x, B0.y, B0.z, B0.w, B1.x, B1.y, B1.z, B1.w};
    float Cv[8] = {C0.x, C0.y, C0.z, C0.w, C1.x, C1.y, C1.z, C1.w};
    float p0 = 0.f, p1 = 0.f;
    #pragma unroll
    for (int k = 0; k < 8; ++k) {
      float dA = EXP2F(dsp * Al2[k]);
      h[k] = __builtin_fmaf(dA, h[k], du * Bv[k]);
      if (k & 1) p1 = __builtin_fmaf(h[k], Cv[k], p1);
      else       p0 = __builtin_fmaf(h[k], Cv[k], p0);
    }
    float p = p0 + p1;
    // add the partner lane's half (n 8..15 vs 0..7): quad_perm swap xor1
    p += __int_as_float(__builtin_amdgcn_update_dpp(
        0, __float_as_int(p), 0xB1, 0xF, 0xF, true));
    if (nh == 0) {
      float r = rbase[t * 3072];
      float sr = r * RCPF(1.f + __expf(-r));
      yrow[t * 1536] = f2b(__builtin_fmaf(ut, Dp, p) * sr);
    }
  }
}

// ---------------- bf16 MFMA GEMM: C(MxN) = A(MxK) @ B(NxK)^T -------------
// MODE 0: C fp32 = acc
// MODE 1: C fp32 = res + acc
// MODE 2: C bf16 = gelu_exact(acc + bias[col])
// MODE 3: C fp32 = res + bias[col] + acc
template <int MODE>
__global__ __launch_bounds__(256, 2) void gemm_bt(
    const unsigned short* __restrict__ A, const unsigned short* __restrict__ B,
    int M, int N, int K, float* __restrict__ Cf, unsigned short* __restrict__ Cb,
    const float* __restrict__ res, const float* __restrict__ bias) {
  __shared__ __align__(16) unsigned short As[128 * 32];
  __shared__ __align__(16) unsigned short Bs[128 * 32];
  int tid = threadIdx.x;
  int lane = tid & 63;
  int w = tid >> 6;
  int wm = w >> 1, wn = w & 1;
  int row0 = blockIdx.y * 128;
  int col0 = blockIdx.x * 128;
  const int lr = lane & 15;
  const int kb = lane >> 4;

  f32x4 acc[4][4];
  #pragma unroll
  for (int i = 0; i < 4; ++i)
    #pragma unroll
    for (int j = 0; j < 4; ++j) acc[i][j] = (f32x4)0.f;

  for (int k0 = 0; k0 < K; k0 += 32) {
    #pragma unroll
    for (int j = 0; j < 2; ++j) {
      int e = j * 256 + tid;
      int r = e >> 2, cc = e & 3;
      gload_lds16(A + (size_t)(row0 + r) * K + k0 + cc * 8, &As[e * 8]);
      gload_lds16(B + (size_t)(col0 + r) * K + k0 + cc * 8, &Bs[e * 8]);
    }
    __syncthreads();
    s16x8 af[4], bf[4];
    #pragma unroll
    for (int m = 0; m < 4; ++m)
      af[m] = *(const s16x8*)&As[(wm * 64 + m * 16 + lr) * 32 + kb * 8];
    #pragma unroll
    for (int nn = 0; nn < 4; ++nn)
      bf[nn] = *(const s16x8*)&Bs[(wn * 64 + nn * 16 + lr) * 32 + kb * 8];
    #pragma unroll
    for (int m = 0; m < 4; ++m)
      #pragma unroll
      for (int nn = 0; nn < 4; ++nn)
        acc[m][nn] = __builtin_amdgcn_mfma_f32_16x16x32_bf16(af[m], bf[nn], acc[m][nn], 0, 0, 0);
    __syncthreads();
  }

  #pragma unroll
  for (int m = 0; m < 4; ++m) {
    int rbase = row0 + wm * 64 + m * 16 + kb * 4;
    #pragma unroll
    for (int nn = 0; nn < 4; ++nn) {
      int col = col0 + wn * 64 + nn * 16 + lr;
      #pragma unroll
      for (int r = 0; r < 4; ++r) {
        int row = rbase + r;
        size_t idx = (size_t)row * N + col;
        float v = acc[m][nn][r];
        if (MODE == 0) {
          Cf[idx] = v;
        } else if (MODE == 1) {
          Cf[idx] = res[idx] + v;
        } else if (MODE == 2) {
          float tt = v + bias[col];
          float gl = 0.5f * tt * (1.f + erff(tt * 0.7071067811865475f));
          Cb[idx] = f2b(gl);
        } else {
          Cf[idx] = res[idx] + bias[col] + v;
        }
      }
    }
  }
}

extern "C" void kernel_launch(void* const* d_in, const int* in_sizes, int n_in,
                              void* d_out, int out_size, void* d_ws, size_t ws_size,
                              hipStream_t stream) {
  (void)in_sizes; (void)n_in; (void)out_size; (void)ws_size;
  const float* src   = (const float*)d_in[0];
  const float* n1g   = (const float*)d_in[1];
  const float* n1b   = (const float*)d_in[2];
  const float* inW   = (const float*)d_in[3];
  const float* convW = (const float*)d_in[4];
  const float* convB = (const float*)d_in[5];
  const float* xpW   = (const float*)d_in[6];
  const float* dtW   = (const float*)d_in[7];
  const float* dtB   = (const float*)d_in[8];
  const float* Alog  = (const float*)d_in[9];
  const float* Dpar  = (const float*)d_in[10];
  const float* outW  = (const float*)d_in[11];
  const float* n2g   = (const float*)d_in[12];
  const float* n2b   = (const float*)d_in[13];
  const float* w1    = (const float*)d_in[14];
  const float* b1    = (const float*)d_in[15];
  const float* w2    = (const float*)d_in[16];
  const float* b2    = (const float*)d_in[17];

  char* ws = (char*)d_ws;
  unsigned short* wbA  = (unsigned short*)(ws + 0);           // in_proj bf16  (3072x768)
  unsigned short* wbO  = (unsigned short*)(ws + 4718592);     // out_proj bf16 (768x1536)
  unsigned short* wb1  = (unsigned short*)(ws + 7077888);     // w1 bf16       (3072x768)
  unsigned short* wb2  = (unsigned short*)(ws + 11796480);    // w2 bf16       (768x3072)
  unsigned short* wbig = (unsigned short*)(ws + 16515072);    // (1664x1536) bf16
  unsigned short* hbf  = (unsigned short*)(ws + 21626880);    // (4096x768) bf16; reused as h2
  float*          Pbuf = (float*)(ws + 21626880);             // scan scratch: reuses hbf (dead between GEMM1 and LN2)
  float*          xres = (float*)(ws + 27918336);             // (4096x3072) fp32; first-half cols reused as scan h_end holes
  unsigned short* xsact= (unsigned short*)(ws + 78249984);    // (4096x1536) bf16
  float*          xbuf = (float*)(ws + 78249984);             // (4096x768) fp32 (reuse, after scan)
  float*          dbc  = (float*)(ws + 90832896);             // (4096x1664) fp32
  unsigned short* ff1  = (unsigned short*)(ws + 90832896);    // (4096x3072) bf16 (reuse, after scan)
  unsigned short* ybuf = (unsigned short*)(ws + 118095872);   // (4096x1536) bf16
  float* outp = (float*)d_out;

  // weight prep
  cvt_bf16_k<<<2304, 256, 0, stream>>>(inW, wbA, 589824);
  cvt_bf16_k<<<1152, 256, 0, stream>>>(outW, wbO, 294912);
  cvt_bf16_k<<<2304, 256, 0, stream>>>(w1, wb1, 589824);
  cvt_bf16_k<<<2304, 256, 0, stream>>>(w2, wb2, 589824);
  build_wbig<<<dim3(6, 1664), 256, 0, stream>>>(xpW, dtW, wbig);

  // mamba block
  ln_kernel<<<1024, 256, 0, stream>>>(src, n1g, n1b, hbf);
  gemm_bt<0><<<dim3(24, 32), 256, 0, stream>>>(hbf, wbA, 4096, 3072, 768, xres, nullptr, nullptr, nullptr);
  conv_silu<<<6144, 256, 0, stream>>>(xres, convW, convB, xsact);
  gemm_bt<0><<<dim3(13, 32), 256, 0, stream>>>(xsact, wbig, 4096, 1664, 1536, dbc, nullptr, nullptr, nullptr);
  scan_p1<<<768, 256, 0, stream>>>(dbc, xsact, Alog, dtB, Pbuf, xres);
  scan_p2<<<384, 256, 0, stream>>>(Pbuf, xres);
  scan_p3<<<768, 256, 0, stream>>>(dbc, xsact, xres, Alog, Dpar, dtB, Pbuf, ybuf);
  gemm_bt<1><<<dim3(6, 32), 256, 0, stream>>>(ybuf, wbO, 4096, 768, 1536, xbuf, nullptr, src, nullptr);

  // FFN block
  ln_kernel<<<1024, 256, 0, stream>>>(xbuf, n2g, n2b, hbf);
  gemm_bt<2><<<dim3(24, 32), 256, 0, stream>>>(hbf, wb1, 4096, 3072, 768, nullptr, ff1, nullptr, b1);
  gemm_bt<3><<<dim3(6, 32), 256, 0, stream>>>(ff1, wb2, 4096, 768, 3072, outp, nullptr, xbuf, b2);
}

// Round 4
// 348.524 us; speedup vs baseline: 3.1218x; 1.0543x over previous
//
#include <hip/hip_runtime.h>
#include <cstdint>
#include <cstddef>

typedef __attribute__((ext_vector_type(4))) float f32x4;
typedef __attribute__((ext_vector_type(8))) short s16x8;

#if __has_builtin(__builtin_amdgcn_exp2f)
#define EXP2F(x) __builtin_amdgcn_exp2f(x)
#else
#define EXP2F(x) __expf((x) * 0.6931471805599453f)
#endif
#if __has_builtin(__builtin_amdgcn_rcpf)
#define RCPF(x) __builtin_amdgcn_rcpf(x)
#else
#define RCPF(x) (1.0f / (x))
#endif

__device__ inline unsigned short f2b(float f) {
  union { float f; unsigned u; } c; c.f = f;
  return (unsigned short)((c.u + 0x7FFFu + ((c.u >> 16) & 1u)) >> 16);
}
__device__ inline float b2f(unsigned short u) {
  union { unsigned u; float f; } c; c.u = ((unsigned)u) << 16;
  return c.f;
}

__device__ inline void gload_lds16(const void* g, void* l) {
  __builtin_amdgcn_global_load_lds(
      (const __attribute__((address_space(1))) unsigned int*)g,
      (__attribute__((address_space(3))) unsigned int*)l, 16, 0, 0);
}

// map linear index j in [0, 1.57M) into the dead first-half columns of xres
__device__ inline size_t hole(int j) {
  int r = j / 1536;
  int c = j - r * 1536;
  return (size_t)r * 3072 + c;
}

// ------------- fused fp32 -> bf16 convert for the 4 weight tensors --------
__global__ __launch_bounds__(256) void cvt_all(const float* __restrict__ inW,
                                               const float* __restrict__ outW,
                                               const float* __restrict__ w1,
                                               const float* __restrict__ w2,
                                               unsigned short* __restrict__ wbA,
                                               unsigned short* __restrict__ wbO,
                                               unsigned short* __restrict__ wb1,
                                               unsigned short* __restrict__ wb2) {
  int i = blockIdx.x * 256 + threadIdx.x;  // [0, 2064384) float4 units
  const float* src;
  unsigned short* dst;
  int o;
  if (i < 589824)       { src = inW;  dst = wbA; o = i; }
  else if (i < 884736)  { src = outW; dst = wbO; o = i - 589824; }
  else if (i < 1474560) { src = w1;   dst = wb1; o = i - 884736; }
  else                  { src = w2;   dst = wb2; o = i - 1474560; }
  float4 v = ((const float4*)src)[o];
  ushort4 u;
  u.x = f2b(v.x); u.y = f2b(v.y); u.z = f2b(v.z); u.w = f2b(v.w);
  ((ushort4*)dst)[o] = u;
}

// ------- build combined weight: rows 0..1535 = dt_proj_w @ x_proj_w[:48]
// -------                        rows 1536..1663 = x_proj_w[48:80] then zeros
__global__ __launch_bounds__(256) void build_wbig(const float* __restrict__ xpw,
                                                  const float* __restrict__ dtw,
                                                  unsigned short* __restrict__ wbig) {
  int k = blockIdx.x * 256 + threadIdx.x;   // 0..1535
  int rowid = blockIdx.y;                   // 0..1663
  float v;
  if (rowid < 1536) {
    float s = 0.f;
    #pragma unroll 8
    for (int r = 0; r < 48; ++r)
      s = __builtin_fmaf(dtw[rowid * 48 + r], xpw[r * 1536 + k], s);
    v = s;
  } else {
    int rr = rowid - 1536;
    v = (rr < 32) ? xpw[(48 + rr) * 1536 + k] : 0.f;
  }
  wbig[(size_t)rowid * 1536 + k] = f2b(v);
}

// ---------------- LayerNorm over 768, one wave per row, bf16 out ----------
__global__ __launch_bounds__(256) void ln_kernel(const float* __restrict__ x,
                                                 const float* __restrict__ gam,
                                                 const float* __restrict__ bet,
                                                 unsigned short* __restrict__ out) {
  int w = threadIdx.x >> 6, lane = threadIdx.x & 63;
  size_t row = (size_t)blockIdx.x * 4 + w;
  const float4* xr = (const float4*)(x + row * 768);
  float4 v0 = xr[lane], v1 = xr[lane + 64], v2 = xr[lane + 128];
  float s = v0.x + v0.y + v0.z + v0.w + v1.x + v1.y + v1.z + v1.w +
            v2.x + v2.y + v2.z + v2.w;
  #pragma unroll
  for (int o = 32; o; o >>= 1) s += __shfl_xor(s, o);
  float mu = s * (1.f / 768.f);
  float q = 0.f;
  {
    float d;
    d = v0.x - mu; q += d * d; d = v0.y - mu; q += d * d;
    d = v0.z - mu; q += d * d; d = v0.w - mu; q += d * d;
    d = v1.x - mu; q += d * d; d = v1.y - mu; q += d * d;
    d = v1.z - mu; q += d * d; d = v1.w - mu; q += d * d;
    d = v2.x - mu; q += d * d; d = v2.y - mu; q += d * d;
    d = v2.z - mu; q += d * d; d = v2.w - mu; q += d * d;
  }
  #pragma unroll
  for (int o = 32; o; o >>= 1) q += __shfl_xor(q, o);
  float rs = rsqrtf(q * (1.f / 768.f) + 1e-5f);
  const float4* gr = (const float4*)gam;
  const float4* br = (const float4*)bet;
  ushort4* orow = (ushort4*)(out + row * 768);
  float4 vv[3] = {v0, v1, v2};
  #pragma unroll
  for (int i = 0; i < 3; ++i) {
    int c4 = lane + i * 64;
    float4 g4 = gr[c4], b4 = br[c4];
    ushort4 o;
    o.x = f2b((vv[i].x - mu) * rs * g4.x + b4.x);
    o.y = f2b((vv[i].y - mu) * rs * g4.y + b4.y);
    o.z = f2b((vv[i].z - mu) * rs * g4.z + b4.z);
    o.w = f2b((vv[i].w - mu) * rs * g4.w + b4.w);
    orow[c4] = o;
  }
}

// ---------------- causal depthwise conv(4) + bias + SiLU -> bf16 ----------
__global__ __launch_bounds__(256) void conv_silu(const float* __restrict__ xres,
                                                 const float* __restrict__ cw,
                                                 const float* __restrict__ cb,
                                                 unsigned short* __restrict__ xs_act) {
  int idx = blockIdx.x * 256 + threadIdx.x;  // 4096*384
  int t = idx / 384;
  int c4 = idx - t * 384;
  int pos = t & 1023;
  const float* base = xres + (size_t)t * 3072 + c4 * 4;
  float4 z = {0.f, 0.f, 0.f, 0.f};
  float4 x3 = *(const float4*)base;
  float4 x2 = (pos >= 1) ? *(const float4*)(base - 3072) : z;
  float4 x1 = (pos >= 2) ? *(const float4*)(base - 6144) : z;
  float4 x0 = (pos >= 3) ? *(const float4*)(base - 9216) : z;
  float a0[4] = {x0.x, x0.y, x0.z, x0.w};
  float a1[4] = {x1.x, x1.y, x1.z, x1.w};
  float a2[4] = {x2.x, x2.y, x2.z, x2.w};
  float a3[4] = {x3.x, x3.y, x3.z, x3.w};
  ushort4 o;
  unsigned short* op = &o.x;
  #pragma unroll
  for (int i = 0; i < 4; ++i) {
    int dd = c4 * 4 + i;
    float4 wv = *(const float4*)(cw + dd * 4);
    float v = wv.x * a0[i] + wv.y * a1[i] + wv.z * a2[i] + wv.w * a3[i] + cb[dd];
    float sv = v * RCPF(1.f + __expf(-v));
    op[i] = f2b(sv);
  }
  *(ushort4*)(xs_act + (size_t)t * 1536 + c4 * 4) = o;
}

// ================== chunked selective scan (16 chunks x 64 steps) =========
__global__ __launch_bounds__(256) void scan_p1(
    const float* __restrict__ dbc, const unsigned short* __restrict__ u_bf,
    const float* __restrict__ A_log, const float* __restrict__ dt_bias,
    float* __restrict__ P_buf, float* __restrict__ h_holes) {
  int tid = threadIdx.x;
  int dl = tid >> 1;
  int nh = (tid & 1) * 8;
  int blk = blockIdx.x;
  int c = blk & 15;
  int bt = blk >> 4;
  int b = bt / 12;
  int dtile = bt - b * 12;
  int d = dtile * 128 + dl;
  float bias = dt_bias[d];
  float Al2[8];
  {
    float4 a0 = *(const float4*)(A_log + d * 16 + nh);
    float4 a1 = *(const float4*)(A_log + d * 16 + nh + 4);
    const float L2E = 1.4426950408889634f;
    Al2[0] = -__expf(a0.x) * L2E; Al2[1] = -__expf(a0.y) * L2E;
    Al2[2] = -__expf(a0.z) * L2E; Al2[3] = -__expf(a0.w) * L2E;
    Al2[4] = -__expf(a1.x) * L2E; Al2[5] = -__expf(a1.y) * L2E;
    Al2[6] = -__expf(a1.z) * L2E; Al2[7] = -__expf(a1.w) * L2E;
  }
  const float* base_d = dbc + (size_t)b * 1024 * 1664 + d;
  const float* base_bc = dbc + (size_t)b * 1024 * 1664 + 1536 + nh;
  const unsigned short* ub = u_bf + (size_t)b * 1024 * 1536 + d;
  float h[8], P[8];
  #pragma unroll
  for (int k = 0; k < 8; ++k) { h[k] = 0.f; P[k] = 1.f; }
  int t0 = c * 64;
  #pragma unroll 2
  for (int s = 0; s < 64; ++s) {
    size_t t = t0 + s;
    float x = base_d[t * 1664] + bias;
    float dsp = (x > 20.f) ? x : __logf(1.f + __expf(x));
    float du = dsp * b2f(ub[t * 1536]);
    float4 B0 = *(const float4*)(base_bc + t * 1664);
    float4 B1 = *(const float4*)(base_bc + t * 1664 + 4);
    float Bv[8] = {B0.x, B0.y, B0.z, B0.w, B1.x, B1.y, B1.z, B1.w};
    #pragma unroll
    for (int k = 0; k < 8; ++k) {
      float dA = EXP2F(dsp * Al2[k]);
      h[k] = __builtin_fmaf(dA, h[k], du * Bv[k]);
      P[k] *= dA;
    }
  }
  int j = c * 98304 + (b * 1536 + d) * 16 + nh;
  *(float4*)(P_buf + j) = make_float4(P[0], P[1], P[2], P[3]);
  *(float4*)(P_buf + j + 4) = make_float4(P[4], P[5], P[6], P[7]);
  float* hp = h_holes + hole(j);
  *(float4*)hp = make_float4(h[0], h[1], h[2], h[3]);
  *(float4*)(hp + 4) = make_float4(h[4], h[5], h[6], h[7]);
}

__global__ __launch_bounds__(256) void scan_p2(float* __restrict__ P_buf,
                                               const float* __restrict__ h_holes) {
  int i = blockIdx.x * 256 + threadIdx.x;  // [0, 98304)
  float H = 0.f;
  #pragma unroll
  for (int c = 0; c < 16; ++c) {
    int j = c * 98304 + i;
    float P = P_buf[j];
    float he = h_holes[hole(j)];
    P_buf[j] = H;
    H = __builtin_fmaf(P, H, he);
  }
}

__global__ __launch_bounds__(256) void scan_p3(
    const float* __restrict__ dbc, const unsigned short* __restrict__ u_bf,
    const float* __restrict__ xres, const float* __restrict__ A_log,
    const float* __restrict__ D_param, const float* __restrict__ dt_bias,
    const float* __restrict__ P_buf, unsigned short* __restrict__ y_out) {
  int tid = threadIdx.x;
  int dl = tid >> 1;
  int nh = (tid & 1) * 8;
  int blk = blockIdx.x;
  int c = blk & 15;
  int bt = blk >> 4;
  int b = bt / 12;
  int dtile = bt - b * 12;
  int d = dtile * 128 + dl;
  float bias = dt_bias[d];
  float Dp = D_param[d];
  float Al2[8];
  {
    float4 a0 = *(const float4*)(A_log + d * 16 + nh);
    float4 a1 = *(const float4*)(A_log + d * 16 + nh + 4);
    const float L2E = 1.4426950408889634f;
    Al2[0] = -__expf(a0.x) * L2E; Al2[1] = -__expf(a0.y) * L2E;
    Al2[2] = -__expf(a0.z) * L2E; Al2[3] = -__expf(a0.w) * L2E;
    Al2[4] = -__expf(a1.x) * L2E; Al2[5] = -__expf(a1.y) * L2E;
    Al2[6] = -__expf(a1.z) * L2E; Al2[7] = -__expf(a1.w) * L2E;
  }
  const float* base_d = dbc + (size_t)b * 1024 * 1664 + d;
  const float* base_bc = dbc + (size_t)b * 1024 * 1664 + 1536 + nh;
  const unsigned short* ub = u_bf + (size_t)b * 1024 * 1536 + d;
  const float* rbase = xres + (size_t)b * 1024 * 3072 + 1536 + d;
  unsigned short* yrow = y_out + (size_t)b * 1024 * 1536 + d;
  int j = c * 98304 + (b * 1536 + d) * 16 + nh;
  float h[8];
  {
    float4 h0 = *(const float4*)(P_buf + j);
    float4 h1 = *(const float4*)(P_buf + j + 4);
    h[0] = h0.x; h[1] = h0.y; h[2] = h0.z; h[3] = h0.w;
    h[4] = h1.x; h[5] = h1.y; h[6] = h1.z; h[7] = h1.w;
  }
  int t0 = c * 64;
  #pragma unroll 2
  for (int s = 0; s < 64; ++s) {
    size_t t = t0 + s;
    float x = base_d[t * 1664] + bias;
    float dsp = (x > 20.f) ? x : __logf(1.f + __expf(x));
    float ut = b2f(ub[t * 1536]);
    float du = dsp * ut;
    float4 B0 = *(const float4*)(base_bc + t * 1664);
    float4 B1 = *(const float4*)(base_bc + t * 1664 + 4);
    float4 C0 = *(const float4*)(base_bc + t * 1664 + 16);
    float4 C1 = *(const float4*)(base_bc + t * 1664 + 20);
    float Bv[8] = {B0.x, B0.y, B0.z, B0.w, B1.x, B1.y, B1.z, B1.w};
    float Cv[8] = {C0.x, C0.y, C0.z, C0.w, C1.x, C1.y, C1.z, C1.w};
    float p0 = 0.f, p1 = 0.f;
    #pragma unroll
    for (int k = 0; k < 8; ++k) {
      float dA = EXP2F(dsp * Al2[k]);
      h[k] = __builtin_fmaf(dA, h[k], du * Bv[k]);
      if (k & 1) p1 = __builtin_fmaf(h[k], Cv[k], p1);
      else       p0 = __builtin_fmaf(h[k], Cv[k], p0);
    }
    float p = p0 + p1;
    p += __int_as_float(__builtin_amdgcn_update_dpp(
        0, __float_as_int(p), 0xB1, 0xF, 0xF, true));
    if (nh == 0) {
      float r = rbase[t * 3072];
      float sr = r * RCPF(1.f + __expf(-r));
      yrow[t * 1536] = f2b(__builtin_fmaf(ut, Dp, p) * sr);
    }
  }
}

// ------------- bf16 MFMA GEMM: C(MxN) = A(MxK) @ B(NxK)^T ----------------
// Double-buffered LDS, prefetch-before-compute, XOR-swizzled staging.
// BM in {128, 64}; BN fixed 128. BM=128: 2x2 waves of 64x64. BM=64: 1x4
// waves of 64x32.
// MODE 0: C fp32 = acc            MODE 1: C fp32 = res + acc
// MODE 2: C bf16 = gelu(acc+b)    MODE 3: C fp32 = res + bias + acc
template <int MODE, int BM>
__global__ __launch_bounds__(256, 2) void gemm_bt(
    const unsigned short* __restrict__ A, const unsigned short* __restrict__ B,
    int M, int N, int K, float* __restrict__ Cf, unsigned short* __restrict__ Cb,
    const float* __restrict__ res, const float* __restrict__ bias) {
  constexpr int NFR = (BM == 128) ? 4 : 2;   // B frags per wave
  constexpr int AIT = BM / 64;               // A staging instrs per thread
  __shared__ __align__(16) unsigned short As[2][BM * 32];
  __shared__ __align__(16) unsigned short Bs[2][128 * 32];
  int tid = threadIdx.x;
  int lane = tid & 63;
  int w = tid >> 6;
  int wm = (BM == 128) ? (w >> 1) : 0;
  int wn = (BM == 128) ? (w & 1) : w;
  int row0 = blockIdx.y * BM;
  int col0 = blockIdx.x * 128;
  const int lr = lane & 15;
  const int kb = lane >> 4;

  f32x4 acc[4][NFR];
  #pragma unroll
  for (int i = 0; i < 4; ++i)
    #pragma unroll
    for (int j = 0; j < NFR; ++j) acc[i][j] = (f32x4)0.f;

  auto stage = [&](int buf, int k0) {
    #pragma unroll
    for (int j = 0; j < AIT; ++j) {
      int e = j * 256 + tid;
      int r = e >> 2, cc = e & 3;
      int sc = cc ^ ((r >> 1) & 3);
      gload_lds16(A + (size_t)(row0 + r) * K + k0 + sc * 8, &As[buf][e * 8]);
    }
    #pragma unroll
    for (int j = 0; j < 2; ++j) {
      int e = j * 256 + tid;
      int r = e >> 2, cc = e & 3;
      int sc = cc ^ ((r >> 1) & 3);
      gload_lds16(B + (size_t)(col0 + r) * K + k0 + sc * 8, &Bs[buf][e * 8]);
    }
  };

  stage(0, 0);
  __syncthreads();

  int nt = K >> 5;
  int cur = 0;
  for (int t = 0; t < nt; ++t) {
    if (t + 1 < nt) stage(cur ^ 1, (t + 1) << 5);
    s16x8 af[4], bfm[NFR];
    #pragma unroll
    for (int m = 0; m < 4; ++m) {
      int rr = wm * 64 + m * 16 + lr;
      int chunk = rr * 4 + (kb ^ ((rr >> 1) & 3));
      af[m] = *(const s16x8*)&As[cur][chunk * 8];
    }
    #pragma unroll
    for (int nn = 0; nn < NFR; ++nn) {
      int rr = wn * (16 * NFR) + nn * 16 + lr;
      int chunk = rr * 4 + (kb ^ ((rr >> 1) & 3));
      bfm[nn] = *(const s16x8*)&Bs[cur][chunk * 8];
    }
    #pragma unroll
    for (int m = 0; m < 4; ++m)
      #pragma unroll
      for (int nn = 0; nn < NFR; ++nn)
        acc[m][nn] = __builtin_amdgcn_mfma_f32_16x16x32_bf16(af[m], bfm[nn], acc[m][nn], 0, 0, 0);
    __syncthreads();
    cur ^= 1;
  }

  #pragma unroll
  for (int m = 0; m < 4; ++m) {
    int rbase = row0 + wm * 64 + m * 16 + kb * 4;
    #pragma unroll
    for (int nn = 0; nn < NFR; ++nn) {
      int col = col0 + wn * (16 * NFR) + nn * 16 + lr;
      #pragma unroll
      for (int r = 0; r < 4; ++r) {
        int row = rbase + r;
        size_t idx = (size_t)row * N + col;
        float v = acc[m][nn][r];
        if (MODE == 0) {
          Cf[idx] = v;
        } else if (MODE == 1) {
          Cf[idx] = res[idx] + v;
        } else if (MODE == 2) {
          float tt = v + bias[col];
          float gl = 0.5f * tt * (1.f + erff(tt * 0.7071067811865475f));
          Cb[idx] = f2b(gl);
        } else {
          Cf[idx] = res[idx] + bias[col] + v;
        }
      }
    }
  }
}

extern "C" void kernel_launch(void* const* d_in, const int* in_sizes, int n_in,
                              void* d_out, int out_size, void* d_ws, size_t ws_size,
                              hipStream_t stream) {
  (void)in_sizes; (void)n_in; (void)out_size; (void)ws_size;
  const float* src   = (const float*)d_in[0];
  const float* n1g   = (const float*)d_in[1];
  const float* n1b   = (const float*)d_in[2];
  const float* inW   = (const float*)d_in[3];
  const float* convW = (const float*)d_in[4];
  const float* convB = (const float*)d_in[5];
  const float* xpW   = (const float*)d_in[6];
  const float* dtW   = (const float*)d_in[7];
  const float* dtB   = (const float*)d_in[8];
  const float* Alog  = (const float*)d_in[9];
  const float* Dpar  = (const float*)d_in[10];
  const float* outW  = (const float*)d_in[11];
  const float* n2g   = (const float*)d_in[12];
  const float* n2b   = (const float*)d_in[13];
  const float* w1    = (const float*)d_in[14];
  const float* b1    = (const float*)d_in[15];
  const float* w2    = (const float*)d_in[16];
  const float* b2    = (const float*)d_in[17];

  char* ws = (char*)d_ws;
  unsigned short* wbA  = (unsigned short*)(ws + 0);           // in_proj bf16  (3072x768)
  unsigned short* wbO  = (unsigned short*)(ws + 4718592);     // out_proj bf16 (768x1536)
  unsigned short* wb1  = (unsigned short*)(ws + 7077888);     // w1 bf16       (3072x768)
  unsigned short* wb2  = (unsigned short*)(ws + 11796480);    // w2 bf16       (768x3072)
  unsigned short* wbig = (unsigned short*)(ws + 16515072);    // (1664x1536) bf16
  unsigned short* hbf  = (unsigned short*)(ws + 21626880);    // (4096x768) bf16; reused as h2
  float*          Pbuf = (float*)(ws + 21626880);             // scan scratch (dead hbf window)
  float*          xres = (float*)(ws + 27918336);             // (4096x3072) fp32; dead half = scan holes
  unsigned short* xsact= (unsigned short*)(ws + 78249984);    // (4096x1536) bf16
  float*          xbuf = (float*)(ws + 78249984);             // (4096x768) fp32 (reuse, after scan)
  float*          dbc  = (float*)(ws + 90832896);             // (4096x1664) fp32
  unsigned short* ff1  = (unsigned short*)(ws + 90832896);    // (4096x3072) bf16 (reuse, after scan)
  unsigned short* ybuf = (unsigned short*)(ws + 118095872);   // (4096x1536) bf16
  float* outp = (float*)d_out;

  // weight prep
  cvt_all<<<8064, 256, 0, stream>>>(inW, outW, w1, w2, wbA, wbO, wb1, wb2);
  build_wbig<<<dim3(6, 1664), 256, 0, stream>>>(xpW, dtW, wbig);

  // mamba block
  ln_kernel<<<1024, 256, 0, stream>>>(src, n1g, n1b, hbf);
  gemm_bt<0, 128><<<dim3(24, 32), 256, 0, stream>>>(hbf, wbA, 4096, 3072, 768, xres, nullptr, nullptr, nullptr);
  conv_silu<<<6144, 256, 0, stream>>>(xres, convW, convB, xsact);
  gemm_bt<0, 64><<<dim3(13, 64), 256, 0, stream>>>(xsact, wbig, 4096, 1664, 1536, dbc, nullptr, nullptr, nullptr);
  scan_p1<<<768, 256, 0, stream>>>(dbc, xsact, Alog, dtB, Pbuf, xres);
  scan_p2<<<384, 256, 0, stream>>>(Pbuf, xres);
  scan_p3<<<768, 256, 0, stream>>>(dbc, xsact, xres, Alog, Dpar, dtB, Pbuf, ybuf);
  gemm_bt<1, 64><<<dim3(6, 64), 256, 0, stream>>>(ybuf, wbO, 4096, 768, 1536, xbuf, nullptr, src, nullptr);

  // FFN block
  ln_kernel<<<1024, 256, 0, stream>>>(xbuf, n2g, n2b, hbf);
  gemm_bt<2, 128><<<dim3(24, 32), 256, 0, stream>>>(hbf, wb1, 4096, 3072, 768, nullptr, ff1, nullptr, b1);
  gemm_bt<3, 64><<<dim3(6, 64), 256, 0, stream>>>(ff1, wb2, 4096, 768, 3072, outp, nullptr, xbuf, b2);
}

// Round 5
// 328.433 us; speedup vs baseline: 3.3128x; 1.0612x over previous
//
#include <hip/hip_runtime.h>
#include <cstdint>
#include <cstddef>

typedef __attribute__((ext_vector_type(4))) float f32x4;
typedef __attribute__((ext_vector_type(8))) short s16x8;

#if __has_builtin(__builtin_amdgcn_exp2f)
#define EXP2F(x) __builtin_amdgcn_exp2f(x)
#else
#define EXP2F(x) __expf((x) * 0.6931471805599453f)
#endif
#if __has_builtin(__builtin_amdgcn_rcpf)
#define RCPF(x) __builtin_amdgcn_rcpf(x)
#else
#define RCPF(x) (1.0f / (x))
#endif

__device__ inline unsigned short f2b(float f) {
  union { float f; unsigned u; } c; c.f = f;
  return (unsigned short)((c.u + 0x7FFFu + ((c.u >> 16) & 1u)) >> 16);
}
__device__ inline float b2f(unsigned short u) {
  union { unsigned u; float f; } c; c.u = ((unsigned)u) << 16;
  return c.f;
}

__device__ inline void gload_lds16(const void* g, void* l) {
  __builtin_amdgcn_global_load_lds(
      (const __attribute__((address_space(1))) unsigned int*)g,
      (__attribute__((address_space(3))) unsigned int*)l, 16, 0, 0);
}

// Scan scratch lives in the dead first-half columns of xres (cols 0..1535,
// all 4096 rows are dead after conv_silu). j in [0, 3.15M) -> P slot;
// +HOLE2 -> h_end slot (rows 2048..4095).
#define HOLE2 6291456
__device__ inline size_t hole(int j) {
  int r = j / 1536;
  int c = j - r * 1536;
  return (size_t)r * 3072 + c;
}

// ------------- fused fp32 -> bf16 convert for the 4 weight tensors --------
__global__ __launch_bounds__(256) void cvt_all(const float* __restrict__ inW,
                                               const float* __restrict__ outW,
                                               const float* __restrict__ w1,
                                               const float* __restrict__ w2,
                                               unsigned short* __restrict__ wbA,
                                               unsigned short* __restrict__ wbO,
                                               unsigned short* __restrict__ wb1,
                                               unsigned short* __restrict__ wb2) {
  int i = blockIdx.x * 256 + threadIdx.x;  // [0, 2064384) float4 units
  const float* src;
  unsigned short* dst;
  int o;
  if (i < 589824)       { src = inW;  dst = wbA; o = i; }
  else if (i < 884736)  { src = outW; dst = wbO; o = i - 589824; }
  else if (i < 1474560) { src = w1;   dst = wb1; o = i - 884736; }
  else                  { src = w2;   dst = wb2; o = i - 1474560; }
  float4 v = ((const float4*)src)[o];
  ushort4 u;
  u.x = f2b(v.x); u.y = f2b(v.y); u.z = f2b(v.z); u.w = f2b(v.w);
  ((ushort4*)dst)[o] = u;
}

// ------- build combined weight: rows 0..1535 = dt_proj_w @ x_proj_w[:48]
// -------                        rows 1536..1663 = x_proj_w[48:80] then zeros
__global__ __launch_bounds__(256) void build_wbig(const float* __restrict__ xpw,
                                                  const float* __restrict__ dtw,
                                                  unsigned short* __restrict__ wbig) {
  int k = blockIdx.x * 256 + threadIdx.x;   // 0..1535
  int rowid = blockIdx.y;                   // 0..1663
  float v;
  if (rowid < 1536) {
    float s = 0.f;
    #pragma unroll 8
    for (int r = 0; r < 48; ++r)
      s = __builtin_fmaf(dtw[rowid * 48 + r], xpw[r * 1536 + k], s);
    v = s;
  } else {
    int rr = rowid - 1536;
    v = (rr < 32) ? xpw[(48 + rr) * 1536 + k] : 0.f;
  }
  wbig[(size_t)rowid * 1536 + k] = f2b(v);
}

// ---------------- LayerNorm over 768, one wave per row, bf16 out ----------
__global__ __launch_bounds__(256) void ln_kernel(const float* __restrict__ x,
                                                 const float* __restrict__ gam,
                                                 const float* __restrict__ bet,
                                                 unsigned short* __restrict__ out) {
  int w = threadIdx.x >> 6, lane = threadIdx.x & 63;
  size_t row = (size_t)blockIdx.x * 4 + w;
  const float4* xr = (const float4*)(x + row * 768);
  float4 v0 = xr[lane], v1 = xr[lane + 64], v2 = xr[lane + 128];
  float s = v0.x + v0.y + v0.z + v0.w + v1.x + v1.y + v1.z + v1.w +
            v2.x + v2.y + v2.z + v2.w;
  #pragma unroll
  for (int o = 32; o; o >>= 1) s += __shfl_xor(s, o);
  float mu = s * (1.f / 768.f);
  float q = 0.f;
  {
    float d;
    d = v0.x - mu; q += d * d; d = v0.y - mu; q += d * d;
    d = v0.z - mu; q += d * d; d = v0.w - mu; q += d * d;
    d = v1.x - mu; q += d * d; d = v1.y - mu; q += d * d;
    d = v1.z - mu; q += d * d; d = v1.w - mu; q += d * d;
    d = v2.x - mu; q += d * d; d = v2.y - mu; q += d * d;
    d = v2.z - mu; q += d * d; d = v2.w - mu; q += d * d;
  }
  #pragma unroll
  for (int o = 32; o; o >>= 1) q += __shfl_xor(q, o);
  float rs = rsqrtf(q * (1.f / 768.f) + 1e-5f);
  const float4* gr = (const float4*)gam;
  const float4* br = (const float4*)bet;
  ushort4* orow = (ushort4*)(out + row * 768);
  float4 vv[3] = {v0, v1, v2};
  #pragma unroll
  for (int i = 0; i < 3; ++i) {
    int c4 = lane + i * 64;
    float4 g4 = gr[c4], b4 = br[c4];
    ushort4 o;
    o.x = f2b((vv[i].x - mu) * rs * g4.x + b4.x);
    o.y = f2b((vv[i].y - mu) * rs * g4.y + b4.y);
    o.z = f2b((vv[i].z - mu) * rs * g4.z + b4.z);
    o.w = f2b((vv[i].w - mu) * rs * g4.w + b4.w);
    orow[c4] = o;
  }
}

// ---------------- causal depthwise conv(4) + bias + SiLU -> bf16 ----------
__global__ __launch_bounds__(256) void conv_silu(const float* __restrict__ xres,
                                                 const float* __restrict__ cw,
                                                 const float* __restrict__ cb,
                                                 unsigned short* __restrict__ xs_act) {
  int idx = blockIdx.x * 256 + threadIdx.x;  // 4096*384
  int t = idx / 384;
  int c4 = idx - t * 384;
  int pos = t & 1023;
  const float* base = xres + (size_t)t * 3072 + c4 * 4;
  float4 z = {0.f, 0.f, 0.f, 0.f};
  float4 x3 = *(const float4*)base;
  float4 x2 = (pos >= 1) ? *(const float4*)(base - 3072) : z;
  float4 x1 = (pos >= 2) ? *(const float4*)(base - 6144) : z;
  float4 x0 = (pos >= 3) ? *(const float4*)(base - 9216) : z;
  float a0[4] = {x0.x, x0.y, x0.z, x0.w};
  float a1[4] = {x1.x, x1.y, x1.z, x1.w};
  float a2[4] = {x2.x, x2.y, x2.z, x2.w};
  float a3[4] = {x3.x, x3.y, x3.z, x3.w};
  ushort4 o;
  unsigned short* op = &o.x;
  #pragma unroll
  for (int i = 0; i < 4; ++i) {
    int dd = c4 * 4 + i;
    float4 wv = *(const float4*)(cw + dd * 4);
    float v = wv.x * a0[i] + wv.y * a1[i] + wv.z * a2[i] + wv.w * a3[i] + cb[dd];
    float sv = v * RCPF(1.f + __expf(-v));
    op[i] = f2b(sv);
  }
  *(ushort4*)(xs_act + (size_t)t * 1536 + c4 * 4) = o;
}

// ================== chunked selective scan (32 chunks x 32 steps) =========
// dbc cols 0..1535 hold dsp = softplus(delta + dt_bias) (GEMM MODE 4).
// Lane layout: 2 lanes per d, 8 n-states in registers per lane.
// grid = b(4) * dtile(12) * chunk(32) = 1536 blocks.
__global__ __launch_bounds__(256) void scan_p1(
    const float* __restrict__ dbc, const unsigned short* __restrict__ u_bf,
    const float* __restrict__ A_log, float* __restrict__ xdead) {
  int tid = threadIdx.x;
  int dl = tid >> 1;
  int nh = (tid & 1) * 8;
  int blk = blockIdx.x;
  int c = blk & 31;
  int bt = blk >> 5;
  int b = bt / 12;
  int dtile = bt - b * 12;
  int d = dtile * 128 + dl;
  float Al2[8];
  {
    float4 a0 = *(const float4*)(A_log + d * 16 + nh);
    float4 a1 = *(const float4*)(A_log + d * 16 + nh + 4);
    const float L2E = 1.4426950408889634f;
    Al2[0] = -__expf(a0.x) * L2E; Al2[1] = -__expf(a0.y) * L2E;
    Al2[2] = -__expf(a0.z) * L2E; Al2[3] = -__expf(a0.w) * L2E;
    Al2[4] = -__expf(a1.x) * L2E; Al2[5] = -__expf(a1.y) * L2E;
    Al2[6] = -__expf(a1.z) * L2E; Al2[7] = -__expf(a1.w) * L2E;
  }
  const float* base_d = dbc + (size_t)b * 1024 * 1664 + d;
  const float* base_bc = dbc + (size_t)b * 1024 * 1664 + 1536 + nh;
  const unsigned short* ub = u_bf + (size_t)b * 1024 * 1536 + d;
  float h[8];
  #pragma unroll
  for (int k = 0; k < 8; ++k) h[k] = 0.f;
  float S = 0.f;
  int t0 = c * 32;
  // 1-deep software pipeline, even/odd bodies (static regs)
  float dspA = base_d[(size_t)t0 * 1664];
  float utA = b2f(ub[(size_t)t0 * 1536]);
  float4 B0A = *(const float4*)(base_bc + (size_t)t0 * 1664);
  float4 B1A = *(const float4*)(base_bc + (size_t)t0 * 1664 + 4);
  float dspB, utB;
  float4 B0B, B1B;
#define P1_BODY(DSP, UT, B0, B1)                                   \
  {                                                                \
    S += DSP;                                                      \
    float du = DSP * UT;                                           \
    float Bv[8] = {B0.x, B0.y, B0.z, B0.w, B1.x, B1.y, B1.z, B1.w};\
    _Pragma("unroll")                                              \
    for (int k = 0; k < 8; ++k) {                                  \
      float dA = EXP2F(DSP * Al2[k]);                              \
      h[k] = __builtin_fmaf(dA, h[k], du * Bv[k]);                 \
    }                                                              \
  }
  for (int s = 0; s < 32; s += 2) {
    size_t t1 = t0 + s + 1;
    dspB = base_d[t1 * 1664];
    utB = b2f(ub[t1 * 1536]);
    B0B = *(const float4*)(base_bc + t1 * 1664);
    B1B = *(const float4*)(base_bc + t1 * 1664 + 4);
    P1_BODY(dspA, utA, B0A, B1A);
    int t2i = t0 + s + 2; if (t2i > 1023) t2i = 1023;
    size_t t2 = t2i;
    dspA = base_d[t2 * 1664];
    utA = b2f(ub[t2 * 1536]);
    B0A = *(const float4*)(base_bc + t2 * 1664);
    B1A = *(const float4*)(base_bc + t2 * 1664 + 4);
    P1_BODY(dspB, utB, B0B, B1B);
  }
#undef P1_BODY
  int j = c * 98304 + (b * 1536 + d) * 16 + nh;
  size_t hp = hole(j);
  // P_k = exp2(Al2_k * sum(dsp)) : log-domain chunk decay product
  xdead[hp]     = EXP2F(Al2[0] * S);
  xdead[hp + 1] = EXP2F(Al2[1] * S);
  xdead[hp + 2] = EXP2F(Al2[2] * S);
  xdead[hp + 3] = EXP2F(Al2[3] * S);
  xdead[hp + 4] = EXP2F(Al2[4] * S);
  xdead[hp + 5] = EXP2F(Al2[5] * S);
  xdead[hp + 6] = EXP2F(Al2[6] * S);
  xdead[hp + 7] = EXP2F(Al2[7] * S);
  float* he = xdead + hp + HOLE2;
  *(float4*)he = make_float4(h[0], h[1], h[2], h[3]);
  *(float4*)(he + 4) = make_float4(h[4], h[5], h[6], h[7]);
}

// P2: per (b,d,n) combine 32 chunks; store each chunk's true initial state
// in-place over the P slot.
__global__ __launch_bounds__(256) void scan_p2(float* __restrict__ xdead) {
  int i = blockIdx.x * 256 + threadIdx.x;  // [0, 98304)
  float H = 0.f;
  #pragma unroll
  for (int c = 0; c < 32; ++c) {
    int j = c * 98304 + i;
    size_t hp = hole(j);
    float P = xdead[hp];
    float he = xdead[hp + HOLE2];
    xdead[hp] = H;
    H = __builtin_fmaf(P, H, he);
  }
}

// P3: replay each chunk from its true H_init; reduce over n in-register +
// one DPP-xor1 across the lane pair; fuse +u*D and *silu(res); bf16 y out.
__global__ __launch_bounds__(256) void scan_p3(
    const float* __restrict__ dbc, const unsigned short* __restrict__ u_bf,
    const float* __restrict__ xres, const float* __restrict__ A_log,
    const float* __restrict__ D_param, unsigned short* __restrict__ y_out) {
  int tid = threadIdx.x;
  int dl = tid >> 1;
  int nh = (tid & 1) * 8;
  int blk = blockIdx.x;
  int c = blk & 31;
  int bt = blk >> 5;
  int b = bt / 12;
  int dtile = bt - b * 12;
  int d = dtile * 128 + dl;
  float Dp = D_param[d];
  float Al2[8];
  {
    float4 a0 = *(const float4*)(A_log + d * 16 + nh);
    float4 a1 = *(const float4*)(A_log + d * 16 + nh + 4);
    const float L2E = 1.4426950408889634f;
    Al2[0] = -__expf(a0.x) * L2E; Al2[1] = -__expf(a0.y) * L2E;
    Al2[2] = -__expf(a0.z) * L2E; Al2[3] = -__expf(a0.w) * L2E;
    Al2[4] = -__expf(a1.x) * L2E; Al2[5] = -__expf(a1.y) * L2E;
    Al2[6] = -__expf(a1.z) * L2E; Al2[7] = -__expf(a1.w) * L2E;
  }
  const float* base_d = dbc + (size_t)b * 1024 * 1664 + d;
  const float* base_bc = dbc + (size_t)b * 1024 * 1664 + 1536 + nh;
  const unsigned short* ub = u_bf + (size_t)b * 1024 * 1536 + d;
  const float* rbase = xres + (size_t)b * 1024 * 3072 + 1536 + d;
  unsigned short* yrow = y_out + (size_t)b * 1024 * 1536 + d;
  int j = c * 98304 + (b * 1536 + d) * 16 + nh;
  float h[8];
  {
    size_t hp = hole(j);
    float4 h0 = *(const float4*)(xres + hp);
    float4 h1 = *(const float4*)(xres + hp + 4);
    h[0] = h0.x; h[1] = h0.y; h[2] = h0.z; h[3] = h0.w;
    h[4] = h1.x; h[5] = h1.y; h[6] = h1.z; h[7] = h1.w;
  }
  int t0 = c * 32;
  float dspA = base_d[(size_t)t0 * 1664];
  float utA = b2f(ub[(size_t)t0 * 1536]);
  float4 B0A = *(const float4*)(base_bc + (size_t)t0 * 1664);
  float4 B1A = *(const float4*)(base_bc + (size_t)t0 * 1664 + 4);
  float4 C0A = *(const float4*)(base_bc + (size_t)t0 * 1664 + 16);
  float4 C1A = *(const float4*)(base_bc + (size_t)t0 * 1664 + 20);
  float rA = rbase[(size_t)t0 * 3072];
  float dspB, utB, rB;
  float4 B0B, B1B, C0B, C1B;
#define P3_BODY(DSP, UT, B0, B1, C0, C1, RV, TT)                   \
  {                                                                \
    float du = DSP * UT;                                           \
    float Bv[8] = {B0.x, B0.y, B0.z, B0.w, B1.x, B1.y, B1.z, B1.w};\
    float Cv[8] = {C0.x, C0.y, C0.z, C0.w, C1.x, C1.y, C1.z, C1.w};\
    float p0 = 0.f, p1v = 0.f;                                     \
    _Pragma("unroll")                                              \
    for (int k = 0; k < 8; ++k) {                                  \
      float dA = EXP2F(DSP * Al2[k]);                              \
      h[k] = __builtin_fmaf(dA, h[k], du * Bv[k]);                 \
      if (k & 1) p1v = __builtin_fmaf(h[k], Cv[k], p1v);           \
      else       p0  = __builtin_fmaf(h[k], Cv[k], p0);            \
    }                                                              \
    float p = p0 + p1v;                                            \
    p += __int_as_float(__builtin_amdgcn_update_dpp(               \
        0, __float_as_int(p), 0xB1, 0xF, 0xF, true));              \
    if (nh == 0) {                                                 \
      float sr = RV * RCPF(1.f + __expf(-RV));                     \
      yrow[(size_t)(TT) * 1536] = f2b(__builtin_fmaf(UT, Dp, p) * sr); \
    }                                                              \
  }
  for (int s = 0; s < 32; s += 2) {
    size_t t1 = t0 + s + 1;
    dspB = base_d[t1 * 1664];
    utB = b2f(ub[t1 * 1536]);
    B0B = *(const float4*)(base_bc + t1 * 1664);
    B1B = *(const float4*)(base_bc + t1 * 1664 + 4);
    C0B = *(const float4*)(base_bc + t1 * 1664 + 16);
    C1B = *(const float4*)(base_bc + t1 * 1664 + 20);
    rB = rbase[t1 * 3072];
    P3_BODY(dspA, utA, B0A, B1A, C0A, C1A, rA, t0 + s);
    int t2i = t0 + s + 2; if (t2i > 1023) t2i = 1023;
    size_t t2 = t2i;
    dspA = base_d[t2 * 1664];
    utA = b2f(ub[t2 * 1536]);
    B0A = *(const float4*)(base_bc + t2 * 1664);
    B1A = *(const float4*)(base_bc + t2 * 1664 + 4);
    C0A = *(const float4*)(base_bc + t2 * 1664 + 16);
    C1A = *(const float4*)(base_bc + t2 * 1664 + 20);
    rA = rbase[t2 * 3072];
    P3_BODY(dspB, utB, B0B, B1B, C0B, C1B, rB, t1);
  }
#undef P3_BODY
}

// ------------- bf16 MFMA GEMM: C(MxN) = A(MxK) @ B(NxK)^T ----------------
// Double-buffered LDS, prefetch-before-compute, XOR-swizzled staging.
// MODE 0: C fp32 = acc            MODE 1: C fp32 = res + acc
// MODE 2: C bf16 = gelu(acc+b)    MODE 3: C fp32 = res + bias + acc
// MODE 4: C fp32 = col<1536 ? softplus(acc + bias[col]) : acc
template <int MODE, int BM>
__global__ __launch_bounds__(256, 2) void gemm_bt(
    const unsigned short* __restrict__ A, const unsigned short* __restrict__ B,
    int M, int N, int K, float* __restrict__ Cf, unsigned short* __restrict__ Cb,
    const float* __restrict__ res, const float* __restrict__ bias) {
  constexpr int NFR = (BM == 128) ? 4 : 2;   // B frags per wave
  constexpr int AIT = BM / 64;               // A staging instrs per thread
  __shared__ __align__(16) unsigned short As[2][BM * 32];
  __shared__ __align__(16) unsigned short Bs[2][128 * 32];
  int tid = threadIdx.x;
  int lane = tid & 63;
  int w = tid >> 6;
  int wm = (BM == 128) ? (w >> 1) : 0;
  int wn = (BM == 128) ? (w & 1) : w;
  int row0 = blockIdx.y * BM;
  int col0 = blockIdx.x * 128;
  const int lr = lane & 15;
  const int kb = lane >> 4;

  f32x4 acc[4][NFR];
  #pragma unroll
  for (int i = 0; i < 4; ++i)
    #pragma unroll
    for (int j = 0; j < NFR; ++j) acc[i][j] = (f32x4)0.f;

  auto stage = [&](int buf, int k0) {
    #pragma unroll
    for (int j = 0; j < AIT; ++j) {
      int e = j * 256 + tid;
      int r = e >> 2, cc = e & 3;
      int sc = cc ^ ((r >> 1) & 3);
      gload_lds16(A + (size_t)(row0 + r) * K + k0 + sc * 8, &As[buf][e * 8]);
    }
    #pragma unroll
    for (int j = 0; j < 2; ++j) {
      int e = j * 256 + tid;
      int r = e >> 2, cc = e & 3;
      int sc = cc ^ ((r >> 1) & 3);
      gload_lds16(B + (size_t)(col0 + r) * K + k0 + sc * 8, &Bs[buf][e * 8]);
    }
  };

  stage(0, 0);
  __syncthreads();

  int nt = K >> 5;
  int cur = 0;
  for (int t = 0; t < nt; ++t) {
    if (t + 1 < nt) stage(cur ^ 1, (t + 1) << 5);
    s16x8 af[4], bfm[NFR];
    #pragma unroll
    for (int m = 0; m < 4; ++m) {
      int rr = wm * 64 + m * 16 + lr;
      int chunk = rr * 4 + (kb ^ ((rr >> 1) & 3));
      af[m] = *(const s16x8*)&As[cur][chunk * 8];
    }
    #pragma unroll
    for (int nn = 0; nn < NFR; ++nn) {
      int rr = wn * (16 * NFR) + nn * 16 + lr;
      int chunk = rr * 4 + (kb ^ ((rr >> 1) & 3));
      bfm[nn] = *(const s16x8*)&Bs[cur][chunk * 8];
    }
    #pragma unroll
    for (int m = 0; m < 4; ++m)
      #pragma unroll
      for (int nn = 0; nn < NFR; ++nn)
        acc[m][nn] = __builtin_amdgcn_mfma_f32_16x16x32_bf16(af[m], bfm[nn], acc[m][nn], 0, 0, 0);
    __syncthreads();
    cur ^= 1;
  }

  #pragma unroll
  for (int m = 0; m < 4; ++m) {
    int rbase = row0 + wm * 64 + m * 16 + kb * 4;
    #pragma unroll
    for (int nn = 0; nn < NFR; ++nn) {
      int col = col0 + wn * (16 * NFR) + nn * 16 + lr;
      #pragma unroll
      for (int r = 0; r < 4; ++r) {
        int row = rbase + r;
        size_t idx = (size_t)row * N + col;
        float v = acc[m][nn][r];
        if (MODE == 0) {
          Cf[idx] = v;
        } else if (MODE == 1) {
          Cf[idx] = res[idx] + v;
        } else if (MODE == 2) {
          float tt = v + bias[col];
          float gl = 0.5f * tt * (1.f + erff(tt * 0.7071067811865475f));
          Cb[idx] = f2b(gl);
        } else if (MODE == 3) {
          Cf[idx] = res[idx] + bias[col] + v;
        } else {
          float tt = v;
          if (col < 1536) {
            float xx = tt + bias[col];
            tt = (xx > 20.f) ? xx : __logf(1.f + __expf(xx));
          }
          Cf[idx] = tt;
        }
      }
    }
  }
}

extern "C" void kernel_launch(void* const* d_in, const int* in_sizes, int n_in,
                              void* d_out, int out_size, void* d_ws, size_t ws_size,
                              hipStream_t stream) {
  (void)in_sizes; (void)n_in; (void)out_size; (void)ws_size;
  const float* src   = (const float*)d_in[0];
  const float* n1g   = (const float*)d_in[1];
  const float* n1b   = (const float*)d_in[2];
  const float* inW   = (const float*)d_in[3];
  const float* convW = (const float*)d_in[4];
  const float* convB = (const float*)d_in[5];
  const float* xpW   = (const float*)d_in[6];
  const float* dtW   = (const float*)d_in[7];
  const float* dtB   = (const float*)d_in[8];
  const float* Alog  = (const float*)d_in[9];
  const float* Dpar  = (const float*)d_in[10];
  const float* outW  = (const float*)d_in[11];
  const float* n2g   = (const float*)d_in[12];
  const float* n2b   = (const float*)d_in[13];
  const float* w1    = (const float*)d_in[14];
  const float* b1    = (const float*)d_in[15];
  const float* w2    = (const float*)d_in[16];
  const float* b2    = (const float*)d_in[17];

  char* ws = (char*)d_ws;
  unsigned short* wbA  = (unsigned short*)(ws + 0);           // in_proj bf16  (3072x768)
  unsigned short* wbO  = (unsigned short*)(ws + 4718592);     // out_proj bf16 (768x1536)
  unsigned short* wb1  = (unsigned short*)(ws + 7077888);     // w1 bf16       (3072x768)
  unsigned short* wb2  = (unsigned short*)(ws + 11796480);    // w2 bf16       (768x3072)
  unsigned short* wbig = (unsigned short*)(ws + 16515072);    // (1664x1536) bf16
  unsigned short* hbf  = (unsigned short*)(ws + 21626880);    // (4096x768) bf16; reused as h2
  float*          xres = (float*)(ws + 27918336);             // (4096x3072) fp32; dead half = scan scratch
  unsigned short* xsact= (unsigned short*)(ws + 78249984);    // (4096x1536) bf16
  float*          xbuf = (float*)(ws + 78249984);             // (4096x768) fp32 (reuse, after scan)
  float*          dbc  = (float*)(ws + 90832896);             // (4096x1664) fp32: dsp | B | C
  unsigned short* ff1  = (unsigned short*)(ws + 90832896);    // (4096x3072) bf16 (reuse, after scan)
  unsigned short* ybuf = (unsigned short*)(ws + 118095872);   // (4096x1536) bf16
  float* outp = (float*)d_out;

  // weight prep
  cvt_all<<<8064, 256, 0, stream>>>(inW, outW, w1, w2, wbA, wbO, wb1, wb2);
  build_wbig<<<dim3(6, 1664), 256, 0, stream>>>(xpW, dtW, wbig);

  // mamba block
  ln_kernel<<<1024, 256, 0, stream>>>(src, n1g, n1b, hbf);
  gemm_bt<0, 128><<<dim3(24, 32), 256, 0, stream>>>(hbf, wbA, 4096, 3072, 768, xres, nullptr, nullptr, nullptr);
  conv_silu<<<6144, 256, 0, stream>>>(xres, convW, convB, xsact);
  gemm_bt<4, 64><<<dim3(13, 64), 256, 0, stream>>>(xsact, wbig, 4096, 1664, 1536, dbc, nullptr, nullptr, dtB);
  scan_p1<<<1536, 256, 0, stream>>>(dbc, xsact, Alog, xres);
  scan_p2<<<384, 256, 0, stream>>>(xres);
  scan_p3<<<1536, 256, 0, stream>>>(dbc, xsact, xres, Alog, Dpar, ybuf);
  gemm_bt<1, 64><<<dim3(6, 64), 256, 0, stream>>>(ybuf, wbO, 4096, 768, 1536, xbuf, nullptr, src, nullptr);

  // FFN block
  ln_kernel<<<1024, 256, 0, stream>>>(xbuf, n2g, n2b, hbf);
  gemm_bt<2, 128><<<dim3(24, 32), 256, 0, stream>>>(hbf, wb1, 4096, 3072, 768, nullptr, ff1, nullptr, b1);
  gemm_bt<3, 64><<<dim3(6, 64), 256, 0, stream>>>(ff1, wb2, 4096, 768, 3072, outp, nullptr, xbuf, b2);
}

// Round 6
// 322.312 us; speedup vs baseline: 3.3757x; 1.0190x over previous
//
#include <hip/hip_runtime.h>
#include <cstdint>
#include <cstddef>

typedef __attribute__((ext_vector_type(4))) float f32x4;
typedef __attribute__((ext_vector_type(8))) short s16x8;

#if __has_builtin(__builtin_amdgcn_exp2f)
#define EXP2F(x) __builtin_amdgcn_exp2f(x)
#else
#define EXP2F(x) __expf((x) * 0.6931471805599453f)
#endif
#if __has_builtin(__builtin_amdgcn_rcpf)
#define RCPF(x) __builtin_amdgcn_rcpf(x)
#else
#define RCPF(x) (1.0f / (x))
#endif

__device__ inline unsigned short f2b(float f) {
  union { float f; unsigned u; } c; c.f = f;
  return (unsigned short)((c.u + 0x7FFFu + ((c.u >> 16) & 1u)) >> 16);
}
__device__ inline float b2f(unsigned short u) {
  union { unsigned u; float f; } c; c.u = ((unsigned)u) << 16;
  return c.f;
}

__device__ inline void gload_lds16(const void* g, void* l) {
  __builtin_amdgcn_global_load_lds(
      (const __attribute__((address_space(1))) unsigned int*)g,
      (__attribute__((address_space(3))) unsigned int*)l, 16, 0, 0);
}

// Scan scratch lives in the dead first-half columns of xres (cols 0..1535,
// all 4096 rows are dead after conv_silu). j in [0, 3.15M) -> P slot;
// +HOLE2 -> h_end slot (rows 2048..4095).
#define HOLE2 6291456
__device__ inline size_t hole(int j) {
  int r = j / 1536;
  int c = j - r * 1536;
  return (size_t)r * 3072 + c;
}

// ------------- fused fp32 -> bf16 convert for the 4 weight tensors --------
__global__ __launch_bounds__(256) void cvt_all(const float* __restrict__ inW,
                                               const float* __restrict__ outW,
                                               const float* __restrict__ w1,
                                               const float* __restrict__ w2,
                                               unsigned short* __restrict__ wbA,
                                               unsigned short* __restrict__ wbO,
                                               unsigned short* __restrict__ wb1,
                                               unsigned short* __restrict__ wb2) {
  int i = blockIdx.x * 256 + threadIdx.x;  // [0, 2064384) float4 units
  const float* src;
  unsigned short* dst;
  int o;
  if (i < 589824)       { src = inW;  dst = wbA; o = i; }
  else if (i < 884736)  { src = outW; dst = wbO; o = i - 589824; }
  else if (i < 1474560) { src = w1;   dst = wb1; o = i - 884736; }
  else                  { src = w2;   dst = wb2; o = i - 1474560; }
  float4 v = ((const float4*)src)[o];
  ushort4 u;
  u.x = f2b(v.x); u.y = f2b(v.y); u.z = f2b(v.z); u.w = f2b(v.w);
  ((ushort4*)dst)[o] = u;
}

// ------- build combined weight: rows 0..1535 = dt_proj_w @ x_proj_w[:48]
// -------                        rows 1536..1663 = x_proj_w[48:80] then zeros
__global__ __launch_bounds__(256) void build_wbig(const float* __restrict__ xpw,
                                                  const float* __restrict__ dtw,
                                                  unsigned short* __restrict__ wbig) {
  int k = blockIdx.x * 256 + threadIdx.x;   // 0..1535
  int rowid = blockIdx.y;                   // 0..1663
  float v;
  if (rowid < 1536) {
    float s = 0.f;
    #pragma unroll 8
    for (int r = 0; r < 48; ++r)
      s = __builtin_fmaf(dtw[rowid * 48 + r], xpw[r * 1536 + k], s);
    v = s;
  } else {
    int rr = rowid - 1536;
    v = (rr < 32) ? xpw[(48 + rr) * 1536 + k] : 0.f;
  }
  wbig[(size_t)rowid * 1536 + k] = f2b(v);
}

// ---------------- LayerNorm over 768, one wave per row, bf16 out ----------
__global__ __launch_bounds__(256) void ln_kernel(const float* __restrict__ x,
                                                 const float* __restrict__ gam,
                                                 const float* __restrict__ bet,
                                                 unsigned short* __restrict__ out) {
  int w = threadIdx.x >> 6, lane = threadIdx.x & 63;
  size_t row = (size_t)blockIdx.x * 4 + w;
  const float4* xr = (const float4*)(x + row * 768);
  float4 v0 = xr[lane], v1 = xr[lane + 64], v2 = xr[lane + 128];
  float s = v0.x + v0.y + v0.z + v0.w + v1.x + v1.y + v1.z + v1.w +
            v2.x + v2.y + v2.z + v2.w;
  #pragma unroll
  for (int o = 32; o; o >>= 1) s += __shfl_xor(s, o);
  float mu = s * (1.f / 768.f);
  float q = 0.f;
  {
    float d;
    d = v0.x - mu; q += d * d; d = v0.y - mu; q += d * d;
    d = v0.z - mu; q += d * d; d = v0.w - mu; q += d * d;
    d = v1.x - mu; q += d * d; d = v1.y - mu; q += d * d;
    d = v1.z - mu; q += d * d; d = v1.w - mu; q += d * d;
    d = v2.x - mu; q += d * d; d = v2.y - mu; q += d * d;
    d = v2.z - mu; q += d * d; d = v2.w - mu; q += d * d;
  }
  #pragma unroll
  for (int o = 32; o; o >>= 1) q += __shfl_xor(q, o);
  float rs = rsqrtf(q * (1.f / 768.f) + 1e-5f);
  const float4* gr = (const float4*)gam;
  const float4* br = (const float4*)bet;
  ushort4* orow = (ushort4*)(out + row * 768);
  float4 vv[3] = {v0, v1, v2};
  #pragma unroll
  for (int i = 0; i < 3; ++i) {
    int c4 = lane + i * 64;
    float4 g4 = gr[c4], b4 = br[c4];
    ushort4 o;
    o.x = f2b((vv[i].x - mu) * rs * g4.x + b4.x);
    o.y = f2b((vv[i].y - mu) * rs * g4.y + b4.y);
    o.z = f2b((vv[i].z - mu) * rs * g4.z + b4.z);
    o.w = f2b((vv[i].w - mu) * rs * g4.w + b4.w);
    orow[c4] = o;
  }
}

// -------- split-K reduce (2 slices) + residual(src) + LayerNorm ----------
// xbuf = src + P0 + P1 ; hbf = bf16 LN(xbuf)
__global__ __launch_bounds__(256) void reduce_ln(
    const float* __restrict__ Pp, const float* __restrict__ src,
    const float* __restrict__ gam, const float* __restrict__ bet,
    float* __restrict__ xbuf, unsigned short* __restrict__ hbf) {
  int w = threadIdx.x >> 6, lane = threadIdx.x & 63;
  size_t row = (size_t)blockIdx.x * 4 + w;
  const float4* s4 = (const float4*)(src + row * 768);
  const float4* p0 = (const float4*)(Pp + row * 768);
  const float4* p1 = (const float4*)(Pp + 3145728 + row * 768);
  float4* xb4 = (float4*)(xbuf + row * 768);
  float4 xv[3];
  float s = 0.f;
  #pragma unroll
  for (int j = 0; j < 3; ++j) {
    int c4 = lane + j * 64;
    float4 a = s4[c4], b = p0[c4], c = p1[c4];
    float4 x;
    x.x = a.x + b.x + c.x; x.y = a.y + b.y + c.y;
    x.z = a.z + b.z + c.z; x.w = a.w + b.w + c.w;
    xv[j] = x;
    xb4[c4] = x;
    s += x.x + x.y + x.z + x.w;
  }
  #pragma unroll
  for (int o = 32; o; o >>= 1) s += __shfl_xor(s, o);
  float mu = s * (1.f / 768.f);
  float q = 0.f;
  #pragma unroll
  for (int j = 0; j < 3; ++j) {
    float d;
    d = xv[j].x - mu; q += d * d; d = xv[j].y - mu; q += d * d;
    d = xv[j].z - mu; q += d * d; d = xv[j].w - mu; q += d * d;
  }
  #pragma unroll
  for (int o = 32; o; o >>= 1) q += __shfl_xor(q, o);
  float rs = rsqrtf(q * (1.f / 768.f) + 1e-5f);
  const float4* gr = (const float4*)gam;
  const float4* br = (const float4*)bet;
  ushort4* orow = (ushort4*)(hbf + row * 768);
  #pragma unroll
  for (int j = 0; j < 3; ++j) {
    int c4 = lane + j * 64;
    float4 g4 = gr[c4], b4 = br[c4];
    ushort4 o;
    o.x = f2b((xv[j].x - mu) * rs * g4.x + b4.x);
    o.y = f2b((xv[j].y - mu) * rs * g4.y + b4.y);
    o.z = f2b((xv[j].z - mu) * rs * g4.z + b4.z);
    o.w = f2b((xv[j].w - mu) * rs * g4.w + b4.w);
    orow[c4] = o;
  }
}

// -------- split-K reduce (2 slices) + residual(xbuf) + bias -> d_out -----
__global__ __launch_bounds__(256) void reduce_out(
    const float* __restrict__ Pp, const float* __restrict__ xbuf,
    const float* __restrict__ bias, float* __restrict__ outp) {
  int i = blockIdx.x * 256 + threadIdx.x;  // f4 idx, [0, 786432)
  int r = i / 192;
  int c4 = i - r * 192;
  float4 b4 = ((const float4*)bias)[c4];
  float4 x = ((const float4*)xbuf)[i];
  float4 p0 = ((const float4*)Pp)[i];
  float4 p1 = ((const float4*)(Pp + 3145728))[i];
  float4 o;
  o.x = x.x + b4.x + p0.x + p1.x;
  o.y = x.y + b4.y + p0.y + p1.y;
  o.z = x.z + b4.z + p0.z + p1.z;
  o.w = x.w + b4.w + p0.w + p1.w;
  ((float4*)outp)[i] = o;
}

// ---------------- causal depthwise conv(4) + bias + SiLU -> bf16 ----------
__global__ __launch_bounds__(256) void conv_silu(const float* __restrict__ xres,
                                                 const float* __restrict__ cw,
                                                 const float* __restrict__ cb,
                                                 unsigned short* __restrict__ xs_act) {
  int idx = blockIdx.x * 256 + threadIdx.x;  // 4096*384
  int t = idx / 384;
  int c4 = idx - t * 384;
  int pos = t & 1023;
  const float* base = xres + (size_t)t * 3072 + c4 * 4;
  float4 z = {0.f, 0.f, 0.f, 0.f};
  float4 x3 = *(const float4*)base;
  float4 x2 = (pos >= 1) ? *(const float4*)(base - 3072) : z;
  float4 x1 = (pos >= 2) ? *(const float4*)(base - 6144) : z;
  float4 x0 = (pos >= 3) ? *(const float4*)(base - 9216) : z;
  float a0[4] = {x0.x, x0.y, x0.z, x0.w};
  float a1[4] = {x1.x, x1.y, x1.z, x1.w};
  float a2[4] = {x2.x, x2.y, x2.z, x2.w};
  float a3[4] = {x3.x, x3.y, x3.z, x3.w};
  ushort4 o;
  unsigned short* op = &o.x;
  #pragma unroll
  for (int i = 0; i < 4; ++i) {
    int dd = c4 * 4 + i;
    float4 wv = *(const float4*)(cw + dd * 4);
    float v = wv.x * a0[i] + wv.y * a1[i] + wv.z * a2[i] + wv.w * a3[i] + cb[dd];
    float sv = v * RCPF(1.f + __expf(-v));
    op[i] = f2b(sv);
  }
  *(ushort4*)(xs_act + (size_t)t * 1536 + c4 * 4) = o;
}

// ================== chunked selective scan (32 chunks x 32 steps) =========
// dbc cols 0..1535 hold dsp = softplus(delta + dt_bias) (GEMM MODE 4).
// Lane layout: 2 lanes per d, 8 n-states in registers per lane.
// grid = b(4) * dtile(12) * chunk(32) = 1536 blocks.
__global__ __launch_bounds__(256) void scan_p1(
    const float* __restrict__ dbc, const unsigned short* __restrict__ u_bf,
    const float* __restrict__ A_log, float* __restrict__ xdead) {
  int tid = threadIdx.x;
  int dl = tid >> 1;
  int nh = (tid & 1) * 8;
  int blk = blockIdx.x;
  int c = blk & 31;
  int bt = blk >> 5;
  int b = bt / 12;
  int dtile = bt - b * 12;
  int d = dtile * 128 + dl;
  float Al2[8];
  {
    float4 a0 = *(const float4*)(A_log + d * 16 + nh);
    float4 a1 = *(const float4*)(A_log + d * 16 + nh + 4);
    const float L2E = 1.4426950408889634f;
    Al2[0] = -__expf(a0.x) * L2E; Al2[1] = -__expf(a0.y) * L2E;
    Al2[2] = -__expf(a0.z) * L2E; Al2[3] = -__expf(a0.w) * L2E;
    Al2[4] = -__expf(a1.x) * L2E; Al2[5] = -__expf(a1.y) * L2E;
    Al2[6] = -__expf(a1.z) * L2E; Al2[7] = -__expf(a1.w) * L2E;
  }
  const float* base_d = dbc + (size_t)b * 1024 * 1664 + d;
  const float* base_bc = dbc + (size_t)b * 1024 * 1664 + 1536 + nh;
  const unsigned short* ub = u_bf + (size_t)b * 1024 * 1536 + d;
  float h[8];
  #pragma unroll
  for (int k = 0; k < 8; ++k) h[k] = 0.f;
  float S = 0.f;
  int t0 = c * 32;
  float dspA = base_d[(size_t)t0 * 1664];
  float utA = b2f(ub[(size_t)t0 * 1536]);
  float4 B0A = *(const float4*)(base_bc + (size_t)t0 * 1664);
  float4 B1A = *(const float4*)(base_bc + (size_t)t0 * 1664 + 4);
  float dspB, utB;
  float4 B0B, B1B;
#define P1_BODY(DSP, UT, B0, B1)                                   \
  {                                                                \
    S += DSP;                                                      \
    float du = DSP * UT;                                           \
    float Bv[8] = {B0.x, B0.y, B0.z, B0.w, B1.x, B1.y, B1.z, B1.w};\
    _Pragma("unroll")                                              \
    for (int k = 0; k < 8; ++k) {                                  \
      float dA = EXP2F(DSP * Al2[k]);                              \
      h[k] = __builtin_fmaf(dA, h[k], du * Bv[k]);                 \
    }                                                              \
  }
  for (int s = 0; s < 32; s += 2) {
    size_t t1 = t0 + s + 1;
    dspB = base_d[t1 * 1664];
    utB = b2f(ub[t1 * 1536]);
    B0B = *(const float4*)(base_bc + t1 * 1664);
    B1B = *(const float4*)(base_bc + t1 * 1664 + 4);
    P1_BODY(dspA, utA, B0A, B1A);
    int t2i = t0 + s + 2; if (t2i > 1023) t2i = 1023;
    size_t t2 = t2i;
    dspA = base_d[t2 * 1664];
    utA = b2f(ub[t2 * 1536]);
    B0A = *(const float4*)(base_bc + t2 * 1664);
    B1A = *(const float4*)(base_bc + t2 * 1664 + 4);
    P1_BODY(dspB, utB, B0B, B1B);
  }
#undef P1_BODY
  int j = c * 98304 + (b * 1536 + d) * 16 + nh;
  size_t hp = hole(j);
  xdead[hp]     = EXP2F(Al2[0] * S);
  xdead[hp + 1] = EXP2F(Al2[1] * S);
  xdead[hp + 2] = EXP2F(Al2[2] * S);
  xdead[hp + 3] = EXP2F(Al2[3] * S);
  xdead[hp + 4] = EXP2F(Al2[4] * S);
  xdead[hp + 5] = EXP2F(Al2[5] * S);
  xdead[hp + 6] = EXP2F(Al2[6] * S);
  xdead[hp + 7] = EXP2F(Al2[7] * S);
  float* he = xdead + hp + HOLE2;
  *(float4*)he = make_float4(h[0], h[1], h[2], h[3]);
  *(float4*)(he + 4) = make_float4(h[4], h[5], h[6], h[7]);
}

// P2: per (b,d,n) combine 32 chunks; store each chunk's true initial state
// in-place over the P slot.
__global__ __launch_bounds__(256) void scan_p2(float* __restrict__ xdead) {
  int i = blockIdx.x * 256 + threadIdx.x;  // [0, 98304)
  float H = 0.f;
  #pragma unroll
  for (int c = 0; c < 32; ++c) {
    int j = c * 98304 + i;
    size_t hp = hole(j);
    float P = xdead[hp];
    float he = xdead[hp + HOLE2];
    xdead[hp] = H;
    H = __builtin_fmaf(P, H, he);
  }
}

// P3: replay each chunk from its true H_init; reduce over n in-register +
// one DPP-xor1 across the lane pair; fuse +u*D and *silu(res); bf16 y out.
__global__ __launch_bounds__(256) void scan_p3(
    const float* __restrict__ dbc, const unsigned short* __restrict__ u_bf,
    const float* __restrict__ xres, const float* __restrict__ A_log,
    const float* __restrict__ D_param, unsigned short* __restrict__ y_out) {
  int tid = threadIdx.x;
  int dl = tid >> 1;
  int nh = (tid & 1) * 8;
  int blk = blockIdx.x;
  int c = blk & 31;
  int bt = blk >> 5;
  int b = bt / 12;
  int dtile = bt - b * 12;
  int d = dtile * 128 + dl;
  float Dp = D_param[d];
  float Al2[8];
  {
    float4 a0 = *(const float4*)(A_log + d * 16 + nh);
    float4 a1 = *(const float4*)(A_log + d * 16 + nh + 4);
    const float L2E = 1.4426950408889634f;
    Al2[0] = -__expf(a0.x) * L2E; Al2[1] = -__expf(a0.y) * L2E;
    Al2[2] = -__expf(a0.z) * L2E; Al2[3] = -__expf(a0.w) * L2E;
    Al2[4] = -__expf(a1.x) * L2E; Al2[5] = -__expf(a1.y) * L2E;
    Al2[6] = -__expf(a1.z) * L2E; Al2[7] = -__expf(a1.w) * L2E;
  }
  const float* base_d = dbc + (size_t)b * 1024 * 1664 + d;
  const float* base_bc = dbc + (size_t)b * 1024 * 1664 + 1536 + nh;
  const unsigned short* ub = u_bf + (size_t)b * 1024 * 1536 + d;
  const float* rbase = xres + (size_t)b * 1024 * 3072 + 1536 + d;
  unsigned short* yrow = y_out + (size_t)b * 1024 * 1536 + d;
  int j = c * 98304 + (b * 1536 + d) * 16 + nh;
  float h[8];
  {
    size_t hp = hole(j);
    float4 h0 = *(const float4*)(xres + hp);
    float4 h1 = *(const float4*)(xres + hp + 4);
    h[0] = h0.x; h[1] = h0.y; h[2] = h0.z; h[3] = h0.w;
    h[4] = h1.x; h[5] = h1.y; h[6] = h1.z; h[7] = h1.w;
  }
  int t0 = c * 32;
  float dspA = base_d[(size_t)t0 * 1664];
  float utA = b2f(ub[(size_t)t0 * 1536]);
  float4 B0A = *(const float4*)(base_bc + (size_t)t0 * 1664);
  float4 B1A = *(const float4*)(base_bc + (size_t)t0 * 1664 + 4);
  float4 C0A = *(const float4*)(base_bc + (size_t)t0 * 1664 + 16);
  float4 C1A = *(const float4*)(base_bc + (size_t)t0 * 1664 + 20);
  float rA = rbase[(size_t)t0 * 3072];
  float dspB, utB, rB;
  float4 B0B, B1B, C0B, C1B;
#define P3_BODY(DSP, UT, B0, B1, C0, C1, RV, TT)                   \
  {                                                                \
    float du = DSP * UT;                                           \
    float Bv[8] = {B0.x, B0.y, B0.z, B0.w, B1.x, B1.y, B1.z, B1.w};\
    float Cv[8] = {C0.x, C0.y, C0.z, C0.w, C1.x, C1.y, C1.z, C1.w};\
    float p0 = 0.f, p1v = 0.f;                                     \
    _Pragma("unroll")                                              \
    for (int k = 0; k < 8; ++k) {                                  \
      float dA = EXP2F(DSP * Al2[k]);                              \
      h[k] = __builtin_fmaf(dA, h[k], du * Bv[k]);                 \
      if (k & 1) p1v = __builtin_fmaf(h[k], Cv[k], p1v);           \
      else       p0  = __builtin_fmaf(h[k], Cv[k], p0);            \
    }                                                              \
    float p = p0 + p1v;                                            \
    p += __int_as_float(__builtin_amdgcn_update_dpp(               \
        0, __float_as_int(p), 0xB1, 0xF, 0xF, true));              \
    if (nh == 0) {                                                 \
      float sr = RV * RCPF(1.f + __expf(-RV));                     \
      yrow[(size_t)(TT) * 1536] = f2b(__builtin_fmaf(UT, Dp, p) * sr); \
    }                                                              \
  }
  for (int s = 0; s < 32; s += 2) {
    size_t t1 = t0 + s + 1;
    dspB = base_d[t1 * 1664];
    utB = b2f(ub[t1 * 1536]);
    B0B = *(const float4*)(base_bc + t1 * 1664);
    B1B = *(const float4*)(base_bc + t1 * 1664 + 4);
    C0B = *(const float4*)(base_bc + t1 * 1664 + 16);
    C1B = *(const float4*)(base_bc + t1 * 1664 + 20);
    rB = rbase[t1 * 3072];
    P3_BODY(dspA, utA, B0A, B1A, C0A, C1A, rA, t0 + s);
    int t2i = t0 + s + 2; if (t2i > 1023) t2i = 1023;
    size_t t2 = t2i;
    dspA = base_d[t2 * 1664];
    utA = b2f(ub[t2 * 1536]);
    B0A = *(const float4*)(base_bc + t2 * 1664);
    B1A = *(const float4*)(base_bc + t2 * 1664 + 4);
    C0A = *(const float4*)(base_bc + t2 * 1664 + 16);
    C1A = *(const float4*)(base_bc + t2 * 1664 + 20);
    rA = rbase[t2 * 3072];
    P3_BODY(dspB, utB, B0B, B1B, C0B, C1B, rB, t1);
  }
#undef P3_BODY
}

// ------------- bf16 MFMA GEMM: C(MxN) = A(MxK) @ B(NxK)^T ----------------
// Double-buffered LDS, prefetch-before-compute, XOR-swizzled staging.
// Split-K via gridDim.z (each z-slice covers K/gridDim.z).
// MODE 0: C fp32 = acc
// MODE 2: C bf16 = gelu(acc+bias)
// MODE 4: C fp32 = col<1536 ? softplus(acc + bias[col]) : acc
// MODE 5: partial fp32 at Cf + z*M*N
template <int MODE, int BM>
__global__ __launch_bounds__(256, 2) void gemm_bt(
    const unsigned short* __restrict__ A, const unsigned short* __restrict__ B,
    int M, int N, int K, float* __restrict__ Cf, unsigned short* __restrict__ Cb,
    const float* __restrict__ res, const float* __restrict__ bias) {
  constexpr int NFR = (BM == 128) ? 4 : 2;   // B frags per wave
  constexpr int AIT = BM / 64;               // A staging instrs per thread
  __shared__ __align__(16) unsigned short As[2][BM * 32];
  __shared__ __align__(16) unsigned short Bs[2][128 * 32];
  int tid = threadIdx.x;
  int lane = tid & 63;
  int w = tid >> 6;
  int wm = (BM == 128) ? (w >> 1) : 0;
  int wn = (BM == 128) ? (w & 1) : w;
  int row0 = blockIdx.y * BM;
  int col0 = blockIdx.x * 128;
  const int lr = lane & 15;
  const int kb = lane >> 4;
  int ksl = K / gridDim.z;
  int kbeg = blockIdx.z * ksl;

  f32x4 acc[4][NFR];
  #pragma unroll
  for (int i = 0; i < 4; ++i)
    #pragma unroll
    for (int j = 0; j < NFR; ++j) acc[i][j] = (f32x4)0.f;

  auto stage = [&](int buf, int k0) {
    #pragma unroll
    for (int j = 0; j < AIT; ++j) {
      int e = j * 256 + tid;
      int r = e >> 2, cc = e & 3;
      int sc = cc ^ ((r >> 1) & 3);
      gload_lds16(A + (size_t)(row0 + r) * K + k0 + sc * 8, &As[buf][e * 8]);
    }
    #pragma unroll
    for (int j = 0; j < 2; ++j) {
      int e = j * 256 + tid;
      int r = e >> 2, cc = e & 3;
      int sc = cc ^ ((r >> 1) & 3);
      gload_lds16(B + (size_t)(col0 + r) * K + k0 + sc * 8, &Bs[buf][e * 8]);
    }
  };

  stage(0, kbeg);
  __syncthreads();

  int nt = ksl >> 5;
  int cur = 0;
  for (int t = 0; t < nt; ++t) {
    if (t + 1 < nt) stage(cur ^ 1, kbeg + ((t + 1) << 5));
    s16x8 af[4], bfm[NFR];
    #pragma unroll
    for (int m = 0; m < 4; ++m) {
      int rr = wm * 64 + m * 16 + lr;
      int chunk = rr * 4 + (kb ^ ((rr >> 1) & 3));
      af[m] = *(const s16x8*)&As[cur][chunk * 8];
    }
    #pragma unroll
    for (int nn = 0; nn < NFR; ++nn) {
      int rr = wn * (16 * NFR) + nn * 16 + lr;
      int chunk = rr * 4 + (kb ^ ((rr >> 1) & 3));
      bfm[nn] = *(const s16x8*)&Bs[cur][chunk * 8];
    }
    #pragma unroll
    for (int m = 0; m < 4; ++m)
      #pragma unroll
      for (int nn = 0; nn < NFR; ++nn)
        acc[m][nn] = __builtin_amdgcn_mfma_f32_16x16x32_bf16(af[m], bfm[nn], acc[m][nn], 0, 0, 0);
    __syncthreads();
    cur ^= 1;
  }

  size_t zoff = (size_t)blockIdx.z * M * N;
  #pragma unroll
  for (int m = 0; m < 4; ++m) {
    int rbase = row0 + wm * 64 + m * 16 + kb * 4;
    #pragma unroll
    for (int nn = 0; nn < NFR; ++nn) {
      int col = col0 + wn * (16 * NFR) + nn * 16 + lr;
      #pragma unroll
      for (int r = 0; r < 4; ++r) {
        int row = rbase + r;
        size_t idx = (size_t)row * N + col;
        float v = acc[m][nn][r];
        if (MODE == 0) {
          Cf[idx] = v;
        } else if (MODE == 2) {
          float tt = v + bias[col];
          float gl = 0.5f * tt * (1.f + erff(tt * 0.7071067811865475f));
          Cb[idx] = f2b(gl);
        } else if (MODE == 4) {
          float tt = v;
          if (col < 1536) {
            float xx = tt + bias[col];
            tt = (xx > 20.f) ? xx : __logf(1.f + __expf(xx));
          }
          Cf[idx] = tt;
        } else {  // MODE 5
          Cf[zoff + idx] = v;
        }
      }
    }
  }
}

extern "C" void kernel_launch(void* const* d_in, const int* in_sizes, int n_in,
                              void* d_out, int out_size, void* d_ws, size_t ws_size,
                              hipStream_t stream) {
  (void)in_sizes; (void)n_in; (void)out_size; (void)ws_size;
  const float* src   = (const float*)d_in[0];
  const float* n1g   = (const float*)d_in[1];
  const float* n1b   = (const float*)d_in[2];
  const float* inW   = (const float*)d_in[3];
  const float* convW = (const float*)d_in[4];
  const float* convB = (const float*)d_in[5];
  const float* xpW   = (const float*)d_in[6];
  const float* dtW   = (const float*)d_in[7];
  const float* dtB   = (const float*)d_in[8];
  const float* Alog  = (const float*)d_in[9];
  const float* Dpar  = (const float*)d_in[10];
  const float* outW  = (const float*)d_in[11];
  const float* n2g   = (const float*)d_in[12];
  const float* n2b   = (const float*)d_in[13];
  const float* w1    = (const float*)d_in[14];
  const float* b1    = (const float*)d_in[15];
  const float* w2    = (const float*)d_in[16];
  const float* b2    = (const float*)d_in[17];

  char* ws = (char*)d_ws;
  unsigned short* wbA  = (unsigned short*)(ws + 0);           // in_proj bf16  (3072x768)
  unsigned short* wbO  = (unsigned short*)(ws + 4718592);     // out_proj bf16 (768x1536)
  unsigned short* wb1  = (unsigned short*)(ws + 7077888);     // w1 bf16       (3072x768)
  unsigned short* wb2  = (unsigned short*)(ws + 11796480);    // w2 bf16       (768x3072)
  unsigned short* wbig = (unsigned short*)(ws + 16515072);    // (1664x1536) bf16
  unsigned short* hbf  = (unsigned short*)(ws + 21626880);    // (4096x768) bf16 LN outputs
  float*          xres = (float*)(ws + 27918336);             // (4096x3072) fp32; dead half = scan scratch;
                                                              // whole region = split-K partials after scan
  float*          Ppart= (float*)(ws + 27918336);             // 2 x (4096x768) fp32 partials
  unsigned short* xsact= (unsigned short*)(ws + 78249984);    // (4096x1536) bf16
  float*          xbuf = (float*)(ws + 78249984);             // (4096x768) fp32 (reuse, after scan)
  float*          dbc  = (float*)(ws + 90832896);             // (4096x1664) fp32: dsp | B | C
  unsigned short* ff1  = (unsigned short*)(ws + 90832896);    // (4096x3072) bf16 (reuse, after scan)
  unsigned short* ybuf = (unsigned short*)(ws + 118095872);   // (4096x1536) bf16
  float* outp = (float*)d_out;

  // weight prep
  cvt_all<<<8064, 256, 0, stream>>>(inW, outW, w1, w2, wbA, wbO, wb1, wb2);
  build_wbig<<<dim3(6, 1664), 256, 0, stream>>>(xpW, dtW, wbig);

  // mamba block
  ln_kernel<<<1024, 256, 0, stream>>>(src, n1g, n1b, hbf);
  gemm_bt<0, 128><<<dim3(24, 32), 256, 0, stream>>>(hbf, wbA, 4096, 3072, 768, xres, nullptr, nullptr, nullptr);
  conv_silu<<<6144, 256, 0, stream>>>(xres, convW, convB, xsact);
  gemm_bt<4, 64><<<dim3(13, 64), 256, 0, stream>>>(xsact, wbig, 4096, 1664, 1536, dbc, nullptr, nullptr, dtB);
  scan_p1<<<1536, 256, 0, stream>>>(dbc, xsact, Alog, xres);
  scan_p2<<<384, 256, 0, stream>>>(xres);
  scan_p3<<<1536, 256, 0, stream>>>(dbc, xsact, xres, Alog, Dpar, ybuf);

  // out_proj split-K=2 (partials into dead xres) + fused residual+LN2
  gemm_bt<5, 64><<<dim3(6, 64, 2), 256, 0, stream>>>(ybuf, wbO, 4096, 768, 1536, Ppart, nullptr, nullptr, nullptr);
  reduce_ln<<<1024, 256, 0, stream>>>(Ppart, src, n2g, n2b, xbuf, hbf);

  // FFN block
  gemm_bt<2, 128><<<dim3(24, 32), 256, 0, stream>>>(hbf, wb1, 4096, 3072, 768, nullptr, ff1, nullptr, b1);
  gemm_bt<5, 64><<<dim3(6, 64, 2), 256, 0, stream>>>(ff1, wb2, 4096, 768, 3072, Ppart, nullptr, nullptr, nullptr);
  reduce_out<<<3072, 256, 0, stream>>>(Ppart, xbuf, b2, outp);
}

// Round 7
// 280.779 us; speedup vs baseline: 3.8750x; 1.1479x over previous
//
#include <hip/hip_runtime.h>
#include <cstdint>
#include <cstddef>

typedef __attribute__((ext_vector_type(4))) float f32x4;
typedef __attribute__((ext_vector_type(8))) short s16x8;

#if __has_builtin(__builtin_amdgcn_exp2f)
#define EXP2F(x) __builtin_amdgcn_exp2f(x)
#else
#define EXP2F(x) __expf((x) * 0.6931471805599453f)
#endif
#if __has_builtin(__builtin_amdgcn_rcpf)
#define RCPF(x) __builtin_amdgcn_rcpf(x)
#else
#define RCPF(x) (1.0f / (x))
#endif

__device__ inline unsigned short f2b(float f) {
  union { float f; unsigned u; } c; c.f = f;
  return (unsigned short)((c.u + 0x7FFFu + ((c.u >> 16) & 1u)) >> 16);
}
__device__ inline float b2f(unsigned short u) {
  union { unsigned u; float f; } c; c.u = ((unsigned)u) << 16;
  return c.f;
}

__device__ inline void gload_lds16(const void* g, void* l) {
  __builtin_amdgcn_global_load_lds(
      (const __attribute__((address_space(1))) unsigned int*)g,
      (__attribute__((address_space(3))) unsigned int*)l, 16, 0, 0);
}

// Scan scratch lives in the dead first-half columns of xres (cols 0..1535,
// all 4096 rows dead after conv_silu). j -> P slot; +HOLE2 -> h_end slot.
#define HOLE2 6291456
__device__ inline size_t hole(int j) {
  int r = j / 1536;
  int c = j - r * 1536;
  return (size_t)r * 3072 + c;
}

// ------------- fused fp32 -> bf16 convert for the 4 weight tensors --------
__global__ __launch_bounds__(256) void cvt_all(const float* __restrict__ inW,
                                               const float* __restrict__ outW,
                                               const float* __restrict__ w1,
                                               const float* __restrict__ w2,
                                               unsigned short* __restrict__ wbA,
                                               unsigned short* __restrict__ wbO,
                                               unsigned short* __restrict__ wb1,
                                               unsigned short* __restrict__ wb2) {
  int i = blockIdx.x * 256 + threadIdx.x;  // [0, 2064384) float4 units
  const float* src;
  unsigned short* dst;
  int o;
  if (i < 589824)       { src = inW;  dst = wbA; o = i; }
  else if (i < 884736)  { src = outW; dst = wbO; o = i - 589824; }
  else if (i < 1474560) { src = w1;   dst = wb1; o = i - 884736; }
  else                  { src = w2;   dst = wb2; o = i - 1474560; }
  float4 v = ((const float4*)src)[o];
  ushort4 u;
  u.x = f2b(v.x); u.y = f2b(v.y); u.z = f2b(v.z); u.w = f2b(v.w);
  ((ushort4*)dst)[o] = u;
}

// ------- build padded projection weights:
//   wpad (128 x 1536 bf16): rows 0..79 = x_proj_w, rows 80..127 = 0
//   wdt  (1536 x 64 bf16):  cols 0..47 = dt_proj_w, cols 48..63 = 0
__global__ __launch_bounds__(256) void build_proj(const float* __restrict__ xpw,
                                                  const float* __restrict__ dtw,
                                                  unsigned short* __restrict__ wpad,
                                                  unsigned short* __restrict__ wdt) {
  int i = blockIdx.x * 256 + threadIdx.x;  // < 294912
  if (i < 196608) {
    int row = i / 1536;
    wpad[i] = (row < 80) ? f2b(xpw[i]) : (unsigned short)0;
  } else {
    int j = i - 196608;  // < 98304
    int row = j >> 6, k = j & 63;
    wdt[j] = (k < 48) ? f2b(dtw[row * 48 + k]) : (unsigned short)0;
  }
}

// ---- reduce stage-A split-K partials (4 slices of 4096x128) ----
// cols 0..47 -> dt (bf16, padded to 64); cols 48..79 -> projBC fp32 (B|C)
__global__ __launch_bounds__(256) void reduce_projA(const float* __restrict__ Pa,
                                                    unsigned short* __restrict__ dtbf,
                                                    float* __restrict__ projBC) {
  int i = blockIdx.x * 256 + threadIdx.x;  // < 524288
  int row = i >> 7, col = i & 127;
  float s = Pa[i] + Pa[i + 524288] + Pa[i + 1048576] + Pa[i + 1572864];
  if (col < 48) {
    dtbf[row * 64 + col] = f2b(s);
  } else if (col < 64) {
    dtbf[row * 64 + col] = 0;
    projBC[row * 32 + col - 48] = s;
  } else if (col < 80) {
    projBC[row * 32 + col - 48] = s;
  }
}

// ---------------- LayerNorm over 768, one wave per row, bf16 out ----------
__global__ __launch_bounds__(256) void ln_kernel(const float* __restrict__ x,
                                                 const float* __restrict__ gam,
                                                 const float* __restrict__ bet,
                                                 unsigned short* __restrict__ out) {
  int w = threadIdx.x >> 6, lane = threadIdx.x & 63;
  size_t row = (size_t)blockIdx.x * 4 + w;
  const float4* xr = (const float4*)(x + row * 768);
  float4 v0 = xr[lane], v1 = xr[lane + 64], v2 = xr[lane + 128];
  float s = v0.x + v0.y + v0.z + v0.w + v1.x + v1.y + v1.z + v1.w +
            v2.x + v2.y + v2.z + v2.w;
  #pragma unroll
  for (int o = 32; o; o >>= 1) s += __shfl_xor(s, o);
  float mu = s * (1.f / 768.f);
  float q = 0.f;
  {
    float d;
    d = v0.x - mu; q += d * d; d = v0.y - mu; q += d * d;
    d = v0.z - mu; q += d * d; d = v0.w - mu; q += d * d;
    d = v1.x - mu; q += d * d; d = v1.y - mu; q += d * d;
    d = v1.z - mu; q += d * d; d = v1.w - mu; q += d * d;
    d = v2.x - mu; q += d * d; d = v2.y - mu; q += d * d;
    d = v2.z - mu; q += d * d; d = v2.w - mu; q += d * d;
  }
  #pragma unroll
  for (int o = 32; o; o >>= 1) q += __shfl_xor(q, o);
  float rs = rsqrtf(q * (1.f / 768.f) + 1e-5f);
  const float4* gr = (const float4*)gam;
  const float4* br = (const float4*)bet;
  ushort4* orow = (ushort4*)(out + row * 768);
  float4 vv[3] = {v0, v1, v2};
  #pragma unroll
  for (int i = 0; i < 3; ++i) {
    int c4 = lane + i * 64;
    float4 g4 = gr[c4], b4 = br[c4];
    ushort4 o;
    o.x = f2b((vv[i].x - mu) * rs * g4.x + b4.x);
    o.y = f2b((vv[i].y - mu) * rs * g4.y + b4.y);
    o.z = f2b((vv[i].z - mu) * rs * g4.z + b4.z);
    o.w = f2b((vv[i].w - mu) * rs * g4.w + b4.w);
    orow[c4] = o;
  }
}

// -------- split-K reduce (2 slices) + residual(src) + LayerNorm ----------
__global__ __launch_bounds__(256) void reduce_ln(
    const float* __restrict__ Pp, const float* __restrict__ src,
    const float* __restrict__ gam, const float* __restrict__ bet,
    float* __restrict__ xbuf, unsigned short* __restrict__ hbf) {
  int w = threadIdx.x >> 6, lane = threadIdx.x & 63;
  size_t row = (size_t)blockIdx.x * 4 + w;
  const float4* s4 = (const float4*)(src + row * 768);
  const float4* p0 = (const float4*)(Pp + row * 768);
  const float4* p1 = (const float4*)(Pp + 3145728 + row * 768);
  float4* xb4 = (float4*)(xbuf + row * 768);
  float4 xv[3];
  float s = 0.f;
  #pragma unroll
  for (int j = 0; j < 3; ++j) {
    int c4 = lane + j * 64;
    float4 a = s4[c4], b = p0[c4], c = p1[c4];
    float4 x;
    x.x = a.x + b.x + c.x; x.y = a.y + b.y + c.y;
    x.z = a.z + b.z + c.z; x.w = a.w + b.w + c.w;
    xv[j] = x;
    xb4[c4] = x;
    s += x.x + x.y + x.z + x.w;
  }
  #pragma unroll
  for (int o = 32; o; o >>= 1) s += __shfl_xor(s, o);
  float mu = s * (1.f / 768.f);
  float q = 0.f;
  #pragma unroll
  for (int j = 0; j < 3; ++j) {
    float d;
    d = xv[j].x - mu; q += d * d; d = xv[j].y - mu; q += d * d;
    d = xv[j].z - mu; q += d * d; d = xv[j].w - mu; q += d * d;
  }
  #pragma unroll
  for (int o = 32; o; o >>= 1) q += __shfl_xor(q, o);
  float rs = rsqrtf(q * (1.f / 768.f) + 1e-5f);
  const float4* gr = (const float4*)gam;
  const float4* br = (const float4*)bet;
  ushort4* orow = (ushort4*)(hbf + row * 768);
  #pragma unroll
  for (int j = 0; j < 3; ++j) {
    int c4 = lane + j * 64;
    float4 g4 = gr[c4], b4 = br[c4];
    ushort4 o;
    o.x = f2b((xv[j].x - mu) * rs * g4.x + b4.x);
    o.y = f2b((xv[j].y - mu) * rs * g4.y + b4.y);
    o.z = f2b((xv[j].z - mu) * rs * g4.z + b4.z);
    o.w = f2b((xv[j].w - mu) * rs * g4.w + b4.w);
    orow[c4] = o;
  }
}

// -------- split-K reduce (2 slices) + residual(xbuf) + bias -> d_out -----
__global__ __launch_bounds__(256) void reduce_out(
    const float* __restrict__ Pp, const float* __restrict__ xbuf,
    const float* __restrict__ bias, float* __restrict__ outp) {
  int i = blockIdx.x * 256 + threadIdx.x;  // f4 idx, [0, 786432)
  int r = i / 192;
  int c4 = i - r * 192;
  float4 b4 = ((const float4*)bias)[c4];
  float4 x = ((const float4*)xbuf)[i];
  float4 p0 = ((const float4*)Pp)[i];
  float4 p1 = ((const float4*)(Pp + 3145728))[i];
  float4 o;
  o.x = x.x + b4.x + p0.x + p1.x;
  o.y = x.y + b4.y + p0.y + p1.y;
  o.z = x.z + b4.z + p0.z + p1.z;
  o.w = x.w + b4.w + p0.w + p1.w;
  ((float4*)outp)[i] = o;
}

// ---------------- causal depthwise conv(4) + bias + SiLU -> bf16 ----------
__global__ __launch_bounds__(256) void conv_silu(const float* __restrict__ xres,
                                                 const float* __restrict__ cw,
                                                 const float* __restrict__ cb,
                                                 unsigned short* __restrict__ xs_act) {
  int idx = blockIdx.x * 256 + threadIdx.x;  // 4096*384
  int t = idx / 384;
  int c4 = idx - t * 384;
  int pos = t & 1023;
  const float* base = xres + (size_t)t * 3072 + c4 * 4;
  float4 z = {0.f, 0.f, 0.f, 0.f};
  float4 x3 = *(const float4*)base;
  float4 x2 = (pos >= 1) ? *(const float4*)(base - 3072) : z;
  float4 x1 = (pos >= 2) ? *(const float4*)(base - 6144) : z;
  float4 x0 = (pos >= 3) ? *(const float4*)(base - 9216) : z;
  float a0[4] = {x0.x, x0.y, x0.z, x0.w};
  float a1[4] = {x1.x, x1.y, x1.z, x1.w};
  float a2[4] = {x2.x, x2.y, x2.z, x2.w};
  float a3[4] = {x3.x, x3.y, x3.z, x3.w};
  ushort4 o;
  unsigned short* op = &o.x;
  #pragma unroll
  for (int i = 0; i < 4; ++i) {
    int dd = c4 * 4 + i;
    float4 wv = *(const float4*)(cw + dd * 4);
    float v = wv.x * a0[i] + wv.y * a1[i] + wv.z * a2[i] + wv.w * a3[i] + cb[dd];
    float sv = v * RCPF(1.f + __expf(-v));
    op[i] = f2b(sv);
  }
  *(ushort4*)(xs_act + (size_t)t * 1536 + c4 * 4) = o;
}

// ================== chunked selective scan (32 chunks x 32 steps) =========
// dsp (4096x1536 fp32) holds softplus(delta + dt_bias); projBC (4096x32)
// holds B|C compact. Lane layout: 2 lanes per d, 8 n-states in registers.
// grid = b(4) * dtile(12) * chunk(32) = 1536 blocks.
__global__ __launch_bounds__(256) void scan_p1(
    const float* __restrict__ dsp, const unsigned short* __restrict__ u_bf,
    const float* __restrict__ projBC, const float* __restrict__ A_log,
    float* __restrict__ xdead) {
  int tid = threadIdx.x;
  int dl = tid >> 1;
  int nh = (tid & 1) * 8;
  int blk = blockIdx.x;
  int c = blk & 31;
  int bt = blk >> 5;
  int b = bt / 12;
  int dtile = bt - b * 12;
  int d = dtile * 128 + dl;
  float Al2[8];
  {
    float4 a0 = *(const float4*)(A_log + d * 16 + nh);
    float4 a1 = *(const float4*)(A_log + d * 16 + nh + 4);
    const float L2E = 1.4426950408889634f;
    Al2[0] = -__expf(a0.x) * L2E; Al2[1] = -__expf(a0.y) * L2E;
    Al2[2] = -__expf(a0.z) * L2E; Al2[3] = -__expf(a0.w) * L2E;
    Al2[4] = -__expf(a1.x) * L2E; Al2[5] = -__expf(a1.y) * L2E;
    Al2[6] = -__expf(a1.z) * L2E; Al2[7] = -__expf(a1.w) * L2E;
  }
  const float* base_d = dsp + (size_t)b * 1024 * 1536 + d;
  const float* base_bc = projBC + (size_t)b * 1024 * 32 + nh;
  const unsigned short* ub = u_bf + (size_t)b * 1024 * 1536 + d;
  float h[8];
  #pragma unroll
  for (int k = 0; k < 8; ++k) h[k] = 0.f;
  float S = 0.f;
  int t0 = c * 32;
  float dspA = base_d[(size_t)t0 * 1536];
  float utA = b2f(ub[(size_t)t0 * 1536]);
  float4 B0A = *(const float4*)(base_bc + (size_t)t0 * 32);
  float4 B1A = *(const float4*)(base_bc + (size_t)t0 * 32 + 4);
  float dspB, utB;
  float4 B0B, B1B;
#define P1_BODY(DSP, UT, B0, B1)                                   \
  {                                                                \
    S += DSP;                                                      \
    float du = DSP * UT;                                           \
    float Bv[8] = {B0.x, B0.y, B0.z, B0.w, B1.x, B1.y, B1.z, B1.w};\
    _Pragma("unroll")                                              \
    for (int k = 0; k < 8; ++k) {                                  \
      float dA = EXP2F(DSP * Al2[k]);                              \
      h[k] = __builtin_fmaf(dA, h[k], du * Bv[k]);                 \
    }                                                              \
  }
  for (int s = 0; s < 32; s += 2) {
    size_t t1 = t0 + s + 1;
    dspB = base_d[t1 * 1536];
    utB = b2f(ub[t1 * 1536]);
    B0B = *(const float4*)(base_bc + t1 * 32);
    B1B = *(const float4*)(base_bc + t1 * 32 + 4);
    P1_BODY(dspA, utA, B0A, B1A);
    int t2i = t0 + s + 2; if (t2i > 1023) t2i = 1023;
    size_t t2 = t2i;
    dspA = base_d[t2 * 1536];
    utA = b2f(ub[t2 * 1536]);
    B0A = *(const float4*)(base_bc + t2 * 32);
    B1A = *(const float4*)(base_bc + t2 * 32 + 4);
    P1_BODY(dspB, utB, B0B, B1B);
  }
#undef P1_BODY
  int j = c * 98304 + (b * 1536 + d) * 16 + nh;
  size_t hp = hole(j);
  xdead[hp]     = EXP2F(Al2[0] * S);
  xdead[hp + 1] = EXP2F(Al2[1] * S);
  xdead[hp + 2] = EXP2F(Al2[2] * S);
  xdead[hp + 3] = EXP2F(Al2[3] * S);
  xdead[hp + 4] = EXP2F(Al2[4] * S);
  xdead[hp + 5] = EXP2F(Al2[5] * S);
  xdead[hp + 6] = EXP2F(Al2[6] * S);
  xdead[hp + 7] = EXP2F(Al2[7] * S);
  float* he = xdead + hp + HOLE2;
  *(float4*)he = make_float4(h[0], h[1], h[2], h[3]);
  *(float4*)(he + 4) = make_float4(h[4], h[5], h[6], h[7]);
}

// P2: per (b,d,n) combine 32 chunks; store each chunk's true initial state
// in-place over the P slot.
__global__ __launch_bounds__(256) void scan_p2(float* __restrict__ xdead) {
  int i = blockIdx.x * 256 + threadIdx.x;  // [0, 98304)
  float H = 0.f;
  #pragma unroll
  for (int c = 0; c < 32; ++c) {
    int j = c * 98304 + i;
    size_t hp = hole(j);
    float P = xdead[hp];
    float he = xdead[hp + HOLE2];
    xdead[hp] = H;
    H = __builtin_fmaf(P, H, he);
  }
}

// P3: replay each chunk from its true H_init; reduce over n in-register +
// one DPP-xor1 across the lane pair; fuse +u*D and *silu(res); bf16 y out.
__global__ __launch_bounds__(256) void scan_p3(
    const float* __restrict__ dsp, const unsigned short* __restrict__ u_bf,
    const float* __restrict__ projBC, const float* __restrict__ xres,
    const float* __restrict__ A_log, const float* __restrict__ D_param,
    unsigned short* __restrict__ y_out) {
  int tid = threadIdx.x;
  int dl = tid >> 1;
  int nh = (tid & 1) * 8;
  int blk = blockIdx.x;
  int c = blk & 31;
  int bt = blk >> 5;
  int b = bt / 12;
  int dtile = bt - b * 12;
  int d = dtile * 128 + dl;
  float Dp = D_param[d];
  float Al2[8];
  {
    float4 a0 = *(const float4*)(A_log + d * 16 + nh);
    float4 a1 = *(const float4*)(A_log + d * 16 + nh + 4);
    const float L2E = 1.4426950408889634f;
    Al2[0] = -__expf(a0.x) * L2E; Al2[1] = -__expf(a0.y) * L2E;
    Al2[2] = -__expf(a0.z) * L2E; Al2[3] = -__expf(a0.w) * L2E;
    Al2[4] = -__expf(a1.x) * L2E; Al2[5] = -__expf(a1.y) * L2E;
    Al2[6] = -__expf(a1.z) * L2E; Al2[7] = -__expf(a1.w) * L2E;
  }
  const float* base_d = dsp + (size_t)b * 1024 * 1536 + d;
  const float* base_bc = projBC + (size_t)b * 1024 * 32 + nh;
  const unsigned short* ub = u_bf + (size_t)b * 1024 * 1536 + d;
  const float* rbase = xres + (size_t)b * 1024 * 3072 + 1536 + d;
  unsigned short* yrow = y_out + (size_t)b * 1024 * 1536 + d;
  int j = c * 98304 + (b * 1536 + d) * 16 + nh;
  float h[8];
  {
    size_t hp = hole(j);
    float4 h0 = *(const float4*)(xres + hp);
    float4 h1 = *(const float4*)(xres + hp + 4);
    h[0] = h0.x; h[1] = h0.y; h[2] = h0.z; h[3] = h0.w;
    h[4] = h1.x; h[5] = h1.y; h[6] = h1.z; h[7] = h1.w;
  }
  int t0 = c * 32;
  float dspA = base_d[(size_t)t0 * 1536];
  float utA = b2f(ub[(size_t)t0 * 1536]);
  float4 B0A = *(const float4*)(base_bc + (size_t)t0 * 32);
  float4 B1A = *(const float4*)(base_bc + (size_t)t0 * 32 + 4);
  float4 C0A = *(const float4*)(base_bc + (size_t)t0 * 32 + 16);
  float4 C1A = *(const float4*)(base_bc + (size_t)t0 * 32 + 20);
  float rA = rbase[(size_t)t0 * 3072];
  float dspB, utB, rB;
  float4 B0B, B1B, C0B, C1B;
#define P3_BODY(DSP, UT, B0, B1, C0, C1, RV, TT)                   \
  {                                                                \
    float du = DSP * UT;                                           \
    float Bv[8] = {B0.x, B0.y, B0.z, B0.w, B1.x, B1.y, B1.z, B1.w};\
    float Cv[8] = {C0.x, C0.y, C0.z, C0.w, C1.x, C1.y, C1.z, C1.w};\
    float p0 = 0.f, p1v = 0.f;                                     \
    _Pragma("unroll")                                              \
    for (int k = 0; k < 8; ++k) {                                  \
      float dA = EXP2F(DSP * Al2[k]);                              \
      h[k] = __builtin_fmaf(dA, h[k], du * Bv[k]);                 \
      if (k & 1) p1v = __builtin_fmaf(h[k], Cv[k], p1v);           \
      else       p0  = __builtin_fmaf(h[k], Cv[k], p0);            \
    }                                                              \
    float p = p0 + p1v;                                            \
    p += __int_as_float(__builtin_amdgcn_update_dpp(               \
        0, __float_as_int(p), 0xB1, 0xF, 0xF, true));              \
    if (nh == 0) {                                                 \
      float sr = RV * RCPF(1.f + __expf(-RV));                     \
      yrow[(size_t)(TT) * 1536] = f2b(__builtin_fmaf(UT, Dp, p) * sr); \
    }                                                              \
  }
  for (int s = 0; s < 32; s += 2) {
    size_t t1 = t0 + s + 1;
    dspB = base_d[t1 * 1536];
    utB = b2f(ub[t1 * 1536]);
    B0B = *(const float4*)(base_bc + t1 * 32);
    B1B = *(const float4*)(base_bc + t1 * 32 + 4);
    C0B = *(const float4*)(base_bc + t1 * 32 + 16);
    C1B = *(const float4*)(base_bc + t1 * 32 + 20);
    rB = rbase[t1 * 3072];
    P3_BODY(dspA, utA, B0A, B1A, C0A, C1A, rA, t0 + s);
    int t2i = t0 + s + 2; if (t2i > 1023) t2i = 1023;
    size_t t2 = t2i;
    dspA = base_d[t2 * 1536];
    utA = b2f(ub[t2 * 1536]);
    B0A = *(const float4*)(base_bc + t2 * 32);
    B1A = *(const float4*)(base_bc + t2 * 32 + 4);
    C0A = *(const float4*)(base_bc + t2 * 32 + 16);
    C1A = *(const float4*)(base_bc + t2 * 32 + 20);
    rA = rbase[t2 * 3072];
    P3_BODY(dspB, utB, B0B, B1B, C0B, C1B, rB, t1);
  }
#undef P3_BODY
}

// ------------- bf16 MFMA GEMM: C(MxN) = A(MxK) @ B(NxK)^T ----------------
// Double-buffered LDS, prefetch-before-compute, XOR-swizzled staging.
// Split-K via gridDim.z (each z-slice covers K/gridDim.z).
// MODE 0: C fp32 = acc
// MODE 2: C bf16 = gelu(acc+bias)
// MODE 5: partial fp32 at Cf + z*M*N
// MODE 6: C fp32 = softplus(acc + bias[col])
template <int MODE, int BM>
__global__ __launch_bounds__(256, 2) void gemm_bt(
    const unsigned short* __restrict__ A, const unsigned short* __restrict__ B,
    int M, int N, int K, float* __restrict__ Cf, unsigned short* __restrict__ Cb,
    const float* __restrict__ res, const float* __restrict__ bias) {
  constexpr int NFR = (BM == 128) ? 4 : 2;   // B frags per wave
  constexpr int AIT = BM / 64;               // A staging instrs per thread
  __shared__ __align__(16) unsigned short As[2][BM * 32];
  __shared__ __align__(16) unsigned short Bs[2][128 * 32];
  int tid = threadIdx.x;
  int lane = tid & 63;
  int w = tid >> 6;
  int wm = (BM == 128) ? (w >> 1) : 0;
  int wn = (BM == 128) ? (w & 1) : w;
  int row0 = blockIdx.y * BM;
  int col0 = blockIdx.x * 128;
  const int lr = lane & 15;
  const int kb = lane >> 4;
  int ksl = K / gridDim.z;
  int kbeg = blockIdx.z * ksl;

  f32x4 acc[4][NFR];
  #pragma unroll
  for (int i = 0; i < 4; ++i)
    #pragma unroll
    for (int j = 0; j < NFR; ++j) acc[i][j] = (f32x4)0.f;

  auto stage = [&](int buf, int k0) {
    #pragma unroll
    for (int j = 0; j < AIT; ++j) {
      int e = j * 256 + tid;
      int r = e >> 2, cc = e & 3;
      int sc = cc ^ ((r >> 1) & 3);
      gload_lds16(A + (size_t)(row0 + r) * K + k0 + sc * 8, &As[buf][e * 8]);
    }
    #pragma unroll
    for (int j = 0; j < 2; ++j) {
      int e = j * 256 + tid;
      int r = e >> 2, cc = e & 3;
      int sc = cc ^ ((r >> 1) & 3);
      gload_lds16(B + (size_t)(col0 + r) * K + k0 + sc * 8, &Bs[buf][e * 8]);
    }
  };

  stage(0, kbeg);
  __syncthreads();

  int nt = ksl >> 5;
  int cur = 0;
  for (int t = 0; t < nt; ++t) {
    if (t + 1 < nt) stage(cur ^ 1, kbeg + ((t + 1) << 5));
    s16x8 af[4], bfm[NFR];
    #pragma unroll
    for (int m = 0; m < 4; ++m) {
      int rr = wm * 64 + m * 16 + lr;
      int chunk = rr * 4 + (kb ^ ((rr >> 1) & 3));
      af[m] = *(const s16x8*)&As[cur][chunk * 8];
    }
    #pragma unroll
    for (int nn = 0; nn < NFR; ++nn) {
      int rr = wn * (16 * NFR) + nn * 16 + lr;
      int chunk = rr * 4 + (kb ^ ((rr >> 1) & 3));
      bfm[nn] = *(const s16x8*)&Bs[cur][chunk * 8];
    }
    #pragma unroll
    for (int m = 0; m < 4; ++m)
      #pragma unroll
      for (int nn = 0; nn < NFR; ++nn)
        acc[m][nn] = __builtin_amdgcn_mfma_f32_16x16x32_bf16(af[m], bfm[nn], acc[m][nn], 0, 0, 0);
    __syncthreads();
    cur ^= 1;
  }

  size_t zoff = (size_t)blockIdx.z * M * N;
  #pragma unroll
  for (int m = 0; m < 4; ++m) {
    int rbase = row0 + wm * 64 + m * 16 + kb * 4;
    #pragma unroll
    for (int nn = 0; nn < NFR; ++nn) {
      int col = col0 + wn * (16 * NFR) + nn * 16 + lr;
      #pragma unroll
      for (int r = 0; r < 4; ++r) {
        int row = rbase + r;
        size_t idx = (size_t)row * N + col;
        float v = acc[m][nn][r];
        if (MODE == 0) {
          Cf[idx] = v;
        } else if (MODE == 2) {
          float tt = v + bias[col];
          float gl = 0.5f * tt * (1.f + erff(tt * 0.7071067811865475f));
          Cb[idx] = f2b(gl);
        } else if (MODE == 5) {
          Cf[zoff + idx] = v;
        } else {  // MODE 6
          float xx = v + bias[col];
          Cf[idx] = (xx > 20.f) ? xx : __logf(1.f + __expf(xx));
        }
      }
    }
  }
}

extern "C" void kernel_launch(void* const* d_in, const int* in_sizes, int n_in,
                              void* d_out, int out_size, void* d_ws, size_t ws_size,
                              hipStream_t stream) {
  (void)in_sizes; (void)n_in; (void)out_size; (void)ws_size;
  const float* src   = (const float*)d_in[0];
  const float* n1g   = (const float*)d_in[1];
  const float* n1b   = (const float*)d_in[2];
  const float* inW   = (const float*)d_in[3];
  const float* convW = (const float*)d_in[4];
  const float* convB = (const float*)d_in[5];
  const float* xpW   = (const float*)d_in[6];
  const float* dtW   = (const float*)d_in[7];
  const float* dtB   = (const float*)d_in[8];
  const float* Alog  = (const float*)d_in[9];
  const float* Dpar  = (const float*)d_in[10];
  const float* outW  = (const float*)d_in[11];
  const float* n2g   = (const float*)d_in[12];
  const float* n2b   = (const float*)d_in[13];
  const float* w1    = (const float*)d_in[14];
  const float* b1    = (const float*)d_in[15];
  const float* w2    = (const float*)d_in[16];
  const float* b2    = (const float*)d_in[17];

  char* ws = (char*)d_ws;
  unsigned short* wbA   = (unsigned short*)(ws + 0);          // in_proj bf16  (3072x768)
  unsigned short* wbO   = (unsigned short*)(ws + 4718592);    // out_proj bf16 (768x1536)
  unsigned short* wb1   = (unsigned short*)(ws + 7077888);    // w1 bf16       (3072x768)
  unsigned short* wb2   = (unsigned short*)(ws + 11796480);   // w2 bf16       (768x3072)
  unsigned short* wpad  = (unsigned short*)(ws + 16515072);   // x_proj padded (128x1536) bf16
  unsigned short* wdt   = (unsigned short*)(ws + 16908288);   // dt_proj padded (1536x64) bf16
  unsigned short* hbf   = (unsigned short*)(ws + 21626880);   // (4096x768) bf16 LN outputs
  float*          xres  = (float*)(ws + 27918336);            // (4096x3072) fp32; dead xs half = scan scratch;
                                                              // whole region = out/ffn2 split-K partials later
  float*          Ppart = (float*)(ws + 27918336);            // 2 x (4096x768) fp32 partials
  unsigned short* xsact = (unsigned short*)(ws + 78249984);   // (4096x1536) bf16 conv output (= u)
  float*          xbuf  = (float*)(ws + 78249984);            // (4096x768) fp32 (reuse, after scan)
  float*          dsp   = (float*)(ws + 90832896);            // (4096x1536) fp32 softplus(delta)
  unsigned short* ff1   = (unsigned short*)(ws + 90832896);   // (4096x3072) bf16 (reuse, after scan)
  float*          projBC= (float*)(ws + 115998720);           // (4096x32) fp32: B | C
  unsigned short* dtbf  = (unsigned short*)(ws + 116523008);  // (4096x64) bf16 dt padded
  float*          Pa    = (float*)(ws + 118095872);           // stage-A partials 4x(4096x128) fp32 (pre-scan)
  unsigned short* ybuf  = (unsigned short*)(ws + 118095872);  // (4096x1536) bf16 (scan output)
  float* outp = (float*)d_out;

  // weight prep
  cvt_all<<<8064, 256, 0, stream>>>(inW, outW, w1, w2, wbA, wbO, wb1, wb2);
  build_proj<<<1152, 256, 0, stream>>>(xpW, dtW, wpad, wdt);

  // mamba block
  ln_kernel<<<1024, 256, 0, stream>>>(src, n1g, n1b, hbf);
  gemm_bt<0, 128><<<dim3(24, 32), 256, 0, stream>>>(hbf, wbA, 4096, 3072, 768, xres, nullptr, nullptr, nullptr);
  conv_silu<<<6144, 256, 0, stream>>>(xres, convW, convB, xsact);

  // x_proj (N=80 padded to 128), split-K=4 -> reduce -> delta GEMM (K=64)
  gemm_bt<5, 64><<<dim3(1, 64, 4), 256, 0, stream>>>(xsact, wpad, 4096, 128, 1536, Pa, nullptr, nullptr, nullptr);
  reduce_projA<<<2048, 256, 0, stream>>>(Pa, dtbf, projBC);
  gemm_bt<6, 128><<<dim3(12, 32), 256, 0, stream>>>(dtbf, wdt, 4096, 1536, 64, dsp, nullptr, nullptr, dtB);

  scan_p1<<<1536, 256, 0, stream>>>(dsp, xsact, projBC, Alog, xres);
  scan_p2<<<384, 256, 0, stream>>>(xres);
  scan_p3<<<1536, 256, 0, stream>>>(dsp, xsact, projBC, xres, Alog, Dpar, ybuf);

  // out_proj split-K=2 (partials into dead xres) + fused residual+LN2
  gemm_bt<5, 64><<<dim3(6, 64, 2), 256, 0, stream>>>(ybuf, wbO, 4096, 768, 1536, Ppart, nullptr, nullptr, nullptr);
  reduce_ln<<<1024, 256, 0, stream>>>(Ppart, src, n2g, n2b, xbuf, hbf);

  // FFN block
  gemm_bt<2, 128><<<dim3(24, 32), 256, 0, stream>>>(hbf, wb1, 4096, 3072, 768, nullptr, ff1, nullptr, b1);
  gemm_bt<5, 64><<<dim3(6, 64, 2), 256, 0, stream>>>(ff1, wb2, 4096, 768, 3072, Ppart, nullptr, nullptr, nullptr);
  reduce_out<<<3072, 256, 0, stream>>>(Ppart, xbuf, b2, outp);
}

// Round 8
// 262.656 us; speedup vs baseline: 4.1424x; 1.0690x over previous
//
#include <hip/hip_runtime.h>
#include <cstdint>
#include <cstddef>

typedef __attribute__((ext_vector_type(4))) float f32x4;
typedef __attribute__((ext_vector_type(8))) short s16x8;

#if __has_builtin(__builtin_amdgcn_exp2f)
#define EXP2F(x) __builtin_amdgcn_exp2f(x)
#else
#define EXP2F(x) __expf((x) * 0.6931471805599453f)
#endif
#if __has_builtin(__builtin_amdgcn_rcpf)
#define RCPF(x) __builtin_amdgcn_rcpf(x)
#else
#define RCPF(x) (1.0f / (x))
#endif

__device__ inline unsigned short f2b(float f) {
  union { float f; unsigned u; } c; c.f = f;
  return (unsigned short)((c.u + 0x7FFFu + ((c.u >> 16) & 1u)) >> 16);
}
__device__ inline float b2f(unsigned short u) {
  union { unsigned u; float f; } c; c.u = ((unsigned)u) << 16;
  return c.f;
}

__device__ inline void gload_lds16(const void* g, void* l) {
  __builtin_amdgcn_global_load_lds(
      (const __attribute__((address_space(1))) unsigned int*)g,
      (__attribute__((address_space(3))) unsigned int*)l, 16, 0, 0);
}

// raw barrier: no compiler-inserted vmcnt(0) drain (that drain is the
// __syncthreads pipeline-killer); "memory" clobber pins LDS/global op order.
#define RAW_BARRIER() asm volatile("s_barrier" ::: "memory")

// Scan scratch lives in the dead first-half columns of xres (cols 0..1535,
// all 4096 rows dead after conv_silu). j -> P slot; +HOLE2 -> h_end slot.
#define HOLE2 6291456
__device__ inline size_t hole(int j) {
  int r = j / 1536;
  int c = j - r * 1536;
  return (size_t)r * 3072 + c;
}

// ------------- fused fp32 -> bf16 convert for the 4 weight tensors --------
__global__ __launch_bounds__(256) void cvt_all(const float* __restrict__ inW,
                                               const float* __restrict__ outW,
                                               const float* __restrict__ w1,
                                               const float* __restrict__ w2,
                                               unsigned short* __restrict__ wbA,
                                               unsigned short* __restrict__ wbO,
                                               unsigned short* __restrict__ wb1,
                                               unsigned short* __restrict__ wb2) {
  int i = blockIdx.x * 256 + threadIdx.x;  // [0, 2064384) float4 units
  const float* src;
  unsigned short* dst;
  int o;
  if (i < 589824)       { src = inW;  dst = wbA; o = i; }
  else if (i < 884736)  { src = outW; dst = wbO; o = i - 589824; }
  else if (i < 1474560) { src = w1;   dst = wb1; o = i - 884736; }
  else                  { src = w2;   dst = wb2; o = i - 1474560; }
  float4 v = ((const float4*)src)[o];
  ushort4 u;
  u.x = f2b(v.x); u.y = f2b(v.y); u.z = f2b(v.z); u.w = f2b(v.w);
  ((ushort4*)dst)[o] = u;
}

// ------- build padded projection weights:
//   wpad (128 x 1536 bf16): rows 0..79 = x_proj_w, rows 80..127 = 0
//   wdt  (1536 x 64 bf16):  cols 0..47 = dt_proj_w, cols 48..63 = 0
__global__ __launch_bounds__(256) void build_proj(const float* __restrict__ xpw,
                                                  const float* __restrict__ dtw,
                                                  unsigned short* __restrict__ wpad,
                                                  unsigned short* __restrict__ wdt) {
  int i = blockIdx.x * 256 + threadIdx.x;  // < 294912
  if (i < 196608) {
    int row = i / 1536;
    wpad[i] = (row < 80) ? f2b(xpw[i]) : (unsigned short)0;
  } else {
    int j = i - 196608;  // < 98304
    int row = j >> 6, k = j & 63;
    wdt[j] = (k < 48) ? f2b(dtw[row * 48 + k]) : (unsigned short)0;
  }
}

// ---- reduce stage-A split-K partials (4 slices of 4096x128) ----
// cols 0..47 -> dt (bf16, padded to 64); cols 48..79 -> projBC fp32 (B|C)
__global__ __launch_bounds__(256) void reduce_projA(const float* __restrict__ Pa,
                                                    unsigned short* __restrict__ dtbf,
                                                    float* __restrict__ projBC) {
  int i = blockIdx.x * 256 + threadIdx.x;  // < 524288
  int row = i >> 7, col = i & 127;
  float s = Pa[i] + Pa[i + 524288] + Pa[i + 1048576] + Pa[i + 1572864];
  if (col < 48) {
    dtbf[row * 64 + col] = f2b(s);
  } else if (col < 64) {
    dtbf[row * 64 + col] = 0;
    projBC[row * 32 + col - 48] = s;
  } else if (col < 80) {
    projBC[row * 32 + col - 48] = s;
  }
}

// ---------------- LayerNorm over 768, one wave per row, bf16 out ----------
__global__ __launch_bounds__(256) void ln_kernel(const float* __restrict__ x,
                                                 const float* __restrict__ gam,
                                                 const float* __restrict__ bet,
                                                 unsigned short* __restrict__ out) {
  int w = threadIdx.x >> 6, lane = threadIdx.x & 63;
  size_t row = (size_t)blockIdx.x * 4 + w;
  const float4* xr = (const float4*)(x + row * 768);
  float4 v0 = xr[lane], v1 = xr[lane + 64], v2 = xr[lane + 128];
  float s = v0.x + v0.y + v0.z + v0.w + v1.x + v1.y + v1.z + v1.w +
            v2.x + v2.y + v2.z + v2.w;
  #pragma unroll
  for (int o = 32; o; o >>= 1) s += __shfl_xor(s, o);
  float mu = s * (1.f / 768.f);
  float q = 0.f;
  {
    float d;
    d = v0.x - mu; q += d * d; d = v0.y - mu; q += d * d;
    d = v0.z - mu; q += d * d; d = v0.w - mu; q += d * d;
    d = v1.x - mu; q += d * d; d = v1.y - mu; q += d * d;
    d = v1.z - mu; q += d * d; d = v1.w - mu; q += d * d;
    d = v2.x - mu; q += d * d; d = v2.y - mu; q += d * d;
    d = v2.z - mu; q += d * d; d = v2.w - mu; q += d * d;
  }
  #pragma unroll
  for (int o = 32; o; o >>= 1) q += __shfl_xor(q, o);
  float rs = rsqrtf(q * (1.f / 768.f) + 1e-5f);
  const float4* gr = (const float4*)gam;
  const float4* br = (const float4*)bet;
  ushort4* orow = (ushort4*)(out + row * 768);
  float4 vv[3] = {v0, v1, v2};
  #pragma unroll
  for (int i = 0; i < 3; ++i) {
    int c4 = lane + i * 64;
    float4 g4 = gr[c4], b4 = br[c4];
    ushort4 o;
    o.x = f2b((vv[i].x - mu) * rs * g4.x + b4.x);
    o.y = f2b((vv[i].y - mu) * rs * g4.y + b4.y);
    o.z = f2b((vv[i].z - mu) * rs * g4.z + b4.z);
    o.w = f2b((vv[i].w - mu) * rs * g4.w + b4.w);
    orow[c4] = o;
  }
}

// -------- split-K reduce (2 slices) + residual(src) + LayerNorm ----------
__global__ __launch_bounds__(256) void reduce_ln(
    const float* __restrict__ Pp, const float* __restrict__ src,
    const float* __restrict__ gam, const float* __restrict__ bet,
    float* __restrict__ xbuf, unsigned short* __restrict__ hbf) {
  int w = threadIdx.x >> 6, lane = threadIdx.x & 63;
  size_t row = (size_t)blockIdx.x * 4 + w;
  const float4* s4 = (const float4*)(src + row * 768);
  const float4* p0 = (const float4*)(Pp + row * 768);
  const float4* p1 = (const float4*)(Pp + 3145728 + row * 768);
  float4* xb4 = (float4*)(xbuf + row * 768);
  float4 xv[3];
  float s = 0.f;
  #pragma unroll
  for (int j = 0; j < 3; ++j) {
    int c4 = lane + j * 64;
    float4 a = s4[c4], b = p0[c4], c = p1[c4];
    float4 x;
    x.x = a.x + b.x + c.x; x.y = a.y + b.y + c.y;
    x.z = a.z + b.z + c.z; x.w = a.w + b.w + c.w;
    xv[j] = x;
    xb4[c4] = x;
    s += x.x + x.y + x.z + x.w;
  }
  #pragma unroll
  for (int o = 32; o; o >>= 1) s += __shfl_xor(s, o);
  float mu = s * (1.f / 768.f);
  float q = 0.f;
  #pragma unroll
  for (int j = 0; j < 3; ++j) {
    float d;
    d = xv[j].x - mu; q += d * d; d = xv[j].y - mu; q += d * d;
    d = xv[j].z - mu; q += d * d; d = xv[j].w - mu; q += d * d;
  }
  #pragma unroll
  for (int o = 32; o; o >>= 1) q += __shfl_xor(q, o);
  float rs = rsqrtf(q * (1.f / 768.f) + 1e-5f);
  const float4* gr = (const float4*)gam;
  const float4* br = (const float4*)bet;
  ushort4* orow = (ushort4*)(hbf + row * 768);
  #pragma unroll
  for (int j = 0; j < 3; ++j) {
    int c4 = lane + j * 64;
    float4 g4 = gr[c4], b4 = br[c4];
    ushort4 o;
    o.x = f2b((xv[j].x - mu) * rs * g4.x + b4.x);
    o.y = f2b((xv[j].y - mu) * rs * g4.y + b4.y);
    o.z = f2b((xv[j].z - mu) * rs * g4.z + b4.z);
    o.w = f2b((xv[j].w - mu) * rs * g4.w + b4.w);
    orow[c4] = o;
  }
}

// -------- split-K reduce (2 slices) + residual(xbuf) + bias -> d_out -----
__global__ __launch_bounds__(256) void reduce_out(
    const float* __restrict__ Pp, const float* __restrict__ xbuf,
    const float* __restrict__ bias, float* __restrict__ outp) {
  int i = blockIdx.x * 256 + threadIdx.x;  // f4 idx, [0, 786432)
  int r = i / 192;
  int c4 = i - r * 192;
  float4 b4 = ((const float4*)bias)[c4];
  float4 x = ((const float4*)xbuf)[i];
  float4 p0 = ((const float4*)Pp)[i];
  float4 p1 = ((const float4*)(Pp + 3145728))[i];
  float4 o;
  o.x = x.x + b4.x + p0.x + p1.x;
  o.y = x.y + b4.y + p0.y + p1.y;
  o.z = x.z + b4.z + p0.z + p1.z;
  o.w = x.w + b4.w + p0.w + p1.w;
  ((float4*)outp)[i] = o;
}

// ---------------- causal depthwise conv(4) + bias + SiLU -> bf16 ----------
__global__ __launch_bounds__(256) void conv_silu(const float* __restrict__ xres,
                                                 const float* __restrict__ cw,
                                                 const float* __restrict__ cb,
                                                 unsigned short* __restrict__ xs_act) {
  int idx = blockIdx.x * 256 + threadIdx.x;  // 4096*384
  int t = idx / 384;
  int c4 = idx - t * 384;
  int pos = t & 1023;
  const float* base = xres + (size_t)t * 3072 + c4 * 4;
  float4 z = {0.f, 0.f, 0.f, 0.f};
  float4 x3 = *(const float4*)base;
  float4 x2 = (pos >= 1) ? *(const float4*)(base - 3072) : z;
  float4 x1 = (pos >= 2) ? *(const float4*)(base - 6144) : z;
  float4 x0 = (pos >= 3) ? *(const float4*)(base - 9216) : z;
  float a0[4] = {x0.x, x0.y, x0.z, x0.w};
  float a1[4] = {x1.x, x1.y, x1.z, x1.w};
  float a2[4] = {x2.x, x2.y, x2.z, x2.w};
  float a3[4] = {x3.x, x3.y, x3.z, x3.w};
  ushort4 o;
  unsigned short* op = &o.x;
  #pragma unroll
  for (int i = 0; i < 4; ++i) {
    int dd = c4 * 4 + i;
    float4 wv = *(const float4*)(cw + dd * 4);
    float v = wv.x * a0[i] + wv.y * a1[i] + wv.z * a2[i] + wv.w * a3[i] + cb[dd];
    float sv = v * RCPF(1.f + __expf(-v));
    op[i] = f2b(sv);
  }
  *(ushort4*)(xs_act + (size_t)t * 1536 + c4 * 4) = o;
}

// ================== chunked selective scan (32 chunks x 32 steps) =========
// dsp (4096x1536 fp32) holds softplus(delta + dt_bias); projBC (4096x32)
// holds B|C compact. Lane layout: 2 lanes per d, 8 n-states in registers.
// grid = b(4) * dtile(12) * chunk(32) = 1536 blocks.
__global__ __launch_bounds__(256) void scan_p1(
    const float* __restrict__ dsp, const unsigned short* __restrict__ u_bf,
    const float* __restrict__ projBC, const float* __restrict__ A_log,
    float* __restrict__ xdead) {
  int tid = threadIdx.x;
  int dl = tid >> 1;
  int nh = (tid & 1) * 8;
  int blk = blockIdx.x;
  int c = blk & 31;
  int bt = blk >> 5;
  int b = bt / 12;
  int dtile = bt - b * 12;
  int d = dtile * 128 + dl;
  float Al2[8];
  {
    float4 a0 = *(const float4*)(A_log + d * 16 + nh);
    float4 a1 = *(const float4*)(A_log + d * 16 + nh + 4);
    const float L2E = 1.4426950408889634f;
    Al2[0] = -__expf(a0.x) * L2E; Al2[1] = -__expf(a0.y) * L2E;
    Al2[2] = -__expf(a0.z) * L2E; Al2[3] = -__expf(a0.w) * L2E;
    Al2[4] = -__expf(a1.x) * L2E; Al2[5] = -__expf(a1.y) * L2E;
    Al2[6] = -__expf(a1.z) * L2E; Al2[7] = -__expf(a1.w) * L2E;
  }
  const float* base_d = dsp + (size_t)b * 1024 * 1536 + d;
  const float* base_bc = projBC + (size_t)b * 1024 * 32 + nh;
  const unsigned short* ub = u_bf + (size_t)b * 1024 * 1536 + d;
  float h[8];
  #pragma unroll
  for (int k = 0; k < 8; ++k) h[k] = 0.f;
  float S = 0.f;
  int t0 = c * 32;
  float dspA = base_d[(size_t)t0 * 1536];
  float utA = b2f(ub[(size_t)t0 * 1536]);
  float4 B0A = *(const float4*)(base_bc + (size_t)t0 * 32);
  float4 B1A = *(const float4*)(base_bc + (size_t)t0 * 32 + 4);
  float dspB, utB;
  float4 B0B, B1B;
#define P1_BODY(DSP, UT, B0, B1)                                   \
  {                                                                \
    S += DSP;                                                      \
    float du = DSP * UT;                                           \
    float Bv[8] = {B0.x, B0.y, B0.z, B0.w, B1.x, B1.y, B1.z, B1.w};\
    _Pragma("unroll")                                              \
    for (int k = 0; k < 8; ++k) {                                  \
      float dA = EXP2F(DSP * Al2[k]);                              \
      h[k] = __builtin_fmaf(dA, h[k], du * Bv[k]);                 \
    }                                                              \
  }
  for (int s = 0; s < 32; s += 2) {
    size_t t1 = t0 + s + 1;
    dspB = base_d[t1 * 1536];
    utB = b2f(ub[t1 * 1536]);
    B0B = *(const float4*)(base_bc + t1 * 32);
    B1B = *(const float4*)(base_bc + t1 * 32 + 4);
    P1_BODY(dspA, utA, B0A, B1A);
    int t2i = t0 + s + 2; if (t2i > 1023) t2i = 1023;
    size_t t2 = t2i;
    dspA = base_d[t2 * 1536];
    utA = b2f(ub[t2 * 1536]);
    B0A = *(const float4*)(base_bc + t2 * 32);
    B1A = *(const float4*)(base_bc + t2 * 32 + 4);
    P1_BODY(dspB, utB, B0B, B1B);
  }
#undef P1_BODY
  int j = c * 98304 + (b * 1536 + d) * 16 + nh;
  size_t hp = hole(j);
  xdead[hp]     = EXP2F(Al2[0] * S);
  xdead[hp + 1] = EXP2F(Al2[1] * S);
  xdead[hp + 2] = EXP2F(Al2[2] * S);
  xdead[hp + 3] = EXP2F(Al2[3] * S);
  xdead[hp + 4] = EXP2F(Al2[4] * S);
  xdead[hp + 5] = EXP2F(Al2[5] * S);
  xdead[hp + 6] = EXP2F(Al2[6] * S);
  xdead[hp + 7] = EXP2F(Al2[7] * S);
  float* he = xdead + hp + HOLE2;
  *(float4*)he = make_float4(h[0], h[1], h[2], h[3]);
  *(float4*)(he + 4) = make_float4(h[4], h[5], h[6], h[7]);
}

// P2: per (b,d,n) combine 32 chunks; store each chunk's true initial state
// in-place over the P slot.
__global__ __launch_bounds__(256) void scan_p2(float* __restrict__ xdead) {
  int i = blockIdx.x * 256 + threadIdx.x;  // [0, 98304)
  float H = 0.f;
  #pragma unroll
  for (int c = 0; c < 32; ++c) {
    int j = c * 98304 + i;
    size_t hp = hole(j);
    float P = xdead[hp];
    float he = xdead[hp + HOLE2];
    xdead[hp] = H;
    H = __builtin_fmaf(P, H, he);
  }
}

// P3: replay each chunk from its true H_init; reduce over n in-register +
// one DPP-xor1 across the lane pair; fuse +u*D and *silu(res); bf16 y out.
__global__ __launch_bounds__(256) void scan_p3(
    const float* __restrict__ dsp, const unsigned short* __restrict__ u_bf,
    const float* __restrict__ projBC, const float* __restrict__ xres,
    const float* __restrict__ A_log, const float* __restrict__ D_param,
    unsigned short* __restrict__ y_out) {
  int tid = threadIdx.x;
  int dl = tid >> 1;
  int nh = (tid & 1) * 8;
  int blk = blockIdx.x;
  int c = blk & 31;
  int bt = blk >> 5;
  int b = bt / 12;
  int dtile = bt - b * 12;
  int d = dtile * 128 + dl;
  float Dp = D_param[d];
  float Al2[8];
  {
    float4 a0 = *(const float4*)(A_log + d * 16 + nh);
    float4 a1 = *(const float4*)(A_log + d * 16 + nh + 4);
    const float L2E = 1.4426950408889634f;
    Al2[0] = -__expf(a0.x) * L2E; Al2[1] = -__expf(a0.y) * L2E;
    Al2[2] = -__expf(a0.z) * L2E; Al2[3] = -__expf(a0.w) * L2E;
    Al2[4] = -__expf(a1.x) * L2E; Al2[5] = -__expf(a1.y) * L2E;
    Al2[6] = -__expf(a1.z) * L2E; Al2[7] = -__expf(a1.w) * L2E;
  }
  const float* base_d = dsp + (size_t)b * 1024 * 1536 + d;
  const float* base_bc = projBC + (size_t)b * 1024 * 32 + nh;
  const unsigned short* ub = u_bf + (size_t)b * 1024 * 1536 + d;
  const float* rbase = xres + (size_t)b * 1024 * 3072 + 1536 + d;
  unsigned short* yrow = y_out + (size_t)b * 1024 * 1536 + d;
  int j = c * 98304 + (b * 1536 + d) * 16 + nh;
  float h[8];
  {
    size_t hp = hole(j);
    float4 h0 = *(const float4*)(xres + hp);
    float4 h1 = *(const float4*)(xres + hp + 4);
    h[0] = h0.x; h[1] = h0.y; h[2] = h0.z; h[3] = h0.w;
    h[4] = h1.x; h[5] = h1.y; h[6] = h1.z; h[7] = h1.w;
  }
  int t0 = c * 32;
  float dspA = base_d[(size_t)t0 * 1536];
  float utA = b2f(ub[(size_t)t0 * 1536]);
  float4 B0A = *(const float4*)(base_bc + (size_t)t0 * 32);
  float4 B1A = *(const float4*)(base_bc + (size_t)t0 * 32 + 4);
  float4 C0A = *(const float4*)(base_bc + (size_t)t0 * 32 + 16);
  float4 C1A = *(const float4*)(base_bc + (size_t)t0 * 32 + 20);
  float rA = rbase[(size_t)t0 * 3072];
  float dspB, utB, rB;
  float4 B0B, B1B, C0B, C1B;
#define P3_BODY(DSP, UT, B0, B1, C0, C1, RV, TT)                   \
  {                                                                \
    float du = DSP * UT;                                           \
    float Bv[8] = {B0.x, B0.y, B0.z, B0.w, B1.x, B1.y, B1.z, B1.w};\
    float Cv[8] = {C0.x, C0.y, C0.z, C0.w, C1.x, C1.y, C1.z, C1.w};\
    float p0 = 0.f, p1v = 0.f;                                     \
    _Pragma("unroll")                                              \
    for (int k = 0; k < 8; ++k) {                                  \
      float dA = EXP2F(DSP * Al2[k]);                              \
      h[k] = __builtin_fmaf(dA, h[k], du * Bv[k]);                 \
      if (k & 1) p1v = __builtin_fmaf(h[k], Cv[k], p1v);           \
      else       p0  = __builtin_fmaf(h[k], Cv[k], p0);            \
    }                                                              \
    float p = p0 + p1v;                                            \
    p += __int_as_float(__builtin_amdgcn_update_dpp(               \
        0, __float_as_int(p), 0xB1, 0xF, 0xF, true));              \
    if (nh == 0) {                                                 \
      float sr = RV * RCPF(1.f + __expf(-RV));                     \
      yrow[(size_t)(TT) * 1536] = f2b(__builtin_fmaf(UT, Dp, p) * sr); \
    }                                                              \
  }
  for (int s = 0; s < 32; s += 2) {
    size_t t1 = t0 + s + 1;
    dspB = base_d[t1 * 1536];
    utB = b2f(ub[t1 * 1536]);
    B0B = *(const float4*)(base_bc + t1 * 32);
    B1B = *(const float4*)(base_bc + t1 * 32 + 4);
    C0B = *(const float4*)(base_bc + t1 * 32 + 16);
    C1B = *(const float4*)(base_bc + t1 * 32 + 20);
    rB = rbase[t1 * 3072];
    P3_BODY(dspA, utA, B0A, B1A, C0A, C1A, rA, t0 + s);
    int t2i = t0 + s + 2; if (t2i > 1023) t2i = 1023;
    size_t t2 = t2i;
    dspA = base_d[t2 * 1536];
    utA = b2f(ub[t2 * 1536]);
    B0A = *(const float4*)(base_bc + t2 * 32);
    B1A = *(const float4*)(base_bc + t2 * 32 + 4);
    C0A = *(const float4*)(base_bc + t2 * 32 + 16);
    C1A = *(const float4*)(base_bc + t2 * 32 + 20);
    rA = rbase[t2 * 3072];
    P3_BODY(dspB, utB, B0B, B1B, C0B, C1B, rB, t1);
  }
#undef P3_BODY
}

// ------------- bf16 MFMA GEMM: C(MxN) = A(MxK) @ B(NxK)^T ----------------
// 2-deep pipelined LDS double-buffer with counted vmcnt + raw barriers
// (loads stay in flight across barriers; never drain to 0 mid-loop).
// Grid: blockIdx.x = M-tile (fastest -> XCD L2 weight-panel locality),
//       blockIdx.y = N-tile, blockIdx.z = K-slice (split-K).
// MODE 0: C fp32 = acc
// MODE 2: C bf16 = gelu(acc+bias)
// MODE 5: partial fp32 at Cf + z*M*N
// MODE 6: C fp32 = softplus(acc + bias[col])
template <int MODE, int BM>
__global__ __launch_bounds__(256, 2) void gemm_bt(
    const unsigned short* __restrict__ A, const unsigned short* __restrict__ B,
    int M, int N, int K, float* __restrict__ Cf, unsigned short* __restrict__ Cb,
    const float* __restrict__ res, const float* __restrict__ bias) {
  constexpr int NFR = (BM == 128) ? 4 : 2;   // B frags per wave
  constexpr int AIT = BM / 64;               // A staging instrs per thread
  __shared__ __align__(16) unsigned short As[2][BM * 32];
  __shared__ __align__(16) unsigned short Bs[2][128 * 32];
  int tid = threadIdx.x;
  int lane = tid & 63;
  int w = tid >> 6;
  int wm = (BM == 128) ? (w >> 1) : 0;
  int wn = (BM == 128) ? (w & 1) : w;
  int row0 = blockIdx.x * BM;
  int col0 = blockIdx.y * 128;
  const int lr = lane & 15;
  const int kb = lane >> 4;
  int ksl = K / gridDim.z;
  int kbeg = blockIdx.z * ksl;

  f32x4 acc[4][NFR];
  #pragma unroll
  for (int i = 0; i < 4; ++i)
    #pragma unroll
    for (int j = 0; j < NFR; ++j) acc[i][j] = (f32x4)0.f;

  auto stage = [&](int buf, int k0) {
    #pragma unroll
    for (int j = 0; j < AIT; ++j) {
      int e = j * 256 + tid;
      int r = e >> 2, cc = e & 3;
      int sc = cc ^ ((r >> 1) & 3);
      gload_lds16(A + (size_t)(row0 + r) * K + k0 + sc * 8, &As[buf][e * 8]);
    }
    #pragma unroll
    for (int j = 0; j < 2; ++j) {
      int e = j * 256 + tid;
      int r = e >> 2, cc = e & 3;
      int sc = cc ^ ((r >> 1) & 3);
      gload_lds16(B + (size_t)(col0 + r) * K + k0 + sc * 8, &Bs[buf][e * 8]);
    }
  };

  int nt = ksl >> 5;
  stage(0, kbeg);
  if (nt > 1) stage(1, kbeg + 32);

  int cur = 0;
  for (int t = 0; t < nt; ++t) {
    // wait for buf[cur]'s loads only; keep the newer stage's LPS loads
    // (AIT+2 per thread) in flight across the barrier.
    if (t + 1 < nt) {
      if (BM == 128) asm volatile("s_waitcnt vmcnt(4)" ::: "memory");
      else           asm volatile("s_waitcnt vmcnt(3)" ::: "memory");
    } else {
      asm volatile("s_waitcnt vmcnt(0)" ::: "memory");
    }
    RAW_BARRIER();
    s16x8 af[4], bfm[NFR];
    #pragma unroll
    for (int m = 0; m < 4; ++m) {
      int rr = wm * 64 + m * 16 + lr;
      int chunk = rr * 4 + (kb ^ ((rr >> 1) & 3));
      af[m] = *(const s16x8*)&As[cur][chunk * 8];
    }
    #pragma unroll
    for (int nn = 0; nn < NFR; ++nn) {
      int rr = wn * (16 * NFR) + nn * 16 + lr;
      int chunk = rr * 4 + (kb ^ ((rr >> 1) & 3));
      bfm[nn] = *(const s16x8*)&Bs[cur][chunk * 8];
    }
    #pragma unroll
    for (int m = 0; m < 4; ++m)
      #pragma unroll
      for (int nn = 0; nn < NFR; ++nn)
        acc[m][nn] = __builtin_amdgcn_mfma_f32_16x16x32_bf16(af[m], bfm[nn], acc[m][nn], 0, 0, 0);
    RAW_BARRIER();
    if (t + 2 < nt) stage(cur, kbeg + ((t + 2) << 5));
    cur ^= 1;
  }

  size_t zoff = (size_t)blockIdx.z * M * N;
  #pragma unroll
  for (int m = 0; m < 4; ++m) {
    int rbase = row0 + wm * 64 + m * 16 + kb * 4;
    #pragma unroll
    for (int nn = 0; nn < NFR; ++nn) {
      int col = col0 + wn * (16 * NFR) + nn * 16 + lr;
      #pragma unroll
      for (int r = 0; r < 4; ++r) {
        int row = rbase + r;
        size_t idx = (size_t)row * N + col;
        float v = acc[m][nn][r];
        if (MODE == 0) {
          Cf[idx] = v;
        } else if (MODE == 2) {
          float tt = v + bias[col];
          float gl = 0.5f * tt * (1.f + erff(tt * 0.7071067811865475f));
          Cb[idx] = f2b(gl);
        } else if (MODE == 5) {
          Cf[zoff + idx] = v;
        } else {  // MODE 6
          float xx = v + bias[col];
          Cf[idx] = (xx > 20.f) ? xx : __logf(1.f + __expf(xx));
        }
      }
    }
  }
}

extern "C" void kernel_launch(void* const* d_in, const int* in_sizes, int n_in,
                              void* d_out, int out_size, void* d_ws, size_t ws_size,
                              hipStream_t stream) {
  (void)in_sizes; (void)n_in; (void)out_size; (void)ws_size;
  const float* src   = (const float*)d_in[0];
  const float* n1g   = (const float*)d_in[1];
  const float* n1b   = (const float*)d_in[2];
  const float* inW   = (const float*)d_in[3];
  const float* convW = (const float*)d_in[4];
  const float* convB = (const float*)d_in[5];
  const float* xpW   = (const float*)d_in[6];
  const float* dtW   = (const float*)d_in[7];
  const float* dtB   = (const float*)d_in[8];
  const float* Alog  = (const float*)d_in[9];
  const float* Dpar  = (const float*)d_in[10];
  const float* outW  = (const float*)d_in[11];
  const float* n2g   = (const float*)d_in[12];
  const float* n2b   = (const float*)d_in[13];
  const float* w1    = (const float*)d_in[14];
  const float* b1    = (const float*)d_in[15];
  const float* w2    = (const float*)d_in[16];
  const float* b2    = (const float*)d_in[17];

  char* ws = (char*)d_ws;
  unsigned short* wbA   = (unsigned short*)(ws + 0);          // in_proj bf16  (3072x768)
  unsigned short* wbO   = (unsigned short*)(ws + 4718592);    // out_proj bf16 (768x1536)
  unsigned short* wb1   = (unsigned short*)(ws + 7077888);    // w1 bf16       (3072x768)
  unsigned short* wb2   = (unsigned short*)(ws + 11796480);   // w2 bf16       (768x3072)
  unsigned short* wpad  = (unsigned short*)(ws + 16515072);   // x_proj padded (128x1536) bf16
  unsigned short* wdt   = (unsigned short*)(ws + 16908288);   // dt_proj padded (1536x64) bf16
  unsigned short* hbf   = (unsigned short*)(ws + 21626880);   // (4096x768) bf16 LN outputs
  float*          xres  = (float*)(ws + 27918336);            // (4096x3072) fp32; dead xs half = scan scratch;
                                                              // whole region = out/ffn2 split-K partials later
  float*          Ppart = (float*)(ws + 27918336);            // 2 x (4096x768) fp32 partials
  unsigned short* xsact = (unsigned short*)(ws + 78249984);   // (4096x1536) bf16 conv output (= u)
  float*          xbuf  = (float*)(ws + 78249984);            // (4096x768) fp32 (reuse, after scan)
  float*          dsp   = (float*)(ws + 90832896);            // (4096x1536) fp32 softplus(delta)
  unsigned short* ff1   = (unsigned short*)(ws + 90832896);   // (4096x3072) bf16 (reuse, after scan)
  float*          projBC= (float*)(ws + 115998720);           // (4096x32) fp32: B | C
  unsigned short* dtbf  = (unsigned short*)(ws + 116523008);  // (4096x64) bf16 dt padded
  float*          Pa    = (float*)(ws + 118095872);           // stage-A partials 4x(4096x128) fp32 (pre-scan)
  unsigned short* ybuf  = (unsigned short*)(ws + 118095872);  // (4096x1536) bf16 (scan output)
  float* outp = (float*)d_out;

  // weight prep
  cvt_all<<<8064, 256, 0, stream>>>(inW, outW, w1, w2, wbA, wbO, wb1, wb2);
  build_proj<<<1152, 256, 0, stream>>>(xpW, dtW, wpad, wdt);

  // mamba block
  ln_kernel<<<1024, 256, 0, stream>>>(src, n1g, n1b, hbf);
  gemm_bt<0, 128><<<dim3(32, 24), 256, 0, stream>>>(hbf, wbA, 4096, 3072, 768, xres, nullptr, nullptr, nullptr);
  conv_silu<<<6144, 256, 0, stream>>>(xres, convW, convB, xsact);

  // x_proj (N=80 padded to 128), split-K=4 -> reduce -> delta GEMM (K=64)
  gemm_bt<5, 64><<<dim3(64, 1, 4), 256, 0, stream>>>(xsact, wpad, 4096, 128, 1536, Pa, nullptr, nullptr, nullptr);
  reduce_projA<<<2048, 256, 0, stream>>>(Pa, dtbf, projBC);
  gemm_bt<6, 128><<<dim3(32, 12), 256, 0, stream>>>(dtbf, wdt, 4096, 1536, 64, dsp, nullptr, nullptr, dtB);

  scan_p1<<<1536, 256, 0, stream>>>(dsp, xsact, projBC, Alog, xres);
  scan_p2<<<384, 256, 0, stream>>>(xres);
  scan_p3<<<1536, 256, 0, stream>>>(dsp, xsact, projBC, xres, Alog, Dpar, ybuf);

  // out_proj split-K=2 (partials into dead xres) + fused residual+LN2
  gemm_bt<5, 64><<<dim3(64, 6, 2), 256, 0, stream>>>(ybuf, wbO, 4096, 768, 1536, Ppart, nullptr, nullptr, nullptr);
  reduce_ln<<<1024, 256, 0, stream>>>(Ppart, src, n2g, n2b, xbuf, hbf);

  // FFN block
  gemm_bt<2, 128><<<dim3(32, 24), 256, 0, stream>>>(hbf, wb1, 4096, 3072, 768, nullptr, ff1, nullptr, b1);
  gemm_bt<5, 64><<<dim3(64, 6, 2), 256, 0, stream>>>(ff1, wb2, 4096, 768, 3072, Ppart, nullptr, nullptr, nullptr);
  reduce_out<<<3072, 256, 0, stream>>>(Ppart, xbuf, b2, outp);
}